// Round 4
// baseline (3052.762 us; speedup 1.0000x reference)
//
#include <hip/hip_runtime.h>
#include <hip/hip_fp16.h>

#define NA 100000
#define NBATCH 4096
#define MLD 65

typedef _Float16 f16;
typedef f16 half8 __attribute__((ext_vector_type(8)));
typedef float f32x4 __attribute__((ext_vector_type(4)));
union H8 { uint4 u; __half h[8]; };
union HU { uint4 u; half8 h; };

// ---------------- CSR build ----------------

struct MapsParams {
  const int* row[6];
  int cnt_off[6];
  int start[6];
  int total;
};

__global__ __launch_bounds__(256) void k_count(MapsParams mp, int* cnt) {
  for (int g = blockIdx.x * 256 + threadIdx.x; g < mp.total; g += gridDim.x * 256) {
    int m = 0;
#pragma unroll
    for (int i = 1; i < 6; i++) if (g >= mp.start[i]) m = i;
    int e = g - mp.start[m];
    atomicAdd(&cnt[mp.cnt_off[m] + mp.row[m][e]], 1);
  }
}

__global__ __launch_bounds__(256) void k_fill(MapsParams mp, int* cursor, int* bucket) {
  for (int g = blockIdx.x * 256 + threadIdx.x; g < mp.total; g += gridDim.x * 256) {
    int m = 0;
#pragma unroll
    for (int i = 1; i < 6; i++) if (g >= mp.start[i]) m = i;
    int e = g - mp.start[m];
    int pos = atomicAdd(&cursor[mp.cnt_off[m] + mp.row[m][e]], 1);
    bucket[pos] = e;
  }
}

__global__ __launch_bounds__(256) void k_scanA(const int* in, int* out, int* bsums, int n) {
  __shared__ int s[256];
  int t = threadIdx.x;
  int base = blockIdx.x * 2048 + t * 8;
  int v[8]; int sum = 0;
#pragma unroll
  for (int i = 0; i < 8; i++) { v[i] = (base + i < n) ? in[base + i] : 0; sum += v[i]; }
  s[t] = sum;
  __syncthreads();
  for (int d = 1; d < 256; d <<= 1) {
    int x = (t >= d) ? s[t - d] : 0;
    __syncthreads();
    s[t] += x;
    __syncthreads();
  }
  if (t == 255) bsums[blockIdx.x] = s[255];
  int run = s[t] - sum;
#pragma unroll
  for (int i = 0; i < 8; i++) { if (base + i < n) out[base + i] = run; run += v[i]; }
}

__global__ __launch_bounds__(256) void k_scanB(int* a, int n) {
  __shared__ int s[256];
  int t = threadIdx.x;
  int carry = 0;
  for (int c0 = 0; c0 < n; c0 += 256) {
    int v = (c0 + t < n) ? a[c0 + t] : 0;
    s[t] = v;
    __syncthreads();
    for (int d = 1; d < 256; d <<= 1) {
      int x = (t >= d) ? s[t - d] : 0;
      __syncthreads();
      s[t] += x;
      __syncthreads();
    }
    if (c0 + t < n) a[c0 + t] = s[t] - v + carry;
    int tot = s[255];
    __syncthreads();
    carry += tot;
  }
}

__global__ __launch_bounds__(256) void k_scanC(int* out, const int* bsums, int n) {
  int addv = bsums[blockIdx.x];
  int base = blockIdx.x * 2048 + threadIdx.x * 8;
#pragma unroll
  for (int i = 0; i < 8; i++) if (base + i < n) out[base + i] += addv;
}

// ---------------- feature init ----------------

__global__ __launch_bounds__(256) void k_atom_init(const int* xa, const float* e0,
                                                   const float* e1, const float* e2, float* x) {
  int idx = blockIdx.x * 256 + threadIdx.x;  // float4 index
  if (idx >= NA * 16) return;
  int a = idx >> 4, q = idx & 15;
  int f0 = xa[a * 3], f1 = xa[a * 3 + 1], f2 = xa[a * 3 + 2];
  float4 v0 = ((const float4*)e0)[f0 * 16 + q];
  float4 v1 = ((const float4*)e1)[f1 * 16 + q];
  float4 v2 = ((const float4*)e2)[f2 * 16 + q];
  float4 o;
  o.x = v0.x + v1.x + v2.x; o.y = v0.y + v1.y + v2.y;
  o.z = v0.z + v1.z + v2.z; o.w = v0.w + v1.w + v2.w;
  ((float4*)x)[idx] = o;
}

struct PInit {
  __half* dst[5];
  const int* vals[5];
  const float* tab[5];
  int start8[5];  // cumulative half8-chunk starts
  int total8;
};

__global__ __launch_bounds__(256) void k_path_init(PInit pp) {
  for (int g = blockIdx.x * 256 + threadIdx.x; g < pp.total8; g += gridDim.x * 256) {
    int m = 0;
#pragma unroll
    for (int i = 1; i < 5; i++) if (g >= pp.start8[i]) m = i;
    int lc = g - pp.start8[m];
    int e = lc >> 3, q = lc & 7;
    int v = pp.vals[m][e];
    const float* src = pp.tab[m] + v * 64 + q * 8;
    H8 o;
#pragma unroll
    for (int j = 0; j < 8; j++) o.h[j] = __float2half(src[j]);
    ((uint4*)pp.dst[m])[lc] = o.u;
  }
}

// ---------------- prepack conv kernels to fp16 MFMA-B layout ----------------

__global__ __launch_bounds__(256) void k_prepB(const float* pK, const float* cK, f16* Bp) {
  int tid = blockIdx.x * 256 + threadIdx.x;
  if (tid >= 10 * 12288) return;
  int set = tid / 12288, pos = tid % 12288;
  int j = pos & 7, lane = (pos >> 3) & 63, kcnt = pos >> 9;
  int kc = kcnt % 6, nt = kcnt / 6;
  int k = kc * 32 + ((lane >> 4) << 3) + j;
  int n = (nt << 4) + (lane & 15);
  int w = k >> 6, ji = k & 63;
  const float* K = (set < 6) ? (pK + set * 3 * 4096) : (cK + (set - 6) * 3 * 4096);
  float v = K[w * 4096 + ji * 64 + n];
  if (set >= 6) v = 0.5f * (v + K[(2 - w) * 4096 + ji * 64 + n]);
  Bp[tid] = (f16)v;
}

// ---------------- prepack p2a weights to fp16 MFMA-B layout (64x64) ----------------
// sets 0..5 = pW_p2a[l*3+m], sets 6..9 = cW_p2a[l*2+i]

__global__ __launch_bounds__(256) void k_prepW(const float* pW, const float* cW, f16* Wp) {
  int tid = blockIdx.x * 256 + threadIdx.x;
  if (tid >= 10 * 4096) return;
  int set = tid >> 12, pos = tid & 4095;
  int j = pos & 7, lane = (pos >> 3) & 63, ntkc = pos >> 9;
  int kc = ntkc & 1, nt = ntkc >> 1;
  int k = kc * 32 + ((lane >> 4) << 3) + j;
  int n = (nt << 4) + (lane & 15);
  const float* W = (set < 6) ? (pW + set * 4096) : (cW + (set - 6) * 4096);
  Wp[tid] = (f16)W[k * 64 + n];
}

// ---------------- a2p: xp = xp + relu(gather(x) @ W + b), fp16 out ----------------

struct A2pParams {
  const float* x;
  const int* gidx[3];
  __half* out[3];
  const float* W[3];
  const float* bias[3];
  int blk_start[3];
  int nseg;
};

__global__ __launch_bounds__(256) void k_a2p(A2pParams p) {
  __shared__ float Wl[4096];
  __shared__ float inl[32 * 64];
  __shared__ float bl[64];
  __shared__ int ridx[32];
  int bid = blockIdx.x;
  int seg = 0;
#pragma unroll
  for (int i = 1; i < 3; i++) if (i < p.nseg && bid >= p.blk_start[i]) seg = i;
  int brow = (bid - p.blk_start[seg]) * 32;  // all E divisible by 32: no tail
  int t = threadIdx.x;
#pragma unroll
  for (int i = 0; i < 4; i++)
    ((float4*)Wl)[t + 256 * i] = ((const float4*)p.W[seg])[t + 256 * i];
  if (t < 64) bl[t] = p.bias[seg][t];
  if (t < 32) ridx[t] = p.gidx[seg][brow + t];
  __syncthreads();
#pragma unroll
  for (int i = 0; i < 2; i++) {
    int idx = t + 256 * i;
    int r = idx >> 4, q = idx & 15;
    ((float4*)inl)[idx] = ((const float4*)(p.x + (long)ridx[r] * 64))[q];
  }
  __syncthreads();
  int c = t & 63, rq = t >> 6;
  float acc[8];
#pragma unroll
  for (int i = 0; i < 8; i++) acc[i] = 0.f;
  for (int j = 0; j < 64; j += 4) {
    float w0 = Wl[(j + 0) * 64 + c], w1 = Wl[(j + 1) * 64 + c];
    float w2 = Wl[(j + 2) * 64 + c], w3 = Wl[(j + 3) * 64 + c];
#pragma unroll
    for (int i = 0; i < 8; i++) {
      int r = rq * 8 + i;
      float4 v = *(const float4*)&inl[r * 64 + j];
      acc[i] += v.x * w0 + v.y * w1 + v.z * w2 + v.w * w3;
    }
  }
  float bv = bl[c];
  __half* out = p.out[seg];
#pragma unroll
  for (int i = 0; i < 8; i++) {
    long e = brow + rq * 8 + i;
    float v = acc[i] + bv;
    v = v > 0.f ? v : 0.f;
    float r32 = __half2float(out[e * 64 + c]);
    out[e * 64 + c] = __float2half(r32 + v);
  }
}

// ---------------- MFMA conv: buf = pre + relu([Rx192]@[192x64] + Kb) ----------------

struct ConvParams {
  f16* buf[3];
  const f16* Bp[3];
  const float* Kb[3];
  int k[3];
  int P[3];
  int ppb[3];
  int blk_start[3];
  int nseg;
  int cyclic;
};

__global__ __launch_bounds__(256) void k_conv(ConvParams p) {
  __shared__ uint4 Apk[2304];  // up to 6 m-tiles * 6 kc * 64 lanes * 16B = 36864B
  __shared__ uint4 Bpk[1536];  // 4 nt * 6 kc * 64 * 16B = 24576B
  __shared__ float kbl[64];
  int bid = blockIdx.x;
  int seg = 0;
#pragma unroll
  for (int i = 1; i < 3; i++) if (i < p.nseg && bid >= p.blk_start[i]) seg = i;
  int kk = p.k[seg], ppb = p.ppb[seg], P = p.P[seg];
  f16* buf = p.buf[seg];
  int t = threadIdx.x;
  int p0 = (bid - p.blk_start[seg]) * ppb;
  int np = min(ppb, P - p0);
  int R = np * kk;       // always a multiple of 16 for our ppb choices
  int mtb = R >> 4;      // m-tiles: 4..6
  long ebase = (long)p0 * kk;
  {
    const uint4* bs = (const uint4*)p.Bp[seg];
    for (int i = t; i < 1536; i += 256) Bpk[i] = bs[i];
  }
  if (t < 64) kbl[t] = p.Kb[seg][t];
  {
    uint4 z; z.x = z.y = z.z = z.w = 0;
    int nU = mtb * 384;
    for (int i = t; i < nU; i += 256) Apk[i] = z;
  }
  __syncthreads();
  {
    const uint4* src = (const uint4*)(buf + ebase * 64);
    int tot = R * 8;
    for (int idx = t; idx < tot; idx += 256) {
      int r = idx >> 3, jj = idx & 7;
      uint4 ch = src[idx];
      int s = r % kk;
      int kchi = jj >> 2, quad = jj & 3;
#pragma unroll
      for (int w = 0; w < 3; w++) {
        int rd;
        if (w == 1) rd = r;
        else if (w == 0) rd = (s + 1 < kk) ? r + 1 : (p.cyclic ? r + 1 - kk : -1);
        else rd = (s >= 1) ? r - 1 : (p.cyclic ? r + kk - 1 : -1);
        if (rd >= 0)
          Apk[((rd >> 4) * 6 + 2 * w + kchi) * 64 + quad * 16 + (rd & 15)] = ch;
      }
    }
  }
  __syncthreads();
  int lane = t & 63, wid = t >> 6;
  int wave_n = wid & 1, wave_m = wid >> 1;
  int mtA = (mtb + 1) >> 1;
  int m0 = wave_m ? mtA : 0;
  int mcnt = wave_m ? (mtb - mtA) : mtA;  // <= 3
  f32x4 acc[3][2];
#pragma unroll
  for (int i = 0; i < 3; i++)
#pragma unroll
    for (int jn = 0; jn < 2; jn++) {
      f32x4 z = {0.f, 0.f, 0.f, 0.f};
      acc[i][jn] = z;
    }
  for (int kc = 0; kc < 6; kc++) {
    HU a[3], b[2];
#pragma unroll
    for (int jn = 0; jn < 2; jn++)
      b[jn].u = Bpk[((wave_n * 2 + jn) * 6 + kc) * 64 + lane];
#pragma unroll
    for (int i = 0; i < 3; i++)
      if (i < mcnt) a[i].u = Apk[((m0 + i) * 6 + kc) * 64 + lane];
#pragma unroll
    for (int i = 0; i < 3; i++)
      if (i < mcnt) {
#pragma unroll
        for (int jn = 0; jn < 2; jn++)
          acc[i][jn] = __builtin_amdgcn_mfma_f32_16x16x32_f16(a[i].h, b[jn].h, acc[i][jn], 0, 0, 0);
      }
  }
  const f16* Ah = (const f16*)Apk;
#pragma unroll
  for (int i = 0; i < 3; i++) {
    if (i >= mcnt) continue;
    int mt = m0 + i;
#pragma unroll
    for (int jn = 0; jn < 2; jn++) {
      int n = (wave_n * 2 + jn) * 16 + (lane & 15);
      int kcr = 2 + (n >> 5), quadb = (n & 31) >> 3, jr = n & 7;
#pragma unroll
      for (int reg = 0; reg < 4; reg++) {
        int r = mt * 16 + ((lane >> 4) << 2) + reg;
        float pre = (float)Ah[(((mt * 6 + kcr) * 64 + quadb * 16 + (r & 15)) << 3) + jr];
        float v = acc[i][jn][reg] + kbl[n];
        v = v > 0.f ? v : 0.f;
        buf[(ebase + r) * 64 + n] = (f16)(pre + v);
      }
    }
  }
}

// ---------------- fused p2a v2: x += sum_m relu(csr_mean(xp_m) @ W_m + b_m) ----------------
// block = 64 atoms; edge-parallel LDS-atomic mean; MFMA GEMM with prepacked fp16 W.

struct P2aParams {
  float* x;
  const f16* xp[3];
  const int* rows[3];
  const f16* Wp[3];
  const float* bias[3];
  const int* bucket;
  const int* basea;
  int off[3];
  int nmaps;
};

__global__ __launch_bounds__(256) void k_p2a(P2aParams p) {
  __shared__ float mean[64 * MLD];  // 16.6KB, stride-65: conflict-free column walks
  __shared__ uint4 Wl[512];         // 8KB fp16 B-frags
  __shared__ uint4 Af[512];         // 8KB fp16 A-frags
  __shared__ float bl[64];
  __shared__ int sb[65];
  int t = threadIdx.x;
  int a0 = blockIdx.x * 64;
  int lane = t & 63, wid = t >> 6;
  f32x4 addv[4];
#pragma unroll
  for (int nt = 0; nt < 4; nt++) {
    f32x4 z = {0.f, 0.f, 0.f, 0.f};
    addv[nt] = z;
  }
  for (int m = 0; m < p.nmaps; m++) {
    __syncthreads();  // prior iteration's MFMA reads done
    for (int i = t; i < 64 * MLD; i += 256) mean[i] = 0.f;
    if (t <= 64) {
      int aa = a0 + t; if (aa > NA) aa = NA;
      sb[t] = p.basea[p.off[m] + aa];
    }
    Wl[t] = ((const uint4*)p.Wp[m])[t];
    Wl[t + 256] = ((const uint4*)p.Wp[m])[t + 256];
    if (t < 64) bl[t] = p.bias[m][t];
    __syncthreads();
    int s0 = sb[0], s1 = sb[64];
    const f16* src = p.xp[m];
    const int* rows = p.rows[m];
    for (int base = s0 + wid * 4; base < s1; base += 16) {
      int e[4];
#pragma unroll
      for (int u = 0; u < 4; u++) {
        int jj = base + u;
        e[u] = (jj < s1) ? p.bucket[jj] : -1;
      }
      int at[4];
#pragma unroll
      for (int u = 0; u < 4; u++) if (e[u] >= 0) at[u] = rows[e[u]];
      float v[4];
#pragma unroll
      for (int u = 0; u < 4; u++) if (e[u] >= 0) v[u] = (float)src[(long)e[u] * 64 + lane];
#pragma unroll
      for (int u = 0; u < 4; u++)
        if (e[u] >= 0) atomicAdd(&mean[(at[u] - a0) * MLD + lane], v[u]);
    }
    __syncthreads();
    // divide by count + pack to fp16 A-frags
#pragma unroll
    for (int i = 0; i < 2; i++) {
      int la = (t >> 3) + 32 * i;
      int g = t & 7;
      int cb = sb[la + 1] - sb[la];
      float inv = 1.f / (float)(cb > 0 ? cb : 1);
      const float* mr = &mean[la * MLD + g * 8];
      HU o;
#pragma unroll
      for (int j = 0; j < 8; j++) o.h[j] = (f16)(mr[j] * inv);
      int kc = g >> 2, lb = ((g & 3) << 4) + (la & 15), mtt = la >> 4;
      Af[(((mtt << 1) + kc) << 6) + lb] = o.u;
    }
    __syncthreads();
    HU af0, af1;
    af0.u = Af[((wid << 1) + 0) * 64 + lane];
    af1.u = Af[((wid << 1) + 1) * 64 + lane];
#pragma unroll
    for (int nt = 0; nt < 4; nt++) {
      f32x4 z = {0.f, 0.f, 0.f, 0.f};
      HU b0, b1;
      b0.u = Wl[((nt << 1) + 0) * 64 + lane];
      b1.u = Wl[((nt << 1) + 1) * 64 + lane];
      z = __builtin_amdgcn_mfma_f32_16x16x32_f16(af0.h, b0.h, z, 0, 0, 0);
      z = __builtin_amdgcn_mfma_f32_16x16x32_f16(af1.h, b1.h, z, 0, 0, 0);
      float bv = bl[nt * 16 + (lane & 15)];
#pragma unroll
      for (int r = 0; r < 4; r++) {
        float vv = z[r] + bv;
        addv[nt][r] += vv > 0.f ? vv : 0.f;
      }
    }
  }
  // epilogue: x += addv (C layout: row = (lane>>4)*4+reg, col = lane&15)
  int rowb = a0 + wid * 16 + ((lane >> 4) << 2);
#pragma unroll
  for (int nt = 0; nt < 4; nt++) {
    int n = nt * 16 + (lane & 15);
#pragma unroll
    for (int r = 0; r < 4; r++) {
      int atom = rowb + r;
      if (atom < NA) p.x[(long)atom * 64 + n] += addv[nt][r];
    }
  }
}

// ---------------- batch mean: g1[b] = mean(x[a]) over CSR bucket ----------------

__global__ __launch_bounds__(256) void k_meanscatter(const float* src, const int* bucket,
                                                     const int* basea, const int* cnta,
                                                     float* dst, int nseg) {
  int wid = (blockIdx.x * 256 + threadIdx.x) >> 6;
  int lane = threadIdx.x & 63;
  if (wid >= nseg) return;
  int b0 = basea[wid], cnt = cnta[wid];
  float s = 0.f;
  for (int i = 0; i < cnt; i++) {
    int e = bucket[b0 + i];
    s += src[(long)e * 64 + lane];
  }
  dst[(long)wid * 64 + lane] = s / (float)(cnt > 0 ? cnt : 1);
}

// ---------------- head gemm: g2 = relu(g1 @ W + b) ----------------

__global__ __launch_bounds__(256) void k_head(const float* g1, const float* W,
                                              const float* bias, float* g2) {
  __shared__ float Wl[4096];
  __shared__ float inl[32 * 64];
  __shared__ float bl[64];
  int t = threadIdx.x;
  int brow = blockIdx.x * 32;
#pragma unroll
  for (int i = 0; i < 4; i++) ((float4*)Wl)[t + 256 * i] = ((const float4*)W)[t + 256 * i];
  if (t < 64) bl[t] = bias[t];
  __syncthreads();
#pragma unroll
  for (int i = 0; i < 2; i++) {
    int idx = t + 256 * i;
    int r = idx >> 4, q = idx & 15;
    ((float4*)inl)[idx] = ((const float4*)(g1 + (long)(brow + r) * 64))[q];
  }
  __syncthreads();
  int c = t & 63, rq = t >> 6;
  float acc[8];
#pragma unroll
  for (int i = 0; i < 8; i++) acc[i] = 0.f;
  for (int j = 0; j < 64; j += 4) {
    float w0 = Wl[(j + 0) * 64 + c], w1 = Wl[(j + 1) * 64 + c];
    float w2 = Wl[(j + 2) * 64 + c], w3 = Wl[(j + 3) * 64 + c];
#pragma unroll
    for (int i = 0; i < 8; i++) {
      int r = rq * 8 + i;
      float4 v = *(const float4*)&inl[r * 64 + j];
      acc[i] += v.x * w0 + v.y * w1 + v.z * w2 + v.w * w3;
    }
  }
#pragma unroll
  for (int i = 0; i < 8; i++) {
    long r = brow + rq * 8 + i;
    float v = acc[i] + bl[c];
    g2[r * 64 + c] = v > 0.f ? v : 0.f;
  }
}

__global__ __launch_bounds__(256) void k_final(const float* g2, const float* linW,
                                               const float* linb, float* out) {
  int wid = (blockIdx.x * 256 + threadIdx.x) >> 6;
  int lane = threadIdx.x & 63;
  if (wid >= NBATCH) return;
  float v = g2[(long)wid * 64 + lane] * linW[lane];
  for (int o = 32; o > 0; o >>= 1) v += __shfl_down(v, o, 64);
  if (lane == 0) out[wid] = v + linb[0];
}

__global__ __launch_bounds__(256) void k_zero_out(float* out, int n) {
  for (int i = blockIdx.x * 256 + threadIdx.x; i < n; i += gridDim.x * 256) out[i] = 0.f;
}

// ---------------- launcher ----------------

extern "C" void kernel_launch(void* const* d_in, const int* in_sizes, int n_in,
                              void* d_out, int out_size, void* d_ws, size_t ws_size,
                              hipStream_t stream) {
  (void)in_sizes; (void)n_in;

  const int* x_atom = (const int*)d_in[0];
  const int* vals[5] = {(const int*)d_in[1], (const int*)d_in[4], (const int*)d_in[7],
                        (const int*)d_in[10], (const int*)d_in[13]};
  const int* rowm[5] = {(const int*)d_in[2], (const int*)d_in[5], (const int*)d_in[8],
                        (const int*)d_in[11], (const int*)d_in[14]};
  const int* batch = (const int*)d_in[16];
  const float* aemb0 = (const float*)d_in[17];
  const float* aemb1 = (const float*)d_in[18];
  const float* aemb2 = (const float*)d_in[19];
  const float* path_emb = (const float*)d_in[20];
  const float* cycle_emb = (const float*)d_in[21];
  const float* pW_a2p = (const float*)d_in[22];
  const float* pb_a2p = (const float*)d_in[23];
  const float* pW_p2a = (const float*)d_in[24];
  const float* pb_p2a = (const float*)d_in[25];
  const float* pK = (const float*)d_in[26];
  const float* pKb = (const float*)d_in[27];
  const float* cW_a2p = (const float*)d_in[28];
  const float* cb_a2p = (const float*)d_in[29];
  const float* cW_p2a = (const float*)d_in[30];
  const float* cb_p2a = (const float*)d_in[31];
  const float* cK = (const float*)d_in[32];
  const float* cKb = (const float*)d_in[33];
  const float* alW = (const float*)d_in[34];
  const float* alb = (const float*)d_in[35];
  const float* linW = (const float*)d_in[36];
  const float* linb = (const float*)d_in[37];

  static const int Em[5] = {300000, 400000, 500000, 200000, 240000};
  static const int Km[5] = {3, 4, 5, 5, 6};
  static const int Ppb[5] = {32, 24, 16, 16, 16};  // paths/block -> R in {96,96,80,80,96}
  const int CNT_N = 5 * 100000 + NBATCH;  // 504096
  const int BUCKET_N = 1640000 + 100000;  // 1740000

  char* ws = (char*)d_ws;
  size_t off = 0;
  auto alloc = [&](size_t nbytes) -> char* {
    char* p = ws + off;
    off = (off + nbytes + 255) & ~(size_t)255;
    return p;
  };
  float* x = (float*)alloc((size_t)NA * 64 * 4);
  __half* xp[5];
  for (int m = 0; m < 5; m++) xp[m] = (__half*)alloc((size_t)Em[m] * 64 * 2);
  float* g1 = (float*)alloc((size_t)NBATCH * 64 * 4);
  float* g2 = (float*)alloc((size_t)NBATCH * 64 * 4);
  int* cnt = (int*)alloc((size_t)CNT_N * 4);
  int* basea = (int*)alloc((size_t)CNT_N * 4);
  int* cursor = (int*)alloc((size_t)CNT_N * 4);
  int* bucket = (int*)alloc((size_t)BUCKET_N * 4);
  int* bsums = (int*)alloc(256 * 4);
  f16* Bp = (f16*)alloc((size_t)10 * 12288 * 2);  // prepacked conv kernels
  f16* Wp2a = (f16*)alloc((size_t)10 * 4096 * 2); // prepacked p2a weights

  if (ws_size < off) {  // workspace too small: emit readable failure, not a fault
    k_zero_out<<<16, 256, 0, stream>>>((float*)d_out, out_size);
    return;
  }

  // ---- CSR build
  MapsParams mp;
  {
    int s = 0;
    for (int m = 0; m < 5; m++) {
      mp.row[m] = rowm[m]; mp.cnt_off[m] = m * 100000;
      mp.start[m] = s; s += Em[m];
    }
    mp.row[5] = batch; mp.cnt_off[5] = 500000; mp.start[5] = s;
    mp.total = s + NA;
  }
  hipMemsetAsync(cnt, 0, (size_t)CNT_N * 4, stream);
  k_count<<<2048, 256, 0, stream>>>(mp, cnt);
  int nbScan = (CNT_N + 2047) / 2048;  // 247
  k_scanA<<<nbScan, 256, 0, stream>>>(cnt, basea, bsums, CNT_N);
  k_scanB<<<1, 256, 0, stream>>>(bsums, nbScan);
  k_scanC<<<nbScan, 256, 0, stream>>>(basea, bsums, CNT_N);
  hipMemcpyAsync(cursor, basea, (size_t)CNT_N * 4, hipMemcpyDeviceToDevice, stream);
  k_fill<<<2048, 256, 0, stream>>>(mp, cursor, bucket);

  // ---- prepack weights + feature init
  k_prepB<<<480, 256, 0, stream>>>(pK, cK, Bp);
  k_prepW<<<160, 256, 0, stream>>>(pW_p2a, cW_p2a, Wp2a);
  k_atom_init<<<NA * 16 / 256, 256, 0, stream>>>(x_atom, aemb0, aemb1, aemb2, x);
  {
    PInit pp;
    int s8 = 0;
    for (int m = 0; m < 5; m++) {
      pp.dst[m] = xp[m];
      pp.vals[m] = vals[m];
      pp.tab[m] = (m < 3) ? (path_emb + m * 6 * 64) : (cycle_emb + (m - 3) * 4 * 64);
      pp.start8[m] = s8;
      s8 += Em[m] * 8;
    }
    pp.total8 = s8;
    k_path_init<<<8192, 256, 0, stream>>>(pp);
  }

  int p2a_blocks = (NA + 63) / 64;  // 1563

  // ---- layers
  for (int l = 0; l < 2; l++) {
    // === paths group (maps 0..2), non-cyclic
    {
      A2pParams gp{};
      gp.nseg = 3; gp.x = x;
      int bs = 0;
      for (int m = 0; m < 3; m++) {
        gp.gidx[m] = rowm[m]; gp.out[m] = xp[m];
        gp.W[m] = pW_a2p + (l * 3 + m) * 4096;
        gp.bias[m] = pb_a2p + (l * 3 + m) * 64;
        gp.blk_start[m] = bs;
        bs += Em[m] / 32;
      }
      k_a2p<<<bs, 256, 0, stream>>>(gp);

      ConvParams cp{};
      cp.nseg = 3; cp.cyclic = 0;
      int cbs = 0;
      for (int m = 0; m < 3; m++) {
        cp.buf[m] = (f16*)xp[m];
        cp.Bp[m] = Bp + (size_t)(l * 3 + m) * 12288;
        cp.Kb[m] = pKb + (l * 3 + m) * 64;
        cp.k[m] = Km[m]; cp.P[m] = Em[m] / Km[m]; cp.ppb[m] = Ppb[m];
        cp.blk_start[m] = cbs;
        cbs += (cp.P[m] + cp.ppb[m] - 1) / cp.ppb[m];
      }
      k_conv<<<cbs, 256, 0, stream>>>(cp);

      P2aParams bp{};
      bp.x = x; bp.bucket = bucket; bp.basea = basea; bp.nmaps = 3;
      for (int m = 0; m < 3; m++) {
        bp.xp[m] = (const f16*)xp[m];
        bp.rows[m] = rowm[m];
        bp.off[m] = m * 100000;
        bp.Wp[m] = Wp2a + (size_t)(l * 3 + m) * 4096;
        bp.bias[m] = pb_p2a + (l * 3 + m) * 64;
      }
      k_p2a<<<p2a_blocks, 256, 0, stream>>>(bp);
    }
    // === cycles group (maps 3..4), cyclic
    {
      A2pParams gp{};
      gp.nseg = 2; gp.x = x;
      int bs = 0;
      for (int m = 3; m < 5; m++) {
        int i = m - 3;
        gp.gidx[i] = rowm[m]; gp.out[i] = xp[m];
        gp.W[i] = cW_a2p + (l * 2 + i) * 4096;
        gp.bias[i] = cb_a2p + (l * 2 + i) * 64;
        gp.blk_start[i] = bs;
        bs += Em[m] / 32;
      }
      k_a2p<<<bs, 256, 0, stream>>>(gp);

      ConvParams cp{};
      cp.nseg = 2; cp.cyclic = 1;
      int cbs = 0;
      for (int m = 3; m < 5; m++) {
        int i = m - 3;
        cp.buf[i] = (f16*)xp[m];
        cp.Bp[i] = Bp + (size_t)(6 + l * 2 + i) * 12288;
        cp.Kb[i] = cKb + (l * 2 + i) * 64;
        cp.k[i] = Km[m]; cp.P[i] = Em[m] / Km[m]; cp.ppb[i] = Ppb[m];
        cp.blk_start[i] = cbs;
        cbs += (cp.P[i] + cp.ppb[i] - 1) / cp.ppb[i];
      }
      k_conv<<<cbs, 256, 0, stream>>>(cp);

      P2aParams bp{};
      bp.x = x; bp.bucket = bucket; bp.basea = basea; bp.nmaps = 2;
      for (int m = 3; m < 5; m++) {
        int i = m - 3;
        bp.xp[i] = (const f16*)xp[m];
        bp.rows[i] = rowm[m];
        bp.off[i] = m * 100000;
        bp.Wp[i] = Wp2a + (size_t)(6 + l * 2 + i) * 4096;
        bp.bias[i] = cb_p2a + (l * 2 + i) * 64;
      }
      k_p2a<<<p2a_blocks, 256, 0, stream>>>(bp);
    }
  }

  // ---- head
  k_meanscatter<<<NBATCH / 4, 256, 0, stream>>>(x, bucket, basea + 500000, cnt + 500000,
                                                g1, NBATCH);
  k_head<<<NBATCH / 32, 256, 0, stream>>>(g1, alW, alb, g2);
  k_final<<<NBATCH / 4, 256, 0, stream>>>(g2, linW, linb, (float*)d_out);
}

// Round 5
// 3051.979 us; speedup vs baseline: 1.0003x; 1.0003x over previous
//
#include <hip/hip_runtime.h>
#include <hip/hip_fp16.h>

#define NA 100000
#define NBATCH 4096
#define MLD 65
#define CHUNK 512

typedef _Float16 f16;
typedef f16 half8 __attribute__((ext_vector_type(8)));
typedef float f32x4 __attribute__((ext_vector_type(4)));
union H8 { uint4 u; __half h[8]; };
union HU { uint4 u; half8 h; };

// ---------------- CSR build ----------------

struct MapsParams {
  const int* row[6];
  int cnt_off[6];
  int start[6];
  int total;
};

__global__ __launch_bounds__(256) void k_count(MapsParams mp, int* cnt) {
  for (int g = blockIdx.x * 256 + threadIdx.x; g < mp.total; g += gridDim.x * 256) {
    int m = 0;
#pragma unroll
    for (int i = 1; i < 6; i++) if (g >= mp.start[i]) m = i;
    int e = g - mp.start[m];
    atomicAdd(&cnt[mp.cnt_off[m] + mp.row[m][e]], 1);
  }
}

// bucket entries carry {edge, atom} to remove the rows[] dependent load
__global__ __launch_bounds__(256) void k_fill(MapsParams mp, int* cursor, int2* bucket) {
  for (int g = blockIdx.x * 256 + threadIdx.x; g < mp.total; g += gridDim.x * 256) {
    int m = 0;
#pragma unroll
    for (int i = 1; i < 6; i++) if (g >= mp.start[i]) m = i;
    int e = g - mp.start[m];
    int a = mp.row[m][e];
    int pos = atomicAdd(&cursor[mp.cnt_off[m] + a], 1);
    int2 v; v.x = e; v.y = a;
    bucket[pos] = v;
  }
}

__global__ __launch_bounds__(256) void k_scanA(const int* in, int* out, int* bsums, int n) {
  __shared__ int s[256];
  int t = threadIdx.x;
  int base = blockIdx.x * 2048 + t * 8;
  int v[8]; int sum = 0;
#pragma unroll
  for (int i = 0; i < 8; i++) { v[i] = (base + i < n) ? in[base + i] : 0; sum += v[i]; }
  s[t] = sum;
  __syncthreads();
  for (int d = 1; d < 256; d <<= 1) {
    int x = (t >= d) ? s[t - d] : 0;
    __syncthreads();
    s[t] += x;
    __syncthreads();
  }
  if (t == 255) bsums[blockIdx.x] = s[255];
  int run = s[t] - sum;
#pragma unroll
  for (int i = 0; i < 8; i++) { if (base + i < n) out[base + i] = run; run += v[i]; }
}

__global__ __launch_bounds__(256) void k_scanB(int* a, int n) {
  __shared__ int s[256];
  int t = threadIdx.x;
  int carry = 0;
  for (int c0 = 0; c0 < n; c0 += 256) {
    int v = (c0 + t < n) ? a[c0 + t] : 0;
    s[t] = v;
    __syncthreads();
    for (int d = 1; d < 256; d <<= 1) {
      int x = (t >= d) ? s[t - d] : 0;
      __syncthreads();
      s[t] += x;
      __syncthreads();
    }
    if (c0 + t < n) a[c0 + t] = s[t] - v + carry;
    int tot = s[255];
    __syncthreads();
    carry += tot;
  }
}

__global__ __launch_bounds__(256) void k_scanC(int* out, const int* bsums, int n) {
  int addv = bsums[blockIdx.x];
  int base = blockIdx.x * 2048 + threadIdx.x * 8;
#pragma unroll
  for (int i = 0; i < 8; i++) if (base + i < n) out[base + i] += addv;
}

// ---------------- feature init ----------------

__global__ __launch_bounds__(256) void k_atom_init(const int* xa, const float* e0,
                                                   const float* e1, const float* e2, float* x) {
  int idx = blockIdx.x * 256 + threadIdx.x;  // float4 index
  if (idx >= NA * 16) return;
  int a = idx >> 4, q = idx & 15;
  int f0 = xa[a * 3], f1 = xa[a * 3 + 1], f2 = xa[a * 3 + 2];
  float4 v0 = ((const float4*)e0)[f0 * 16 + q];
  float4 v1 = ((const float4*)e1)[f1 * 16 + q];
  float4 v2 = ((const float4*)e2)[f2 * 16 + q];
  float4 o;
  o.x = v0.x + v1.x + v2.x; o.y = v0.y + v1.y + v2.y;
  o.z = v0.z + v1.z + v2.z; o.w = v0.w + v1.w + v2.w;
  ((float4*)x)[idx] = o;
}

struct PInit {
  __half* dst[5];
  const int* vals[5];
  const float* tab[5];
  int start8[5];  // cumulative half8-chunk starts
  int total8;
};

__global__ __launch_bounds__(256) void k_path_init(PInit pp) {
  for (int g = blockIdx.x * 256 + threadIdx.x; g < pp.total8; g += gridDim.x * 256) {
    int m = 0;
#pragma unroll
    for (int i = 1; i < 5; i++) if (g >= pp.start8[i]) m = i;
    int lc = g - pp.start8[m];
    int e = lc >> 3, q = lc & 7;
    int v = pp.vals[m][e];
    const float* src = pp.tab[m] + v * 64 + q * 8;
    H8 o;
#pragma unroll
    for (int j = 0; j < 8; j++) o.h[j] = __float2half(src[j]);
    ((uint4*)pp.dst[m])[lc] = o.u;
  }
}

// ---------------- prepack conv kernels to fp16 MFMA-B layout ----------------

__global__ __launch_bounds__(256) void k_prepB(const float* pK, const float* cK, f16* Bp) {
  int tid = blockIdx.x * 256 + threadIdx.x;
  if (tid >= 10 * 12288) return;
  int set = tid / 12288, pos = tid % 12288;
  int j = pos & 7, lane = (pos >> 3) & 63, kcnt = pos >> 9;
  int kc = kcnt % 6, nt = kcnt / 6;
  int k = kc * 32 + ((lane >> 4) << 3) + j;
  int n = (nt << 4) + (lane & 15);
  int w = k >> 6, ji = k & 63;
  const float* K = (set < 6) ? (pK + set * 3 * 4096) : (cK + (set - 6) * 3 * 4096);
  float v = K[w * 4096 + ji * 64 + n];
  if (set >= 6) v = 0.5f * (v + K[(2 - w) * 4096 + ji * 64 + n]);
  Bp[tid] = (f16)v;
}

// ---------------- prepack p2a weights to fp16 MFMA-B layout (64x64) ----------------

__global__ __launch_bounds__(256) void k_prepW(const float* pW, const float* cW, f16* Wp) {
  int tid = blockIdx.x * 256 + threadIdx.x;
  if (tid >= 10 * 4096) return;
  int set = tid >> 12, pos = tid & 4095;
  int j = pos & 7, lane = (pos >> 3) & 63, ntkc = pos >> 9;
  int kc = ntkc & 1, nt = ntkc >> 1;
  int k = kc * 32 + ((lane >> 4) << 3) + j;
  int n = (nt << 4) + (lane & 15);
  const float* W = (set < 6) ? (pW + set * 4096) : (cW + (set - 6) * 4096);
  Wp[tid] = (f16)W[k * 64 + n];
}

// ---------------- a2p: xp = xp + relu(gather(x) @ W + b), fp16 out ----------------

struct A2pParams {
  const float* x;
  const int* gidx[3];
  __half* out[3];
  const float* W[3];
  const float* bias[3];
  int blk_start[3];
  int nseg;
};

__global__ __launch_bounds__(256) void k_a2p(A2pParams p) {
  __shared__ float Wl[4096];
  __shared__ float inl[32 * 64];
  __shared__ float bl[64];
  __shared__ int ridx[32];
  int bid = blockIdx.x;
  int seg = 0;
#pragma unroll
  for (int i = 1; i < 3; i++) if (i < p.nseg && bid >= p.blk_start[i]) seg = i;
  int brow = (bid - p.blk_start[seg]) * 32;  // all E divisible by 32: no tail
  int t = threadIdx.x;
#pragma unroll
  for (int i = 0; i < 4; i++)
    ((float4*)Wl)[t + 256 * i] = ((const float4*)p.W[seg])[t + 256 * i];
  if (t < 64) bl[t] = p.bias[seg][t];
  if (t < 32) ridx[t] = p.gidx[seg][brow + t];
  __syncthreads();
#pragma unroll
  for (int i = 0; i < 2; i++) {
    int idx = t + 256 * i;
    int r = idx >> 4, q = idx & 15;
    ((float4*)inl)[idx] = ((const float4*)(p.x + (long)ridx[r] * 64))[q];
  }
  __syncthreads();
  int c = t & 63, rq = t >> 6;
  float acc[8];
#pragma unroll
  for (int i = 0; i < 8; i++) acc[i] = 0.f;
  for (int j = 0; j < 64; j += 4) {
    float w0 = Wl[(j + 0) * 64 + c], w1 = Wl[(j + 1) * 64 + c];
    float w2 = Wl[(j + 2) * 64 + c], w3 = Wl[(j + 3) * 64 + c];
#pragma unroll
    for (int i = 0; i < 8; i++) {
      int r = rq * 8 + i;
      float4 v = *(const float4*)&inl[r * 64 + j];
      acc[i] += v.x * w0 + v.y * w1 + v.z * w2 + v.w * w3;
    }
  }
  float bv = bl[c];
  __half* out = p.out[seg];
#pragma unroll
  for (int i = 0; i < 8; i++) {
    long e = brow + rq * 8 + i;
    float v = acc[i] + bv;
    v = v > 0.f ? v : 0.f;
    float r32 = __half2float(out[e * 64 + c]);
    out[e * 64 + c] = __float2half(r32 + v);
  }
}

// ---------------- MFMA conv: buf = pre + relu([Rx192]@[192x64] + Kb) ----------------

struct ConvParams {
  f16* buf[3];
  const f16* Bp[3];
  const float* Kb[3];
  int k[3];
  int P[3];
  int ppb[3];
  int blk_start[3];
  int nseg;
  int cyclic;
};

__global__ __launch_bounds__(256) void k_conv(ConvParams p) {
  __shared__ uint4 Apk[2304];  // up to 6 m-tiles * 6 kc * 64 lanes * 16B = 36864B
  __shared__ uint4 Bpk[1536];  // 4 nt * 6 kc * 64 * 16B = 24576B
  __shared__ float kbl[64];
  int bid = blockIdx.x;
  int seg = 0;
#pragma unroll
  for (int i = 1; i < 3; i++) if (i < p.nseg && bid >= p.blk_start[i]) seg = i;
  int kk = p.k[seg], ppb = p.ppb[seg], P = p.P[seg];
  f16* buf = p.buf[seg];
  int t = threadIdx.x;
  int p0 = (bid - p.blk_start[seg]) * ppb;
  int np = min(ppb, P - p0);
  int R = np * kk;       // always a multiple of 16 for our ppb choices
  int mtb = R >> 4;      // m-tiles: 4..6
  long ebase = (long)p0 * kk;
  {
    const uint4* bs = (const uint4*)p.Bp[seg];
    for (int i = t; i < 1536; i += 256) Bpk[i] = bs[i];
  }
  if (t < 64) kbl[t] = p.Kb[seg][t];
  {
    uint4 z; z.x = z.y = z.z = z.w = 0;
    int nU = mtb * 384;
    for (int i = t; i < nU; i += 256) Apk[i] = z;
  }
  __syncthreads();
  {
    const uint4* src = (const uint4*)(buf + ebase * 64);
    int tot = R * 8;
    for (int idx = t; idx < tot; idx += 256) {
      int r = idx >> 3, jj = idx & 7;
      uint4 ch = src[idx];
      int s = r % kk;
      int kchi = jj >> 2, quad = jj & 3;
#pragma unroll
      for (int w = 0; w < 3; w++) {
        int rd;
        if (w == 1) rd = r;
        else if (w == 0) rd = (s + 1 < kk) ? r + 1 : (p.cyclic ? r + 1 - kk : -1);
        else rd = (s >= 1) ? r - 1 : (p.cyclic ? r + kk - 1 : -1);
        if (rd >= 0)
          Apk[((rd >> 4) * 6 + 2 * w + kchi) * 64 + quad * 16 + (rd & 15)] = ch;
      }
    }
  }
  __syncthreads();
  int lane = t & 63, wid = t >> 6;
  int wave_n = wid & 1, wave_m = wid >> 1;
  int mtA = (mtb + 1) >> 1;
  int m0 = wave_m ? mtA : 0;
  int mcnt = wave_m ? (mtb - mtA) : mtA;  // <= 3
  f32x4 acc[3][2];
#pragma unroll
  for (int i = 0; i < 3; i++)
#pragma unroll
    for (int jn = 0; jn < 2; jn++) {
      f32x4 z = {0.f, 0.f, 0.f, 0.f};
      acc[i][jn] = z;
    }
  for (int kc = 0; kc < 6; kc++) {
    HU a[3], b[2];
#pragma unroll
    for (int jn = 0; jn < 2; jn++)
      b[jn].u = Bpk[((wave_n * 2 + jn) * 6 + kc) * 64 + lane];
#pragma unroll
    for (int i = 0; i < 3; i++)
      if (i < mcnt) a[i].u = Apk[((m0 + i) * 6 + kc) * 64 + lane];
#pragma unroll
    for (int i = 0; i < 3; i++)
      if (i < mcnt) {
#pragma unroll
        for (int jn = 0; jn < 2; jn++)
          acc[i][jn] = __builtin_amdgcn_mfma_f32_16x16x32_f16(a[i].h, b[jn].h, acc[i][jn], 0, 0, 0);
      }
  }
  const f16* Ah = (const f16*)Apk;
#pragma unroll
  for (int i = 0; i < 3; i++) {
    if (i >= mcnt) continue;
    int mt = m0 + i;
#pragma unroll
    for (int jn = 0; jn < 2; jn++) {
      int n = (wave_n * 2 + jn) * 16 + (lane & 15);
      int kcr = 2 + (n >> 5), quadb = (n & 31) >> 3, jr = n & 7;
#pragma unroll
      for (int reg = 0; reg < 4; reg++) {
        int r = mt * 16 + ((lane >> 4) << 2) + reg;
        float pre = (float)Ah[(((mt * 6 + kcr) * 64 + quadb * 16 + (r & 15)) << 3) + jr];
        float v = acc[i][jn][reg] + kbl[n];
        v = v > 0.f ? v : 0.f;
        buf[(ebase + r) * 64 + n] = (f16)(pre + v);
      }
    }
  }
}

// ---------------- fused p2a v3: x += sum_m relu(csr_mean(xp_m) @ W_m + b_m) ----------------
// block = 64 atoms; indices staged to LDS (chunked), 8 gather loads in flight per wave.

struct P2aParams {
  float* x;
  const f16* xp[3];
  const f16* Wp[3];
  const float* bias[3];
  const int2* bucket;
  const int* basea;
  int off[3];
  int nmaps;
};

__global__ __launch_bounds__(256) void k_p2a(P2aParams p) {
  __shared__ float mean[64 * MLD];  // 16.6KB, stride-65: conflict-free
  __shared__ uint4 Wl[512];         // 8KB fp16 B-frags
  __shared__ uint4 Af[512];         // 8KB fp16 A-frags
  __shared__ int2 eidx[CHUNK];      // 4KB staged indices
  __shared__ float bl[64];
  __shared__ int sb[65];
  int t = threadIdx.x;
  int a0 = blockIdx.x * 64;
  int lane = t & 63, wid = t >> 6;
  f32x4 addv[4];
#pragma unroll
  for (int nt = 0; nt < 4; nt++) {
    f32x4 z = {0.f, 0.f, 0.f, 0.f};
    addv[nt] = z;
  }
  for (int m = 0; m < p.nmaps; m++) {
    __syncthreads();  // prior iteration's LDS readers done
    for (int i = t; i < 64 * MLD; i += 256) mean[i] = 0.f;
    if (t <= 64) {
      int aa = a0 + t; if (aa > NA) aa = NA;
      sb[t] = p.basea[p.off[m] + aa];
    }
    Wl[t] = ((const uint4*)p.Wp[m])[t];
    Wl[t + 256] = ((const uint4*)p.Wp[m])[t + 256];
    if (t < 64) bl[t] = p.bias[m][t];
    __syncthreads();
    int s0 = sb[0], s1 = sb[64];
    const f16* src = p.xp[m];
    for (int c0 = s0; c0 < s1; c0 += CHUNK) {
      int nc = min(CHUNK, s1 - c0);
      for (int i = t; i < nc; i += 256) eidx[i] = p.bucket[c0 + i];
      __syncthreads();
      for (int j = wid * 8; j < nc; j += 32) {
        if (j + 8 <= nc) {
          int2 e[8];
#pragma unroll
          for (int u = 0; u < 8; u++) e[u] = eidx[j + u];
          float v[8];
#pragma unroll
          for (int u = 0; u < 8; u++) v[u] = (float)src[(long)e[u].x * 64 + lane];
#pragma unroll
          for (int u = 0; u < 8; u++)
            atomicAdd(&mean[(e[u].y - a0) * MLD + lane], v[u]);
        } else {
          for (int u = 0; u < nc - j; u++) {
            int2 e = eidx[j + u];
            float v = (float)src[(long)e.x * 64 + lane];
            atomicAdd(&mean[(e.y - a0) * MLD + lane], v);
          }
        }
      }
      __syncthreads();
    }
    // divide by count + pack to fp16 A-frags
#pragma unroll
    for (int i = 0; i < 2; i++) {
      int la = (t >> 3) + 32 * i;
      int g = t & 7;
      int cb = sb[la + 1] - sb[la];
      float inv = 1.f / (float)(cb > 0 ? cb : 1);
      const float* mr = &mean[la * MLD + g * 8];
      HU o;
#pragma unroll
      for (int j = 0; j < 8; j++) o.h[j] = (f16)(mr[j] * inv);
      int kc = g >> 2, lb = ((g & 3) << 4) + (la & 15), mtt = la >> 4;
      Af[(((mtt << 1) + kc) << 6) + lb] = o.u;
    }
    __syncthreads();
    HU af0, af1;
    af0.u = Af[((wid << 1) + 0) * 64 + lane];
    af1.u = Af[((wid << 1) + 1) * 64 + lane];
#pragma unroll
    for (int nt = 0; nt < 4; nt++) {
      f32x4 z = {0.f, 0.f, 0.f, 0.f};
      HU b0, b1;
      b0.u = Wl[((nt << 1) + 0) * 64 + lane];
      b1.u = Wl[((nt << 1) + 1) * 64 + lane];
      z = __builtin_amdgcn_mfma_f32_16x16x32_f16(af0.h, b0.h, z, 0, 0, 0);
      z = __builtin_amdgcn_mfma_f32_16x16x32_f16(af1.h, b1.h, z, 0, 0, 0);
      float bv = bl[nt * 16 + (lane & 15)];
#pragma unroll
      for (int r = 0; r < 4; r++) {
        float vv = z[r] + bv;
        addv[nt][r] += vv > 0.f ? vv : 0.f;
      }
    }
  }
  // epilogue: x += addv (C layout: row = (lane>>4)*4+reg, col = lane&15)
  int rowb = a0 + wid * 16 + ((lane >> 4) << 2);
#pragma unroll
  for (int nt = 0; nt < 4; nt++) {
    int n = nt * 16 + (lane & 15);
#pragma unroll
    for (int r = 0; r < 4; r++) {
      int atom = rowb + r;
      if (atom < NA) p.x[(long)atom * 64 + n] += addv[nt][r];
    }
  }
}

// ---------------- batch mean: g1[b] = mean(x[a]) over CSR bucket ----------------

__global__ __launch_bounds__(256) void k_meanscatter(const float* src, const int2* bucket,
                                                     const int* basea, const int* cnta,
                                                     float* dst, int nseg) {
  int wid = (blockIdx.x * 256 + threadIdx.x) >> 6;
  int lane = threadIdx.x & 63;
  if (wid >= nseg) return;
  int b0 = basea[wid], cnt = cnta[wid];
  float s = 0.f;
  for (int i = 0; i < cnt; i++) {
    int e = bucket[b0 + i].x;
    s += src[(long)e * 64 + lane];
  }
  dst[(long)wid * 64 + lane] = s / (float)(cnt > 0 ? cnt : 1);
}

// ---------------- head gemm: g2 = relu(g1 @ W + b) ----------------

__global__ __launch_bounds__(256) void k_head(const float* g1, const float* W,
                                              const float* bias, float* g2) {
  __shared__ float Wl[4096];
  __shared__ float inl[32 * 64];
  __shared__ float bl[64];
  int t = threadIdx.x;
  int brow = blockIdx.x * 32;
#pragma unroll
  for (int i = 0; i < 4; i++) ((float4*)Wl)[t + 256 * i] = ((const float4*)W)[t + 256 * i];
  if (t < 64) bl[t] = bias[t];
  __syncthreads();
#pragma unroll
  for (int i = 0; i < 2; i++) {
    int idx = t + 256 * i;
    int r = idx >> 4, q = idx & 15;
    ((float4*)inl)[idx] = ((const float4*)(g1 + (long)(brow + r) * 64))[q];
  }
  __syncthreads();
  int c = t & 63, rq = t >> 6;
  float acc[8];
#pragma unroll
  for (int i = 0; i < 8; i++) acc[i] = 0.f;
  for (int j = 0; j < 64; j += 4) {
    float w0 = Wl[(j + 0) * 64 + c], w1 = Wl[(j + 1) * 64 + c];
    float w2 = Wl[(j + 2) * 64 + c], w3 = Wl[(j + 3) * 64 + c];
#pragma unroll
    for (int i = 0; i < 8; i++) {
      int r = rq * 8 + i;
      float4 v = *(const float4*)&inl[r * 64 + j];
      acc[i] += v.x * w0 + v.y * w1 + v.z * w2 + v.w * w3;
    }
  }
#pragma unroll
  for (int i = 0; i < 8; i++) {
    long r = brow + rq * 8 + i;
    float v = acc[i] + bl[c];
    g2[r * 64 + c] = v > 0.f ? v : 0.f;
  }
}

__global__ __launch_bounds__(256) void k_final(const float* g2, const float* linW,
                                               const float* linb, float* out) {
  int wid = (blockIdx.x * 256 + threadIdx.x) >> 6;
  int lane = threadIdx.x & 63;
  if (wid >= NBATCH) return;
  float v = g2[(long)wid * 64 + lane] * linW[lane];
  for (int o = 32; o > 0; o >>= 1) v += __shfl_down(v, o, 64);
  if (lane == 0) out[wid] = v + linb[0];
}

__global__ __launch_bounds__(256) void k_zero_out(float* out, int n) {
  for (int i = blockIdx.x * 256 + threadIdx.x; i < n; i += gridDim.x * 256) out[i] = 0.f;
}

// ---------------- launcher ----------------

extern "C" void kernel_launch(void* const* d_in, const int* in_sizes, int n_in,
                              void* d_out, int out_size, void* d_ws, size_t ws_size,
                              hipStream_t stream) {
  (void)in_sizes; (void)n_in;

  const int* x_atom = (const int*)d_in[0];
  const int* vals[5] = {(const int*)d_in[1], (const int*)d_in[4], (const int*)d_in[7],
                        (const int*)d_in[10], (const int*)d_in[13]};
  const int* rowm[5] = {(const int*)d_in[2], (const int*)d_in[5], (const int*)d_in[8],
                        (const int*)d_in[11], (const int*)d_in[14]};
  const int* batch = (const int*)d_in[16];
  const float* aemb0 = (const float*)d_in[17];
  const float* aemb1 = (const float*)d_in[18];
  const float* aemb2 = (const float*)d_in[19];
  const float* path_emb = (const float*)d_in[20];
  const float* cycle_emb = (const float*)d_in[21];
  const float* pW_a2p = (const float*)d_in[22];
  const float* pb_a2p = (const float*)d_in[23];
  const float* pW_p2a = (const float*)d_in[24];
  const float* pb_p2a = (const float*)d_in[25];
  const float* pK = (const float*)d_in[26];
  const float* pKb = (const float*)d_in[27];
  const float* cW_a2p = (const float*)d_in[28];
  const float* cb_a2p = (const float*)d_in[29];
  const float* cW_p2a = (const float*)d_in[30];
  const float* cb_p2a = (const float*)d_in[31];
  const float* cK = (const float*)d_in[32];
  const float* cKb = (const float*)d_in[33];
  const float* alW = (const float*)d_in[34];
  const float* alb = (const float*)d_in[35];
  const float* linW = (const float*)d_in[36];
  const float* linb = (const float*)d_in[37];

  static const int Em[5] = {300000, 400000, 500000, 200000, 240000};
  static const int Km[5] = {3, 4, 5, 5, 6};
  static const int Ppb[5] = {32, 24, 16, 16, 16};  // paths/block -> R in {96,96,80,80,96}
  const int CNT_N = 5 * 100000 + NBATCH;  // 504096
  const int BUCKET_N = 1640000 + 100000;  // 1740000

  char* ws = (char*)d_ws;
  size_t off = 0;
  auto alloc = [&](size_t nbytes) -> char* {
    char* p = ws + off;
    off = (off + nbytes + 255) & ~(size_t)255;
    return p;
  };
  float* x = (float*)alloc((size_t)NA * 64 * 4);
  __half* xp[5];
  for (int m = 0; m < 5; m++) xp[m] = (__half*)alloc((size_t)Em[m] * 64 * 2);
  float* g1 = (float*)alloc((size_t)NBATCH * 64 * 4);
  float* g2 = (float*)alloc((size_t)NBATCH * 64 * 4);
  int* cnt = (int*)alloc((size_t)CNT_N * 4);
  int* basea = (int*)alloc((size_t)CNT_N * 4);
  int* cursor = (int*)alloc((size_t)CNT_N * 4);
  int2* bucket = (int2*)alloc((size_t)BUCKET_N * 8);
  int* bsums = (int*)alloc(256 * 4);
  f16* Bp = (f16*)alloc((size_t)10 * 12288 * 2);  // prepacked conv kernels
  f16* Wp2a = (f16*)alloc((size_t)10 * 4096 * 2); // prepacked p2a weights

  if (ws_size < off) {  // workspace too small: emit readable failure, not a fault
    k_zero_out<<<16, 256, 0, stream>>>((float*)d_out, out_size);
    return;
  }

  // ---- CSR build
  MapsParams mp;
  {
    int s = 0;
    for (int m = 0; m < 5; m++) {
      mp.row[m] = rowm[m]; mp.cnt_off[m] = m * 100000;
      mp.start[m] = s; s += Em[m];
    }
    mp.row[5] = batch; mp.cnt_off[5] = 500000; mp.start[5] = s;
    mp.total = s + NA;
  }
  hipMemsetAsync(cnt, 0, (size_t)CNT_N * 4, stream);
  k_count<<<2048, 256, 0, stream>>>(mp, cnt);
  int nbScan = (CNT_N + 2047) / 2048;  // 247
  k_scanA<<<nbScan, 256, 0, stream>>>(cnt, basea, bsums, CNT_N);
  k_scanB<<<1, 256, 0, stream>>>(bsums, nbScan);
  k_scanC<<<nbScan, 256, 0, stream>>>(basea, bsums, CNT_N);
  hipMemcpyAsync(cursor, basea, (size_t)CNT_N * 4, hipMemcpyDeviceToDevice, stream);
  k_fill<<<2048, 256, 0, stream>>>(mp, cursor, bucket);

  // ---- prepack weights + feature init
  k_prepB<<<480, 256, 0, stream>>>(pK, cK, Bp);
  k_prepW<<<160, 256, 0, stream>>>(pW_p2a, cW_p2a, Wp2a);
  k_atom_init<<<NA * 16 / 256, 256, 0, stream>>>(x_atom, aemb0, aemb1, aemb2, x);
  {
    PInit pp;
    int s8 = 0;
    for (int m = 0; m < 5; m++) {
      pp.dst[m] = xp[m];
      pp.vals[m] = vals[m];
      pp.tab[m] = (m < 3) ? (path_emb + m * 6 * 64) : (cycle_emb + (m - 3) * 4 * 64);
      pp.start8[m] = s8;
      s8 += Em[m] * 8;
    }
    pp.total8 = s8;
    k_path_init<<<8192, 256, 0, stream>>>(pp);
  }

  int p2a_blocks = (NA + 63) / 64;  // 1563

  // ---- layers
  for (int l = 0; l < 2; l++) {
    // === paths group (maps 0..2), non-cyclic
    {
      A2pParams gp{};
      gp.nseg = 3; gp.x = x;
      int bs = 0;
      for (int m = 0; m < 3; m++) {
        gp.gidx[m] = rowm[m]; gp.out[m] = xp[m];
        gp.W[m] = pW_a2p + (l * 3 + m) * 4096;
        gp.bias[m] = pb_a2p + (l * 3 + m) * 64;
        gp.blk_start[m] = bs;
        bs += Em[m] / 32;
      }
      k_a2p<<<bs, 256, 0, stream>>>(gp);

      ConvParams cp{};
      cp.nseg = 3; cp.cyclic = 0;
      int cbs = 0;
      for (int m = 0; m < 3; m++) {
        cp.buf[m] = (f16*)xp[m];
        cp.Bp[m] = Bp + (size_t)(l * 3 + m) * 12288;
        cp.Kb[m] = pKb + (l * 3 + m) * 64;
        cp.k[m] = Km[m]; cp.P[m] = Em[m] / Km[m]; cp.ppb[m] = Ppb[m];
        cp.blk_start[m] = cbs;
        cbs += (cp.P[m] + cp.ppb[m] - 1) / cp.ppb[m];
      }
      k_conv<<<cbs, 256, 0, stream>>>(cp);

      P2aParams bp{};
      bp.x = x; bp.bucket = bucket; bp.basea = basea; bp.nmaps = 3;
      for (int m = 0; m < 3; m++) {
        bp.xp[m] = (const f16*)xp[m];
        bp.off[m] = m * 100000;
        bp.Wp[m] = Wp2a + (size_t)(l * 3 + m) * 4096;
        bp.bias[m] = pb_p2a + (l * 3 + m) * 64;
      }
      k_p2a<<<p2a_blocks, 256, 0, stream>>>(bp);
    }
    // === cycles group (maps 3..4), cyclic
    {
      A2pParams gp{};
      gp.nseg = 2; gp.x = x;
      int bs = 0;
      for (int m = 3; m < 5; m++) {
        int i = m - 3;
        gp.gidx[i] = rowm[m]; gp.out[i] = xp[m];
        gp.W[i] = cW_a2p + (l * 2 + i) * 4096;
        gp.bias[i] = cb_a2p + (l * 2 + i) * 64;
        gp.blk_start[i] = bs;
        bs += Em[m] / 32;
      }
      k_a2p<<<bs, 256, 0, stream>>>(gp);

      ConvParams cp{};
      cp.nseg = 2; cp.cyclic = 1;
      int cbs = 0;
      for (int m = 3; m < 5; m++) {
        int i = m - 3;
        cp.buf[i] = (f16*)xp[m];
        cp.Bp[i] = Bp + (size_t)(6 + l * 2 + i) * 12288;
        cp.Kb[i] = cKb + (l * 2 + i) * 64;
        cp.k[i] = Km[m]; cp.P[i] = Em[m] / Km[m]; cp.ppb[i] = Ppb[m];
        cp.blk_start[i] = cbs;
        cbs += (cp.P[i] + cp.ppb[i] - 1) / cp.ppb[i];
      }
      k_conv<<<cbs, 256, 0, stream>>>(cp);

      P2aParams bp{};
      bp.x = x; bp.bucket = bucket; bp.basea = basea; bp.nmaps = 2;
      for (int m = 3; m < 5; m++) {
        int i = m - 3;
        bp.xp[i] = (const f16*)xp[m];
        bp.off[i] = m * 100000;
        bp.Wp[i] = Wp2a + (size_t)(6 + l * 2 + i) * 4096;
        bp.bias[i] = cb_p2a + (l * 2 + i) * 64;
      }
      k_p2a<<<p2a_blocks, 256, 0, stream>>>(bp);
    }
  }

  // ---- head
  k_meanscatter<<<NBATCH / 4, 256, 0, stream>>>(x, bucket, basea + 500000, cnt + 500000,
                                                g1, NBATCH);
  k_head<<<NBATCH / 32, 256, 0, stream>>>(g1, alW, alb, g2);
  k_final<<<NBATCH / 4, 256, 0, stream>>>(g2, linW, linb, (float*)d_out);
}

// Round 6
// 2553.759 us; speedup vs baseline: 1.1954x; 1.1951x over previous
//
#include <hip/hip_runtime.h>
#include <hip/hip_fp16.h>

#define NA 100000
#define NBATCH 4096
#define MLD 68

typedef _Float16 f16;
typedef f16 half8 __attribute__((ext_vector_type(8)));
typedef float f32x4 __attribute__((ext_vector_type(4)));
union H8 { uint4 u; __half h[8]; };
union HU { uint4 u; half8 h; };

// ---------------- counts (all 5 maps + batch) ----------------

struct MapsParams {
  const int* row[6];
  int cnt_off[6];
  int start[6];
  int total;
};

__global__ __launch_bounds__(256) void k_count(MapsParams mp, int* cnt) {
  for (int g = blockIdx.x * 256 + threadIdx.x; g < mp.total; g += gridDim.x * 256) {
    int m = 0;
#pragma unroll
    for (int i = 1; i < 6; i++) if (g >= mp.start[i]) m = i;
    int e = g - mp.start[m];
    atomicAdd(&cnt[mp.cnt_off[m] + mp.row[m][e]], 1);
  }
}

// single-block exclusive scan of the 4096 batch counts
__global__ __launch_bounds__(256) void k_scan_batch(const int* cntb, int* basea) {
  __shared__ int s[256];
  int t = threadIdx.x;
  int carry = 0;
  for (int c0 = 0; c0 < NBATCH; c0 += 256) {
    int v = cntb[c0 + t];
    s[t] = v;
    __syncthreads();
    for (int d = 1; d < 256; d <<= 1) {
      int x = (t >= d) ? s[t - d] : 0;
      __syncthreads();
      s[t] += x;
      __syncthreads();
    }
    basea[c0 + t] = s[t] - v + carry;
    int tot = s[255];
    __syncthreads();
    carry += tot;
  }
}

__global__ __launch_bounds__(256) void k_fill_batch(const int* batch, int* cursor, int* bucket) {
  for (int a = blockIdx.x * 256 + threadIdx.x; a < NA; a += gridDim.x * 256) {
    int b = batch[a];
    int pos = atomicAdd(&cursor[b], 1);
    bucket[pos] = a;
  }
}

// ---------------- feature init ----------------

__global__ __launch_bounds__(256) void k_atom_init(const int* xa, const float* e0,
                                                   const float* e1, const float* e2, float* x) {
  int idx = blockIdx.x * 256 + threadIdx.x;  // float4 index
  if (idx >= NA * 16) return;
  int a = idx >> 4, q = idx & 15;
  int f0 = xa[a * 3], f1 = xa[a * 3 + 1], f2 = xa[a * 3 + 2];
  float4 v0 = ((const float4*)e0)[f0 * 16 + q];
  float4 v1 = ((const float4*)e1)[f1 * 16 + q];
  float4 v2 = ((const float4*)e2)[f2 * 16 + q];
  float4 o;
  o.x = v0.x + v1.x + v2.x; o.y = v0.y + v1.y + v2.y;
  o.z = v0.z + v1.z + v2.z; o.w = v0.w + v1.w + v2.w;
  ((float4*)x)[idx] = o;
}

struct PInit {
  __half* dst[5];
  const int* vals[5];
  const float* tab[5];
  int start8[5];  // cumulative half8-chunk starts
  int total8;
};

__global__ __launch_bounds__(256) void k_path_init(PInit pp) {
  for (int g = blockIdx.x * 256 + threadIdx.x; g < pp.total8; g += gridDim.x * 256) {
    int m = 0;
#pragma unroll
    for (int i = 1; i < 5; i++) if (g >= pp.start8[i]) m = i;
    int lc = g - pp.start8[m];
    int e = lc >> 3, q = lc & 7;
    int v = pp.vals[m][e];
    const float* src = pp.tab[m] + v * 64 + q * 8;
    H8 o;
#pragma unroll
    for (int j = 0; j < 8; j++) o.h[j] = __float2half(src[j]);
    ((uint4*)pp.dst[m])[lc] = o.u;
  }
}

// ---------------- prepack conv kernels to fp16 MFMA-B layout ----------------

__global__ __launch_bounds__(256) void k_prepB(const float* pK, const float* cK, f16* Bp) {
  int tid = blockIdx.x * 256 + threadIdx.x;
  if (tid >= 10 * 12288) return;
  int set = tid / 12288, pos = tid % 12288;
  int j = pos & 7, lane = (pos >> 3) & 63, kcnt = pos >> 9;
  int kc = kcnt % 6, nt = kcnt / 6;
  int k = kc * 32 + ((lane >> 4) << 3) + j;
  int n = (nt << 4) + (lane & 15);
  int w = k >> 6, ji = k & 63;
  const float* K = (set < 6) ? (pK + set * 3 * 4096) : (cK + (set - 6) * 3 * 4096);
  float v = K[w * 4096 + ji * 64 + n];
  if (set >= 6) v = 0.5f * (v + K[(2 - w) * 4096 + ji * 64 + n]);
  Bp[tid] = (f16)v;
}

// ---------------- prepack p2a weights to fp16 MFMA-B layout (64x64) ----------------

__global__ __launch_bounds__(256) void k_prepW(const float* pW, const float* cW, f16* Wp) {
  int tid = blockIdx.x * 256 + threadIdx.x;
  if (tid >= 10 * 4096) return;
  int set = tid >> 12, pos = tid & 4095;
  int j = pos & 7, lane = (pos >> 3) & 63, ntkc = pos >> 9;
  int kc = ntkc & 1, nt = ntkc >> 1;
  int k = kc * 32 + ((lane >> 4) << 3) + j;
  int n = (nt << 4) + (lane & 15);
  const float* W = (set < 6) ? (pW + set * 4096) : (cW + (set - 6) * 4096);
  Wp[tid] = (f16)W[k * 64 + n];
}

// ---------------- a2p: xp = xp + relu(gather(x) @ W + b), fp16 out ----------------

struct A2pParams {
  const float* x;
  const int* gidx[3];
  __half* out[3];
  const float* W[3];
  const float* bias[3];
  int blk_start[3];
  int nseg;
};

__global__ __launch_bounds__(256) void k_a2p(A2pParams p) {
  __shared__ float Wl[4096];
  __shared__ float inl[32 * 64];
  __shared__ float bl[64];
  __shared__ int ridx[32];
  int bid = blockIdx.x;
  int seg = 0;
#pragma unroll
  for (int i = 1; i < 3; i++) if (i < p.nseg && bid >= p.blk_start[i]) seg = i;
  int brow = (bid - p.blk_start[seg]) * 32;  // all E divisible by 32: no tail
  int t = threadIdx.x;
#pragma unroll
  for (int i = 0; i < 4; i++)
    ((float4*)Wl)[t + 256 * i] = ((const float4*)p.W[seg])[t + 256 * i];
  if (t < 64) bl[t] = p.bias[seg][t];
  if (t < 32) ridx[t] = p.gidx[seg][brow + t];
  __syncthreads();
#pragma unroll
  for (int i = 0; i < 2; i++) {
    int idx = t + 256 * i;
    int r = idx >> 4, q = idx & 15;
    ((float4*)inl)[idx] = ((const float4*)(p.x + (long)ridx[r] * 64))[q];
  }
  __syncthreads();
  int c = t & 63, rq = t >> 6;
  float acc[8];
#pragma unroll
  for (int i = 0; i < 8; i++) acc[i] = 0.f;
  for (int j = 0; j < 64; j += 4) {
    float w0 = Wl[(j + 0) * 64 + c], w1 = Wl[(j + 1) * 64 + c];
    float w2 = Wl[(j + 2) * 64 + c], w3 = Wl[(j + 3) * 64 + c];
#pragma unroll
    for (int i = 0; i < 8; i++) {
      int r = rq * 8 + i;
      float4 v = *(const float4*)&inl[r * 64 + j];
      acc[i] += v.x * w0 + v.y * w1 + v.z * w2 + v.w * w3;
    }
  }
  float bv = bl[c];
  __half* out = p.out[seg];
#pragma unroll
  for (int i = 0; i < 8; i++) {
    long e = brow + rq * 8 + i;
    float v = acc[i] + bv;
    v = v > 0.f ? v : 0.f;
    float r32 = __half2float(out[e * 64 + c]);
    out[e * 64 + c] = __float2half(r32 + v);
  }
}

// ---------------- MFMA conv: buf = pre + relu([Rx192]@[192x64] + Kb) ----------------

struct ConvParams {
  f16* buf[3];
  const f16* Bp[3];
  const float* Kb[3];
  int k[3];
  int P[3];
  int ppb[3];
  int blk_start[3];
  int nseg;
  int cyclic;
};

__global__ __launch_bounds__(256) void k_conv(ConvParams p) {
  __shared__ uint4 Apk[2304];  // up to 6 m-tiles * 6 kc * 64 lanes * 16B = 36864B
  __shared__ uint4 Bpk[1536];  // 4 nt * 6 kc * 64 * 16B = 24576B
  __shared__ float kbl[64];
  int bid = blockIdx.x;
  int seg = 0;
#pragma unroll
  for (int i = 1; i < 3; i++) if (i < p.nseg && bid >= p.blk_start[i]) seg = i;
  int kk = p.k[seg], ppb = p.ppb[seg], P = p.P[seg];
  f16* buf = p.buf[seg];
  int t = threadIdx.x;
  int p0 = (bid - p.blk_start[seg]) * ppb;
  int np = min(ppb, P - p0);
  int R = np * kk;       // always a multiple of 16 for our ppb choices
  int mtb = R >> 4;      // m-tiles: 4..6
  long ebase = (long)p0 * kk;
  {
    const uint4* bs = (const uint4*)p.Bp[seg];
    for (int i = t; i < 1536; i += 256) Bpk[i] = bs[i];
  }
  if (t < 64) kbl[t] = p.Kb[seg][t];
  {
    uint4 z; z.x = z.y = z.z = z.w = 0;
    int nU = mtb * 384;
    for (int i = t; i < nU; i += 256) Apk[i] = z;
  }
  __syncthreads();
  {
    const uint4* src = (const uint4*)(buf + ebase * 64);
    int tot = R * 8;
    for (int idx = t; idx < tot; idx += 256) {
      int r = idx >> 3, jj = idx & 7;
      uint4 ch = src[idx];
      int s = r % kk;
      int kchi = jj >> 2, quad = jj & 3;
#pragma unroll
      for (int w = 0; w < 3; w++) {
        int rd;
        if (w == 1) rd = r;
        else if (w == 0) rd = (s + 1 < kk) ? r + 1 : (p.cyclic ? r + 1 - kk : -1);
        else rd = (s >= 1) ? r - 1 : (p.cyclic ? r + kk - 1 : -1);
        if (rd >= 0)
          Apk[((rd >> 4) * 6 + 2 * w + kchi) * 64 + quad * 16 + (rd & 15)] = ch;
      }
    }
  }
  __syncthreads();
  int lane = t & 63, wid = t >> 6;
  int wave_n = wid & 1, wave_m = wid >> 1;
  int mtA = (mtb + 1) >> 1;
  int m0 = wave_m ? mtA : 0;
  int mcnt = wave_m ? (mtb - mtA) : mtA;  // <= 3
  f32x4 acc[3][2];
#pragma unroll
  for (int i = 0; i < 3; i++)
#pragma unroll
    for (int jn = 0; jn < 2; jn++) {
      f32x4 z = {0.f, 0.f, 0.f, 0.f};
      acc[i][jn] = z;
    }
  for (int kc = 0; kc < 6; kc++) {
    HU a[3], b[2];
#pragma unroll
    for (int jn = 0; jn < 2; jn++)
      b[jn].u = Bpk[((wave_n * 2 + jn) * 6 + kc) * 64 + lane];
#pragma unroll
    for (int i = 0; i < 3; i++)
      if (i < mcnt) a[i].u = Apk[((m0 + i) * 6 + kc) * 64 + lane];
#pragma unroll
    for (int i = 0; i < 3; i++)
      if (i < mcnt) {
#pragma unroll
        for (int jn = 0; jn < 2; jn++)
          acc[i][jn] = __builtin_amdgcn_mfma_f32_16x16x32_f16(a[i].h, b[jn].h, acc[i][jn], 0, 0, 0);
      }
  }
  const f16* Ah = (const f16*)Apk;
#pragma unroll
  for (int i = 0; i < 3; i++) {
    if (i >= mcnt) continue;
    int mt = m0 + i;
#pragma unroll
    for (int jn = 0; jn < 2; jn++) {
      int n = (wave_n * 2 + jn) * 16 + (lane & 15);
      int kcr = 2 + (n >> 5), quadb = (n & 31) >> 3, jr = n & 7;
#pragma unroll
      for (int reg = 0; reg < 4; reg++) {
        int r = mt * 16 + ((lane >> 4) << 2) + reg;
        float pre = (float)Ah[(((mt * 6 + kcr) * 64 + quadb * 16 + (r & 15)) << 3) + jr];
        float v = acc[i][jn][reg] + kbl[n];
        v = v > 0.f ? v : 0.f;
        buf[(ebase + r) * 64 + n] = (f16)(pre + v);
      }
    }
  }
}

// ---------------- p2a scatter: acc[row[e]] += xp[e] (fp32 global atomics) ----------------
// Wave handles 4 edges/iter: sequential coalesced xp reads, fire-and-forget atomics.

__global__ __launch_bounds__(256) void k_scatter(const f16* xp, const int* row,
                                                 float* acc, int E) {
  int gw = (blockIdx.x * 256 + threadIdx.x) >> 6;
  int lane = threadIdx.x & 63;
  int nw = (gridDim.x * 256) >> 6;
  for (int e0 = gw * 4; e0 < E; e0 += nw * 4) {
    int4 a4 = ((const int4*)row)[e0 >> 2];   // broadcast: 4 atom ids
    float v[4];
#pragma unroll
    for (int u = 0; u < 4; u++) v[u] = (float)xp[(long)(e0 + u) * 64 + lane];
    atomicAdd(&acc[(long)a4.x * 64 + lane], v[0]);
    atomicAdd(&acc[(long)a4.y * 64 + lane], v[1]);
    atomicAdd(&acc[(long)a4.z * 64 + lane], v[2]);
    atomicAdd(&acc[(long)a4.w * 64 + lane], v[3]);
  }
}

// ---------------- p2a apply: x += relu(acc/cnt @ W + b); self-zeroes acc ----------------

__global__ __launch_bounds__(256) void k_apply(float* acc, const int* cnt, const f16* Wp,
                                               const float* bias, float* x) {
  __shared__ float mean[64 * MLD];  // 17.4KB
  __shared__ uint4 Af[512];         // 8KB fp16 A-frags
  __shared__ float invl[64];
  __shared__ float bl[64];
  int t = threadIdx.x;
  int a0 = blockIdx.x * 64;
  if (t < 64) {
    int cb = cnt[a0 + t];
    invl[t] = 1.f / (float)(cb > 0 ? cb : 1);
    bl[t] = bias[t];
  }
  float4* acc4 = (float4*)acc;
#pragma unroll
  for (int i = 0; i < 4; i++) {
    int idx = t + 256 * i;
    int r = idx >> 4, q = idx & 15;
    float4 v = acc4[a0 * 16 + idx];
    float4 z4 = {0.f, 0.f, 0.f, 0.f};
    acc4[a0 * 16 + idx] = z4;  // ready for next map (each elem touched by exactly this thread)
    *(float4*)&mean[r * MLD + q * 4] = v;
  }
  __syncthreads();
#pragma unroll
  for (int i = 0; i < 2; i++) {
    int la = (t >> 3) + 32 * i;
    int g = t & 7;
    float inv = invl[la];
    const float* mr = &mean[la * MLD + g * 8];
    HU o;
#pragma unroll
    for (int j = 0; j < 8; j++) o.h[j] = (f16)(mr[j] * inv);
    int kc = g >> 2, lb = ((g & 3) << 4) + (la & 15), mtt = la >> 4;
    Af[(((mtt << 1) + kc) << 6) + lb] = o.u;
  }
  __syncthreads();
  int lane = t & 63, wid = t >> 6;
  HU af0, af1;
  af0.u = Af[((wid << 1) + 0) * 64 + lane];
  af1.u = Af[((wid << 1) + 1) * 64 + lane];
  const uint4* Wu = (const uint4*)Wp;
  int rowb = a0 + wid * 16 + ((lane >> 4) << 2);
#pragma unroll
  for (int nt = 0; nt < 4; nt++) {
    HU b0, b1;
    b0.u = Wu[((nt << 1) + 0) * 64 + lane];
    b1.u = Wu[((nt << 1) + 1) * 64 + lane];
    f32x4 z = {0.f, 0.f, 0.f, 0.f};
    z = __builtin_amdgcn_mfma_f32_16x16x32_f16(af0.h, b0.h, z, 0, 0, 0);
    z = __builtin_amdgcn_mfma_f32_16x16x32_f16(af1.h, b1.h, z, 0, 0, 0);
    int n = nt * 16 + (lane & 15);
    float bv = bl[n];
#pragma unroll
    for (int r = 0; r < 4; r++) {
      int atom = rowb + r;
      if (atom < NA) {
        float vv = z[r] + bv;
        vv = vv > 0.f ? vv : 0.f;
        x[(long)atom * 64 + n] += vv;
      }
    }
  }
}

// ---------------- batch mean: g1[b] = mean(x[a]) over CSR bucket ----------------

__global__ __launch_bounds__(256) void k_meanscatter(const float* src, const int* bucket,
                                                     const int* basea, const int* cnta,
                                                     float* dst, int nseg) {
  int wid = (blockIdx.x * 256 + threadIdx.x) >> 6;
  int lane = threadIdx.x & 63;
  if (wid >= nseg) return;
  int b0 = basea[wid], cnt = cnta[wid];
  float s = 0.f;
  for (int i = 0; i < cnt; i++) {
    int e = bucket[b0 + i];
    s += src[(long)e * 64 + lane];
  }
  dst[(long)wid * 64 + lane] = s / (float)(cnt > 0 ? cnt : 1);
}

// ---------------- head gemm: g2 = relu(g1 @ W + b) ----------------

__global__ __launch_bounds__(256) void k_head(const float* g1, const float* W,
                                              const float* bias, float* g2) {
  __shared__ float Wl[4096];
  __shared__ float inl[32 * 64];
  __shared__ float bl[64];
  int t = threadIdx.x;
  int brow = blockIdx.x * 32;
#pragma unroll
  for (int i = 0; i < 4; i++) ((float4*)Wl)[t + 256 * i] = ((const float4*)W)[t + 256 * i];
  if (t < 64) bl[t] = bias[t];
  __syncthreads();
#pragma unroll
  for (int i = 0; i < 2; i++) {
    int idx = t + 256 * i;
    int r = idx >> 4, q = idx & 15;
    ((float4*)inl)[idx] = ((const float4*)(g1 + (long)(brow + r) * 64))[q];
  }
  __syncthreads();
  int c = t & 63, rq = t >> 6;
  float acc[8];
#pragma unroll
  for (int i = 0; i < 8; i++) acc[i] = 0.f;
  for (int j = 0; j < 64; j += 4) {
    float w0 = Wl[(j + 0) * 64 + c], w1 = Wl[(j + 1) * 64 + c];
    float w2 = Wl[(j + 2) * 64 + c], w3 = Wl[(j + 3) * 64 + c];
#pragma unroll
    for (int i = 0; i < 8; i++) {
      int r = rq * 8 + i;
      float4 v = *(const float4*)&inl[r * 64 + j];
      acc[i] += v.x * w0 + v.y * w1 + v.z * w2 + v.w * w3;
    }
  }
#pragma unroll
  for (int i = 0; i < 8; i++) {
    long r = brow + rq * 8 + i;
    float v = acc[i] + bl[c];
    g2[r * 64 + c] = v > 0.f ? v : 0.f;
  }
}

__global__ __launch_bounds__(256) void k_final(const float* g2, const float* linW,
                                               const float* linb, float* out) {
  int wid = (blockIdx.x * 256 + threadIdx.x) >> 6;
  int lane = threadIdx.x & 63;
  if (wid >= NBATCH) return;
  float v = g2[(long)wid * 64 + lane] * linW[lane];
  for (int o = 32; o > 0; o >>= 1) v += __shfl_down(v, o, 64);
  if (lane == 0) out[wid] = v + linb[0];
}

__global__ __launch_bounds__(256) void k_zero_out(float* out, int n) {
  for (int i = blockIdx.x * 256 + threadIdx.x; i < n; i += gridDim.x * 256) out[i] = 0.f;
}

// ---------------- launcher ----------------

extern "C" void kernel_launch(void* const* d_in, const int* in_sizes, int n_in,
                              void* d_out, int out_size, void* d_ws, size_t ws_size,
                              hipStream_t stream) {
  (void)in_sizes; (void)n_in;

  const int* x_atom = (const int*)d_in[0];
  const int* vals[5] = {(const int*)d_in[1], (const int*)d_in[4], (const int*)d_in[7],
                        (const int*)d_in[10], (const int*)d_in[13]};
  const int* rowm[5] = {(const int*)d_in[2], (const int*)d_in[5], (const int*)d_in[8],
                        (const int*)d_in[11], (const int*)d_in[14]};
  const int* batch = (const int*)d_in[16];
  const float* aemb0 = (const float*)d_in[17];
  const float* aemb1 = (const float*)d_in[18];
  const float* aemb2 = (const float*)d_in[19];
  const float* path_emb = (const float*)d_in[20];
  const float* cycle_emb = (const float*)d_in[21];
  const float* pW_a2p = (const float*)d_in[22];
  const float* pb_a2p = (const float*)d_in[23];
  const float* pW_p2a = (const float*)d_in[24];
  const float* pb_p2a = (const float*)d_in[25];
  const float* pK = (const float*)d_in[26];
  const float* pKb = (const float*)d_in[27];
  const float* cW_a2p = (const float*)d_in[28];
  const float* cb_a2p = (const float*)d_in[29];
  const float* cW_p2a = (const float*)d_in[30];
  const float* cb_p2a = (const float*)d_in[31];
  const float* cK = (const float*)d_in[32];
  const float* cKb = (const float*)d_in[33];
  const float* alW = (const float*)d_in[34];
  const float* alb = (const float*)d_in[35];
  const float* linW = (const float*)d_in[36];
  const float* linb = (const float*)d_in[37];

  static const int Em[5] = {300000, 400000, 500000, 200000, 240000};
  static const int Km[5] = {3, 4, 5, 5, 6};
  static const int Ppb[5] = {32, 24, 16, 16, 16};  // paths/block -> R in {96,96,80,80,96}
  const int CNT_N = 5 * 100000 + NBATCH;  // 504096
  const int ACC_ROWS = 100032;            // padded to block grid (1563*64)

  char* ws = (char*)d_ws;
  size_t off = 0;
  auto alloc = [&](size_t nbytes) -> char* {
    char* p = ws + off;
    off = (off + nbytes + 255) & ~(size_t)255;
    return p;
  };
  float* x = (float*)alloc((size_t)NA * 64 * 4);
  __half* xp[5];
  for (int m = 0; m < 5; m++) xp[m] = (__half*)alloc((size_t)Em[m] * 64 * 2);
  float* acc = (float*)alloc((size_t)ACC_ROWS * 64 * 4);
  float* g1 = (float*)alloc((size_t)NBATCH * 64 * 4);
  float* g2 = (float*)alloc((size_t)NBATCH * 64 * 4);
  int* cnt = (int*)alloc((size_t)CNT_N * 4);
  int* basea_b = (int*)alloc((size_t)(NBATCH + 1) * 4);
  int* cursor_b = (int*)alloc((size_t)NBATCH * 4);
  int* bucket = (int*)alloc((size_t)NA * 4);
  f16* Bp = (f16*)alloc((size_t)10 * 12288 * 2);  // prepacked conv kernels
  f16* Wp2a = (f16*)alloc((size_t)10 * 4096 * 2); // prepacked p2a weights

  if (ws_size < off) {  // workspace too small: emit readable failure, not a fault
    k_zero_out<<<16, 256, 0, stream>>>((float*)d_out, out_size);
    return;
  }

  // ---- counts (all maps + batch) and batch CSR
  MapsParams mp;
  {
    int s = 0;
    for (int m = 0; m < 5; m++) {
      mp.row[m] = rowm[m]; mp.cnt_off[m] = m * 100000;
      mp.start[m] = s; s += Em[m];
    }
    mp.row[5] = batch; mp.cnt_off[5] = 500000; mp.start[5] = s;
    mp.total = s + NA;
  }
  hipMemsetAsync(cnt, 0, (size_t)CNT_N * 4, stream);
  hipMemsetAsync(acc, 0, (size_t)ACC_ROWS * 64 * 4, stream);
  k_count<<<2048, 256, 0, stream>>>(mp, cnt);
  k_scan_batch<<<1, 256, 0, stream>>>(cnt + 500000, basea_b);
  hipMemcpyAsync(cursor_b, basea_b, (size_t)NBATCH * 4, hipMemcpyDeviceToDevice, stream);
  k_fill_batch<<<128, 256, 0, stream>>>(batch, cursor_b, bucket);

  // ---- prepack weights + feature init
  k_prepB<<<480, 256, 0, stream>>>(pK, cK, Bp);
  k_prepW<<<160, 256, 0, stream>>>(pW_p2a, cW_p2a, Wp2a);
  k_atom_init<<<NA * 16 / 256, 256, 0, stream>>>(x_atom, aemb0, aemb1, aemb2, x);
  {
    PInit pp;
    int s8 = 0;
    for (int m = 0; m < 5; m++) {
      pp.dst[m] = xp[m];
      pp.vals[m] = vals[m];
      pp.tab[m] = (m < 3) ? (path_emb + m * 6 * 64) : (cycle_emb + (m - 3) * 4 * 64);
      pp.start8[m] = s8;
      s8 += Em[m] * 8;
    }
    pp.total8 = s8;
    k_path_init<<<8192, 256, 0, stream>>>(pp);
  }

  int apply_blocks = ACC_ROWS / 64;  // 1563

  // ---- layers
  for (int l = 0; l < 2; l++) {
    // === paths group (maps 0..2), non-cyclic
    {
      A2pParams gp{};
      gp.nseg = 3; gp.x = x;
      int bs = 0;
      for (int m = 0; m < 3; m++) {
        gp.gidx[m] = rowm[m]; gp.out[m] = xp[m];
        gp.W[m] = pW_a2p + (l * 3 + m) * 4096;
        gp.bias[m] = pb_a2p + (l * 3 + m) * 64;
        gp.blk_start[m] = bs;
        bs += Em[m] / 32;
      }
      k_a2p<<<bs, 256, 0, stream>>>(gp);

      ConvParams cp{};
      cp.nseg = 3; cp.cyclic = 0;
      int cbs = 0;
      for (int m = 0; m < 3; m++) {
        cp.buf[m] = (f16*)xp[m];
        cp.Bp[m] = Bp + (size_t)(l * 3 + m) * 12288;
        cp.Kb[m] = pKb + (l * 3 + m) * 64;
        cp.k[m] = Km[m]; cp.P[m] = Em[m] / Km[m]; cp.ppb[m] = Ppb[m];
        cp.blk_start[m] = cbs;
        cbs += (cp.P[m] + cp.ppb[m] - 1) / cp.ppb[m];
      }
      k_conv<<<cbs, 256, 0, stream>>>(cp);

      for (int m = 0; m < 3; m++) {
        k_scatter<<<1024, 256, 0, stream>>>((const f16*)xp[m], rowm[m], acc, Em[m]);
        k_apply<<<apply_blocks, 256, 0, stream>>>(acc, cnt + m * 100000,
                                                  Wp2a + (size_t)(l * 3 + m) * 4096,
                                                  pb_p2a + (l * 3 + m) * 64, x);
      }
    }
    // === cycles group (maps 3..4), cyclic
    {
      A2pParams gp{};
      gp.nseg = 2; gp.x = x;
      int bs = 0;
      for (int m = 3; m < 5; m++) {
        int i = m - 3;
        gp.gidx[i] = rowm[m]; gp.out[i] = xp[m];
        gp.W[i] = cW_a2p + (l * 2 + i) * 4096;
        gp.bias[i] = cb_a2p + (l * 2 + i) * 64;
        gp.blk_start[i] = bs;
        bs += Em[m] / 32;
      }
      k_a2p<<<bs, 256, 0, stream>>>(gp);

      ConvParams cp{};
      cp.nseg = 2; cp.cyclic = 1;
      int cbs = 0;
      for (int m = 3; m < 5; m++) {
        int i = m - 3;
        cp.buf[i] = (f16*)xp[m];
        cp.Bp[i] = Bp + (size_t)(6 + l * 2 + i) * 12288;
        cp.Kb[i] = cKb + (l * 2 + i) * 64;
        cp.k[i] = Km[m]; cp.P[i] = Em[m] / Km[m]; cp.ppb[i] = Ppb[m];
        cp.blk_start[i] = cbs;
        cbs += (cp.P[i] + cp.ppb[i] - 1) / cp.ppb[i];
      }
      k_conv<<<cbs, 256, 0, stream>>>(cp);

      for (int m = 3; m < 5; m++) {
        int i = m - 3;
        k_scatter<<<1024, 256, 0, stream>>>((const f16*)xp[m], rowm[m], acc, Em[m]);
        k_apply<<<apply_blocks, 256, 0, stream>>>(acc, cnt + m * 100000,
                                                  Wp2a + (size_t)(6 + l * 2 + i) * 4096,
                                                  cb_p2a + (l * 2 + i) * 64, x);
      }
    }
  }

  // ---- head
  k_meanscatter<<<NBATCH / 4, 256, 0, stream>>>(x, bucket, basea_b, cnt + 500000,
                                                g1, NBATCH);
  k_head<<<NBATCH / 32, 256, 0, stream>>>(g1, alW, alb, g2);
  k_final<<<NBATCH / 4, 256, 0, stream>>>(g2, linW, linb, (float*)d_out);
}

// Round 8
// 1922.629 us; speedup vs baseline: 1.5878x; 1.3283x over previous
//
#include <hip/hip_runtime.h>
#include <hip/hip_fp16.h>

#define NA 100000
#define NBATCH 4096
#define MLD 68
#define CLD 68

typedef _Float16 f16;
typedef f16 half8 __attribute__((ext_vector_type(8)));
typedef float f32x4 __attribute__((ext_vector_type(4)));
union H8 { uint4 u; __half h[8]; };
union HU { uint4 u; half8 h; f16 s[8]; };

// ---------------- counts (all 5 maps + batch) ----------------

struct MapsParams {
  const int* row[6];
  int cnt_off[6];
  int start[6];
  int total;
};

__global__ __launch_bounds__(256) void k_count(MapsParams mp, int* cnt) {
  for (int g = blockIdx.x * 256 + threadIdx.x; g < mp.total; g += gridDim.x * 256) {
    int m = 0;
#pragma unroll
    for (int i = 1; i < 6; i++) if (g >= mp.start[i]) m = i;
    int e = g - mp.start[m];
    atomicAdd(&cnt[mp.cnt_off[m] + mp.row[m][e]], 1);
  }
}

// single-block exclusive scan of the 4096 batch counts
__global__ __launch_bounds__(256) void k_scan_batch(const int* cntb, int* basea) {
  __shared__ int s[256];
  int t = threadIdx.x;
  int carry = 0;
  for (int c0 = 0; c0 < NBATCH; c0 += 256) {
    int v = cntb[c0 + t];
    s[t] = v;
    __syncthreads();
    for (int d = 1; d < 256; d <<= 1) {
      int x = (t >= d) ? s[t - d] : 0;
      __syncthreads();
      s[t] += x;
      __syncthreads();
    }
    basea[c0 + t] = s[t] - v + carry;
    int tot = s[255];
    __syncthreads();
    carry += tot;
  }
}

__global__ __launch_bounds__(256) void k_fill_batch(const int* batch, int* cursor, int* bucket) {
  for (int a = blockIdx.x * 256 + threadIdx.x; a < NA; a += gridDim.x * 256) {
    int b = batch[a];
    int pos = atomicAdd(&cursor[b], 1);
    bucket[pos] = a;
  }
}

// ---------------- feature init ----------------

__global__ __launch_bounds__(256) void k_atom_init(const int* xa, const float* e0,
                                                   const float* e1, const float* e2, float* x) {
  int idx = blockIdx.x * 256 + threadIdx.x;  // float4 index
  if (idx >= NA * 16) return;
  int a = idx >> 4, q = idx & 15;
  int f0 = xa[a * 3], f1 = xa[a * 3 + 1], f2 = xa[a * 3 + 2];
  float4 v0 = ((const float4*)e0)[f0 * 16 + q];
  float4 v1 = ((const float4*)e1)[f1 * 16 + q];
  float4 v2 = ((const float4*)e2)[f2 * 16 + q];
  float4 o;
  o.x = v0.x + v1.x + v2.x; o.y = v0.y + v1.y + v2.y;
  o.z = v0.z + v1.z + v2.z; o.w = v0.w + v1.w + v2.w;
  ((float4*)x)[idx] = o;
}

struct PInit {
  __half* dst[5];
  const int* vals[5];
  const float* tab[5];
  int start8[5];  // cumulative half8-chunk starts
  int total8;
};

__global__ __launch_bounds__(256) void k_path_init(PInit pp) {
  for (int g = blockIdx.x * 256 + threadIdx.x; g < pp.total8; g += gridDim.x * 256) {
    int m = 0;
#pragma unroll
    for (int i = 1; i < 5; i++) if (g >= pp.start8[i]) m = i;
    int lc = g - pp.start8[m];
    int e = lc >> 3, q = lc & 7;
    int v = pp.vals[m][e];
    const float* src = pp.tab[m] + v * 64 + q * 8;
    H8 o;
#pragma unroll
    for (int j = 0; j < 8; j++) o.h[j] = __float2half(src[j]);
    ((uint4*)pp.dst[m])[lc] = o.u;
  }
}

// ---------------- prepack conv kernels to fp16 MFMA-B layout ----------------

__global__ __launch_bounds__(256) void k_prepB(const float* pK, const float* cK, f16* Bp) {
  int tid = blockIdx.x * 256 + threadIdx.x;
  if (tid >= 10 * 12288) return;
  int set = tid / 12288, pos = tid % 12288;
  int j = pos & 7, lane = (pos >> 3) & 63, kcnt = pos >> 9;
  int kc = kcnt % 6, nt = kcnt / 6;
  int k = kc * 32 + ((lane >> 4) << 3) + j;
  int n = (nt << 4) + (lane & 15);
  int w = k >> 6, ji = k & 63;
  const float* K = (set < 6) ? (pK + set * 3 * 4096) : (cK + (set - 6) * 3 * 4096);
  float v = K[w * 4096 + ji * 64 + n];
  if (set >= 6) v = 0.5f * (v + K[(2 - w) * 4096 + ji * 64 + n]);
  Bp[tid] = (f16)v;
}

// ---------------- prepack 64x64 weights to fp16 MFMA-B layout ----------------
// sets 0..5 pW_p2a, 6..9 cW_p2a, 10..15 pW_a2p, 16..19 cW_a2p

__global__ __launch_bounds__(256) void k_prepW(const float* pW, const float* cW,
                                               const float* pWa, const float* cWa, f16* Wp) {
  int tid = blockIdx.x * 256 + threadIdx.x;
  if (tid >= 20 * 4096) return;
  int set = tid >> 12, pos = tid & 4095;
  int j = pos & 7, lane = (pos >> 3) & 63, ntkc = pos >> 9;
  int kc = ntkc & 1, nt = ntkc >> 1;
  int k = kc * 32 + ((lane >> 4) << 3) + j;
  int n = (nt << 4) + (lane & 15);
  const float* W;
  if (set < 6) W = pW + set * 4096;
  else if (set < 10) W = cW + (set - 6) * 4096;
  else if (set < 16) W = pWa + (set - 10) * 4096;
  else W = cWa + (set - 16) * 4096;
  Wp[tid] = (f16)W[k * 64 + n];
}

// ---------------- a2p (MFMA): xp = xp + relu(gather(x) @ W + b) ----------------
// block = 64 edges; fp32 gather converted into A-frag layout; B-frags from global.

struct A2pParams {
  const float* x;
  const int* gidx[3];
  __half* out[3];
  const f16* Wp[3];
  const float* bias[3];
  int rows[3];
  int blk_start[3];
  int nseg;
};

__global__ __launch_bounds__(256) void k_a2p(A2pParams p) {
  __shared__ uint4 Af[512];        // 8KB: 4 m-tiles x 2 kc x 64 lanes
  __shared__ float Cf[64 * CLD];   // 17.4KB fp32 result, stride-68
  __shared__ float bl[64];
  __shared__ int ridx[64];
  int bid = blockIdx.x;
  int seg = 0;
#pragma unroll
  for (int i = 1; i < 3; i++) if (i < p.nseg && bid >= p.blk_start[i]) seg = i;
  int E = p.rows[seg];
  int brow = (bid - p.blk_start[seg]) * 64;
  int rowsv = min(64, E - brow);
  int t = threadIdx.x;
  if (t < 64) {
    int e = brow + t;
    ridx[t] = (e < E) ? p.gidx[seg][e] : 0;
    bl[t] = p.bias[seg][t];
  }
  __syncthreads();
  // gather fp32 x rows -> f16 A-frag layout
  const float4* x4 = (const float4*)p.x;
#pragma unroll
  for (int i = 0; i < 2; i++) {
    int idx = t + 256 * i;            // 0..511
    int la = idx >> 3, g = idx & 7;   // row-in-block, 8-half chunk
    long base = (long)ridx[la] * 16 + g * 2;
    float4 v0 = x4[base];
    float4 v1 = x4[base + 1];
    HU o;
    o.s[0] = (f16)v0.x; o.s[1] = (f16)v0.y; o.s[2] = (f16)v0.z; o.s[3] = (f16)v0.w;
    o.s[4] = (f16)v1.x; o.s[5] = (f16)v1.y; o.s[6] = (f16)v1.z; o.s[7] = (f16)v1.w;
    Af[(((la >> 4) << 1) + (g >> 2)) * 64 + (((g & 3) << 4) + (la & 15))] = o.u;
  }
  __syncthreads();
  int lane = t & 63, wid = t >> 6;
  HU af0, af1;
  af0.u = Af[((wid << 1) + 0) * 64 + lane];
  af1.u = Af[((wid << 1) + 1) * 64 + lane];
  const uint4* Wu = (const uint4*)p.Wp[seg];
#pragma unroll
  for (int nt = 0; nt < 4; nt++) {
    HU b0, b1;
    b0.u = Wu[((nt << 1) + 0) * 64 + lane];
    b1.u = Wu[((nt << 1) + 1) * 64 + lane];
    f32x4 z = {0.f, 0.f, 0.f, 0.f};
    z = __builtin_amdgcn_mfma_f32_16x16x32_f16(af0.h, b0.h, z, 0, 0, 0);
    z = __builtin_amdgcn_mfma_f32_16x16x32_f16(af1.h, b1.h, z, 0, 0, 0);
    int n = (nt << 4) + (lane & 15);
    float bv = bl[n];
    int rb = (wid << 4) + ((lane >> 4) << 2);
#pragma unroll
    for (int r = 0; r < 4; r++) {
      float vv = z[r] + bv;
      Cf[(rb + r) * CLD + n] = vv > 0.f ? vv : 0.f;
    }
  }
  __syncthreads();
  // residual add + store (coalesced uint4 over xp)
  __half* out = p.out[seg];
  uint4* out4 = (uint4*)(out + (long)brow * 64);
#pragma unroll
  for (int i = 0; i < 2; i++) {
    int idx = t + 256 * i;
    int r = idx >> 3, g = idx & 7;
    if (r < rowsv) {
      HU res; res.u = out4[idx];
      const float* c = &Cf[r * CLD + g * 8];
      HU o;
#pragma unroll
      for (int j = 0; j < 8; j++) o.s[j] = (f16)((float)res.s[j] + c[j]);
      out4[idx] = o.u;
    }
  }
}

// ---------------- MFMA conv: buf = pre + relu([Rx192]@[192x64] + Kb) ----------------

struct ConvParams {
  f16* buf[3];
  const f16* Bp[3];
  const float* Kb[3];
  int k[3];
  int P[3];
  int ppb[3];
  int blk_start[3];
  int nseg;
  int cyclic;
};

__global__ __launch_bounds__(256) void k_conv(ConvParams p) {
  __shared__ uint4 Apk[2304];  // up to 6 m-tiles * 6 kc * 64 lanes * 16B = 36864B
  __shared__ uint4 Bpk[1536];  // 4 nt * 6 kc * 64 * 16B = 24576B
  __shared__ float kbl[64];
  int bid = blockIdx.x;
  int seg = 0;
#pragma unroll
  for (int i = 1; i < 3; i++) if (i < p.nseg && bid >= p.blk_start[i]) seg = i;
  int kk = p.k[seg], ppb = p.ppb[seg], P = p.P[seg];
  f16* buf = p.buf[seg];
  int t = threadIdx.x;
  int p0 = (bid - p.blk_start[seg]) * ppb;
  int np = min(ppb, P - p0);
  int R = np * kk;       // always a multiple of 16 for our ppb choices
  int mtb = R >> 4;      // m-tiles: 4..6
  long ebase = (long)p0 * kk;
  {
    const uint4* bs = (const uint4*)p.Bp[seg];
    for (int i = t; i < 1536; i += 256) Bpk[i] = bs[i];
  }
  if (t < 64) kbl[t] = p.Kb[seg][t];
  {
    uint4 z; z.x = z.y = z.z = z.w = 0;
    int nU = mtb * 384;
    for (int i = t; i < nU; i += 256) Apk[i] = z;
  }
  __syncthreads();
  {
    const uint4* src = (const uint4*)(buf + ebase * 64);
    int tot = R * 8;
    for (int idx = t; idx < tot; idx += 256) {
      int r = idx >> 3, jj = idx & 7;
      uint4 ch = src[idx];
      int s = r % kk;
      int kchi = jj >> 2, quad = jj & 3;
#pragma unroll
      for (int w = 0; w < 3; w++) {
        int rd;
        if (w == 1) rd = r;
        else if (w == 0) rd = (s + 1 < kk) ? r + 1 : (p.cyclic ? r + 1 - kk : -1);
        else rd = (s >= 1) ? r - 1 : (p.cyclic ? r + kk - 1 : -1);
        if (rd >= 0)
          Apk[((rd >> 4) * 6 + 2 * w + kchi) * 64 + quad * 16 + (rd & 15)] = ch;
      }
    }
  }
  __syncthreads();
  int lane = t & 63, wid = t >> 6;
  int wave_n = wid & 1, wave_m = wid >> 1;
  int mtA = (mtb + 1) >> 1;
  int m0 = wave_m ? mtA : 0;
  int mcnt = wave_m ? (mtb - mtA) : mtA;  // <= 3
  f32x4 acc[3][2];
#pragma unroll
  for (int i = 0; i < 3; i++)
#pragma unroll
    for (int jn = 0; jn < 2; jn++) {
      f32x4 z = {0.f, 0.f, 0.f, 0.f};
      acc[i][jn] = z;
    }
  for (int kc = 0; kc < 6; kc++) {
    HU a[3], b[2];
#pragma unroll
    for (int jn = 0; jn < 2; jn++)
      b[jn].u = Bpk[((wave_n * 2 + jn) * 6 + kc) * 64 + lane];
#pragma unroll
    for (int i = 0; i < 3; i++)
      if (i < mcnt) a[i].u = Apk[((m0 + i) * 6 + kc) * 64 + lane];
#pragma unroll
    for (int i = 0; i < 3; i++)
      if (i < mcnt) {
#pragma unroll
        for (int jn = 0; jn < 2; jn++)
          acc[i][jn] = __builtin_amdgcn_mfma_f32_16x16x32_f16(a[i].h, b[jn].h, acc[i][jn], 0, 0, 0);
      }
  }
  const f16* Ah = (const f16*)Apk;
#pragma unroll
  for (int i = 0; i < 3; i++) {
    if (i >= mcnt) continue;
    int mt = m0 + i;
#pragma unroll
    for (int jn = 0; jn < 2; jn++) {
      int n = (wave_n * 2 + jn) * 16 + (lane & 15);
      int kcr = 2 + (n >> 5), quadb = (n & 31) >> 3, jr = n & 7;
#pragma unroll
      for (int reg = 0; reg < 4; reg++) {
        int r = mt * 16 + ((lane >> 4) << 2) + reg;
        float pre = (float)Ah[(((mt * 6 + kcr) * 64 + quadb * 16 + (r & 15)) << 3) + jr];
        float v = acc[i][jn][reg] + kbl[n];
        v = v > 0.f ? v : 0.f;
        buf[(ebase + r) * 64 + n] = (f16)(pre + v);
      }
    }
  }
}

// ---------------- p2a scatter: acc[row[e]] += xp[e] (fp32 global atomics) ----------------

__global__ __launch_bounds__(256) void k_scatter(const f16* xp, const int* row,
                                                 float* acc, int E) {
  int gw = (blockIdx.x * 256 + threadIdx.x) >> 6;
  int lane = threadIdx.x & 63;
  int nw = (gridDim.x * 256) >> 6;
  for (int e0 = gw * 4; e0 < E; e0 += nw * 4) {
    int4 a4 = ((const int4*)row)[e0 >> 2];   // broadcast: 4 atom ids
    float v[4];
#pragma unroll
    for (int u = 0; u < 4; u++) v[u] = (float)xp[(long)(e0 + u) * 64 + lane];
    atomicAdd(&acc[(long)a4.x * 64 + lane], v[0]);
    atomicAdd(&acc[(long)a4.y * 64 + lane], v[1]);
    atomicAdd(&acc[(long)a4.z * 64 + lane], v[2]);
    atomicAdd(&acc[(long)a4.w * 64 + lane], v[3]);
  }
}

// ---------------- p2a apply: x += relu(acc/cnt @ W + b); self-zeroes acc ----------------

__global__ __launch_bounds__(256) void k_apply(float* acc, const int* cnt, const f16* Wp,
                                               const float* bias, float* x) {
  __shared__ float mean[64 * MLD];  // 17.4KB
  __shared__ uint4 Af[512];         // 8KB fp16 A-frags
  __shared__ float invl[64];
  __shared__ float bl[64];
  int t = threadIdx.x;
  int a0 = blockIdx.x * 64;
  if (t < 64) {
    int cb = cnt[a0 + t];
    invl[t] = 1.f / (float)(cb > 0 ? cb : 1);
    bl[t] = bias[t];
  }
  float4* acc4 = (float4*)acc;
#pragma unroll
  for (int i = 0; i < 4; i++) {
    int idx = t + 256 * i;
    int r = idx >> 4, q = idx & 15;
    float4 v = acc4[a0 * 16 + idx];
    float4 z4 = {0.f, 0.f, 0.f, 0.f};
    acc4[a0 * 16 + idx] = z4;  // ready for next map
    *(float4*)&mean[r * MLD + q * 4] = v;
  }
  __syncthreads();
#pragma unroll
  for (int i = 0; i < 2; i++) {
    int la = (t >> 3) + 32 * i;
    int g = t & 7;
    float inv = invl[la];
    const float* mr = &mean[la * MLD + g * 8];
    HU o;
#pragma unroll
    for (int j = 0; j < 8; j++) o.h[j] = (f16)(mr[j] * inv);
    int kc = g >> 2, lb = ((g & 3) << 4) + (la & 15), mtt = la >> 4;
    Af[(((mtt << 1) + kc) << 6) + lb] = o.u;
  }
  __syncthreads();
  int lane = t & 63, wid = t >> 6;
  HU af0, af1;
  af0.u = Af[((wid << 1) + 0) * 64 + lane];
  af1.u = Af[((wid << 1) + 1) * 64 + lane];
  const uint4* Wu = (const uint4*)Wp;
  int rowb = a0 + wid * 16 + ((lane >> 4) << 2);
#pragma unroll
  for (int nt = 0; nt < 4; nt++) {
    HU b0, b1;
    b0.u = Wu[((nt << 1) + 0) * 64 + lane];
    b1.u = Wu[((nt << 1) + 1) * 64 + lane];
    f32x4 z = {0.f, 0.f, 0.f, 0.f};
    z = __builtin_amdgcn_mfma_f32_16x16x32_f16(af0.h, b0.h, z, 0, 0, 0);
    z = __builtin_amdgcn_mfma_f32_16x16x32_f16(af1.h, b1.h, z, 0, 0, 0);
    int n = nt * 16 + (lane & 15);
    float bv = bl[n];
#pragma unroll
    for (int r = 0; r < 4; r++) {
      int atom = rowb + r;
      if (atom < NA) {
        float vv = z[r] + bv;
        vv = vv > 0.f ? vv : 0.f;
        x[(long)atom * 64 + n] += vv;
      }
    }
  }
}

// ---------------- batch mean: g1[b] = mean(x[a]) over CSR bucket ----------------

__global__ __launch_bounds__(256) void k_meanscatter(const float* src, const int* bucket,
                                                     const int* basea, const int* cnta,
                                                     float* dst, int nseg) {
  int wid = (blockIdx.x * 256 + threadIdx.x) >> 6;
  int lane = threadIdx.x & 63;
  if (wid >= nseg) return;
  int b0 = basea[wid], cnt = cnta[wid];
  float s = 0.f;
  for (int i = 0; i < cnt; i++) {
    int e = bucket[b0 + i];
    s += src[(long)e * 64 + lane];
  }
  dst[(long)wid * 64 + lane] = s / (float)(cnt > 0 ? cnt : 1);
}

// ---------------- head gemm: g2 = relu(g1 @ W + b) ----------------

__global__ __launch_bounds__(256) void k_head(const float* g1, const float* W,
                                              const float* bias, float* g2) {
  __shared__ float Wl[4096];
  __shared__ float inl[32 * 64];
  __shared__ float bl[64];
  int t = threadIdx.x;
  int brow = blockIdx.x * 32;
#pragma unroll
  for (int i = 0; i < 4; i++) ((float4*)Wl)[t + 256 * i] = ((const float4*)W)[t + 256 * i];
  if (t < 64) bl[t] = bias[t];
  __syncthreads();
#pragma unroll
  for (int i = 0; i < 2; i++) {
    int idx = t + 256 * i;
    int r = idx >> 4, q = idx & 15;
    ((float4*)inl)[idx] = ((const float4*)(g1 + (long)(brow + r) * 64))[q];
  }
  __syncthreads();
  int c = t & 63, rq = t >> 6;
  float acc[8];
#pragma unroll
  for (int i = 0; i < 8; i++) acc[i] = 0.f;
  for (int j = 0; j < 64; j += 4) {
    float w0 = Wl[(j + 0) * 64 + c], w1 = Wl[(j + 1) * 64 + c];
    float w2 = Wl[(j + 2) * 64 + c], w3 = Wl[(j + 3) * 64 + c];
#pragma unroll
    for (int i = 0; i < 8; i++) {
      int r = rq * 8 + i;
      float4 v = *(const float4*)&inl[r * 64 + j];
      acc[i] += v.x * w0 + v.y * w1 + v.z * w2 + v.w * w3;
    }
  }
#pragma unroll
  for (int i = 0; i < 8; i++) {
    long r = brow + rq * 8 + i;
    float v = acc[i] + bl[c];
    g2[r * 64 + c] = v > 0.f ? v : 0.f;
  }
}

__global__ __launch_bounds__(256) void k_final(const float* g2, const float* linW,
                                               const float* linb, float* out) {
  int wid = (blockIdx.x * 256 + threadIdx.x) >> 6;
  int lane = threadIdx.x & 63;
  if (wid >= NBATCH) return;
  float v = g2[(long)wid * 64 + lane] * linW[lane];
  for (int o = 32; o > 0; o >>= 1) v += __shfl_down(v, o, 64);
  if (lane == 0) out[wid] = v + linb[0];
}

__global__ __launch_bounds__(256) void k_zero_out(float* out, int n) {
  for (int i = blockIdx.x * 256 + threadIdx.x; i < n; i += gridDim.x * 256) out[i] = 0.f;
}

// ---------------- launcher ----------------

extern "C" void kernel_launch(void* const* d_in, const int* in_sizes, int n_in,
                              void* d_out, int out_size, void* d_ws, size_t ws_size,
                              hipStream_t stream) {
  (void)in_sizes; (void)n_in;

  const int* x_atom = (const int*)d_in[0];
  const int* vals[5] = {(const int*)d_in[1], (const int*)d_in[4], (const int*)d_in[7],
                        (const int*)d_in[10], (const int*)d_in[13]};
  const int* rowm[5] = {(const int*)d_in[2], (const int*)d_in[5], (const int*)d_in[8],
                        (const int*)d_in[11], (const int*)d_in[14]};
  const int* batch = (const int*)d_in[16];
  const float* aemb0 = (const float*)d_in[17];
  const float* aemb1 = (const float*)d_in[18];
  const float* aemb2 = (const float*)d_in[19];
  const float* path_emb = (const float*)d_in[20];
  const float* cycle_emb = (const float*)d_in[21];
  const float* pW_a2p = (const float*)d_in[22];
  const float* pb_a2p = (const float*)d_in[23];
  const float* pW_p2a = (const float*)d_in[24];
  const float* pb_p2a = (const float*)d_in[25];
  const float* pK = (const float*)d_in[26];
  const float* pKb = (const float*)d_in[27];
  const float* cW_a2p = (const float*)d_in[28];
  const float* cb_a2p = (const float*)d_in[29];
  const float* cW_p2a = (const float*)d_in[30];
  const float* cb_p2a = (const float*)d_in[31];
  const float* cK = (const float*)d_in[32];
  const float* cKb = (const float*)d_in[33];
  const float* alW = (const float*)d_in[34];
  const float* alb = (const float*)d_in[35];
  const float* linW = (const float*)d_in[36];
  const float* linb = (const float*)d_in[37];

  static const int Em[5] = {300000, 400000, 500000, 200000, 240000};
  static const int Km[5] = {3, 4, 5, 5, 6};
  static const int Ppb[5] = {32, 24, 16, 16, 16};  // paths/block -> R in {96,96,80,80,96}
  const int CNT_N = 5 * 100000 + NBATCH;  // 504096
  const int ACC_ROWS = 100032;            // padded to block grid (1563*64)

  char* ws = (char*)d_ws;
  size_t off = 0;
  auto alloc = [&](size_t nbytes) -> char* {
    char* p = ws + off;
    off = (off + nbytes + 255) & ~(size_t)255;
    return p;
  };
  float* x = (float*)alloc((size_t)NA * 64 * 4);
  __half* xp[5];
  for (int m = 0; m < 5; m++) xp[m] = (__half*)alloc((size_t)Em[m] * 64 * 2);
  float* acc = (float*)alloc((size_t)ACC_ROWS * 64 * 4);
  float* g1 = (float*)alloc((size_t)NBATCH * 64 * 4);
  float* g2 = (float*)alloc((size_t)NBATCH * 64 * 4);
  int* cnt = (int*)alloc((size_t)CNT_N * 4);
  int* basea_b = (int*)alloc((size_t)(NBATCH + 1) * 4);
  int* cursor_b = (int*)alloc((size_t)NBATCH * 4);
  int* bucket = (int*)alloc((size_t)NA * 4);
  f16* Bp = (f16*)alloc((size_t)10 * 12288 * 2);  // prepacked conv kernels
  f16* Wpk = (f16*)alloc((size_t)20 * 4096 * 2);  // prepacked p2a+a2p weights

  if (ws_size < off) {  // workspace too small: emit readable failure, not a fault
    k_zero_out<<<16, 256, 0, stream>>>((float*)d_out, out_size);
    return;
  }

  // ---- counts (all maps + batch) and batch CSR
  MapsParams mp;
  {
    int s = 0;
    for (int m = 0; m < 5; m++) {
      mp.row[m] = rowm[m]; mp.cnt_off[m] = m * 100000;
      mp.start[m] = s; s += Em[m];
    }
    mp.row[5] = batch; mp.cnt_off[5] = 500000; mp.start[5] = s;
    mp.total = s + NA;
  }
  hipMemsetAsync(cnt, 0, (size_t)CNT_N * 4, stream);
  hipMemsetAsync(acc, 0, (size_t)ACC_ROWS * 64 * 4, stream);
  k_count<<<2048, 256, 0, stream>>>(mp, cnt);
  k_scan_batch<<<1, 256, 0, stream>>>(cnt + 500000, basea_b);
  hipMemcpyAsync(cursor_b, basea_b, (size_t)NBATCH * 4, hipMemcpyDeviceToDevice, stream);
  k_fill_batch<<<128, 256, 0, stream>>>(batch, cursor_b, bucket);

  // ---- prepack weights + feature init
  k_prepB<<<480, 256, 0, stream>>>(pK, cK, Bp);
  k_prepW<<<320, 256, 0, stream>>>(pW_p2a, cW_p2a, pW_a2p, cW_a2p, Wpk);
  k_atom_init<<<NA * 16 / 256, 256, 0, stream>>>(x_atom, aemb0, aemb1, aemb2, x);
  {
    PInit pp;
    int s8 = 0;
    for (int m = 0; m < 5; m++) {
      pp.dst[m] = xp[m];
      pp.vals[m] = vals[m];
      pp.tab[m] = (m < 3) ? (path_emb + m * 6 * 64) : (cycle_emb + (m - 3) * 4 * 64);
      pp.start8[m] = s8;
      s8 += Em[m] * 8;
    }
    pp.total8 = s8;
    k_path_init<<<8192, 256, 0, stream>>>(pp);
  }

  int apply_blocks = ACC_ROWS / 64;  // 1563

  // ---- layers
  for (int l = 0; l < 2; l++) {
    // === paths group (maps 0..2), non-cyclic
    {
      A2pParams gp{};
      gp.nseg = 3; gp.x = x;
      int bs = 0;
      for (int m = 0; m < 3; m++) {
        gp.gidx[m] = rowm[m]; gp.out[m] = xp[m];
        gp.Wp[m] = Wpk + (size_t)(10 + l * 3 + m) * 4096;
        gp.bias[m] = pb_a2p + (l * 3 + m) * 64;
        gp.rows[m] = Em[m];
        gp.blk_start[m] = bs;
        bs += (Em[m] + 63) / 64;
      }
      k_a2p<<<bs, 256, 0, stream>>>(gp);

      ConvParams cp{};
      cp.nseg = 3; cp.cyclic = 0;
      int cbs = 0;
      for (int m = 0; m < 3; m++) {
        cp.buf[m] = (f16*)xp[m];
        cp.Bp[m] = Bp + (size_t)(l * 3 + m) * 12288;
        cp.Kb[m] = pKb + (l * 3 + m) * 64;
        cp.k[m] = Km[m]; cp.P[m] = Em[m] / Km[m]; cp.ppb[m] = Ppb[m];
        cp.blk_start[m] = cbs;
        cbs += (cp.P[m] + cp.ppb[m] - 1) / cp.ppb[m];
      }
      k_conv<<<cbs, 256, 0, stream>>>(cp);

      for (int m = 0; m < 3; m++) {
        k_scatter<<<1024, 256, 0, stream>>>((const f16*)xp[m], rowm[m], acc, Em[m]);
        k_apply<<<apply_blocks, 256, 0, stream>>>(acc, cnt + m * 100000,
                                                  Wpk + (size_t)(l * 3 + m) * 4096,
                                                  pb_p2a + (l * 3 + m) * 64, x);
      }
    }
    // === cycles group (maps 3..4), cyclic
    {
      A2pParams gp{};
      gp.nseg = 2; gp.x = x;
      int bs = 0;
      for (int m = 3; m < 5; m++) {
        int i = m - 3;
        gp.gidx[i] = rowm[m]; gp.out[i] = xp[m];
        gp.Wp[i] = Wpk + (size_t)(16 + l * 2 + i) * 4096;
        gp.bias[i] = cb_a2p + (l * 2 + i) * 64;
        gp.rows[i] = Em[m];
        gp.blk_start[i] = bs;
        bs += (Em[m] + 63) / 64;
      }
      k_a2p<<<bs, 256, 0, stream>>>(gp);

      ConvParams cp{};
      cp.nseg = 2; cp.cyclic = 1;
      int cbs = 0;
      for (int m = 3; m < 5; m++) {
        int i = m - 3;
        cp.buf[i] = (f16*)xp[m];
        cp.Bp[i] = Bp + (size_t)(6 + l * 2 + i) * 12288;
        cp.Kb[i] = cKb + (l * 2 + i) * 64;
        cp.k[i] = Km[m]; cp.P[i] = Em[m] / Km[m]; cp.ppb[i] = Ppb[m];
        cp.blk_start[i] = cbs;
        cbs += (cp.P[i] + cp.ppb[i] - 1) / cp.ppb[i];
      }
      k_conv<<<cbs, 256, 0, stream>>>(cp);

      for (int m = 3; m < 5; m++) {
        int i = m - 3;
        k_scatter<<<1024, 256, 0, stream>>>((const f16*)xp[m], rowm[m], acc, Em[m]);
        k_apply<<<apply_blocks, 256, 0, stream>>>(acc, cnt + m * 100000,
                                                  Wpk + (size_t)(6 + l * 2 + i) * 4096,
                                                  cb_p2a + (l * 2 + i) * 64, x);
      }
    }
  }

  // ---- head
  k_meanscatter<<<NBATCH / 4, 256, 0, stream>>>(x, bucket, basea_b, cnt + 500000,
                                                g1, NBATCH);
  k_head<<<NBATCH / 32, 256, 0, stream>>>(g1, alW, alb, g2);
  k_final<<<NBATCH / 4, 256, 0, stream>>>(g2, linW, linb, (float*)d_out);
}

// Round 9
// 1794.275 us; speedup vs baseline: 1.7014x; 1.0715x over previous
//
#include <hip/hip_runtime.h>
#include <hip/hip_fp16.h>

#define NA 100000
#define NBATCH 4096
#define MLD 68
#define CLD 68

typedef _Float16 f16;
typedef f16 half8 __attribute__((ext_vector_type(8)));
typedef float f32x4 __attribute__((ext_vector_type(4)));
union H8 { uint4 u; __half h[8]; };
union HU { uint4 u; half8 h; f16 s[8]; };

// ---------------- counts (all 5 maps + batch) ----------------

struct MapsParams {
  const int* row[6];
  int cnt_off[6];
  int start[6];
  int total;
};

__global__ __launch_bounds__(256) void k_count(MapsParams mp, int* cnt) {
  for (int g = blockIdx.x * 256 + threadIdx.x; g < mp.total; g += gridDim.x * 256) {
    int m = 0;
#pragma unroll
    for (int i = 1; i < 6; i++) if (g >= mp.start[i]) m = i;
    int e = g - mp.start[m];
    atomicAdd(&cnt[mp.cnt_off[m] + mp.row[m][e]], 1);
  }
}

// single-block exclusive scan of the 4096 batch counts
__global__ __launch_bounds__(256) void k_scan_batch(const int* cntb, int* basea) {
  __shared__ int s[256];
  int t = threadIdx.x;
  int carry = 0;
  for (int c0 = 0; c0 < NBATCH; c0 += 256) {
    int v = cntb[c0 + t];
    s[t] = v;
    __syncthreads();
    for (int d = 1; d < 256; d <<= 1) {
      int x = (t >= d) ? s[t - d] : 0;
      __syncthreads();
      s[t] += x;
      __syncthreads();
    }
    basea[c0 + t] = s[t] - v + carry;
    int tot = s[255];
    __syncthreads();
    carry += tot;
  }
}

__global__ __launch_bounds__(256) void k_fill_batch(const int* batch, int* cursor, int* bucket) {
  for (int a = blockIdx.x * 256 + threadIdx.x; a < NA; a += gridDim.x * 256) {
    int b = batch[a];
    int pos = atomicAdd(&cursor[b], 1);
    bucket[pos] = a;
  }
}

// ---------------- feature init ----------------

__global__ __launch_bounds__(256) void k_atom_init(const int* xa, const float* e0,
                                                   const float* e1, const float* e2, float* x) {
  int idx = blockIdx.x * 256 + threadIdx.x;  // float4 index
  if (idx >= NA * 16) return;
  int a = idx >> 4, q = idx & 15;
  int f0 = xa[a * 3], f1 = xa[a * 3 + 1], f2 = xa[a * 3 + 2];
  float4 v0 = ((const float4*)e0)[f0 * 16 + q];
  float4 v1 = ((const float4*)e1)[f1 * 16 + q];
  float4 v2 = ((const float4*)e2)[f2 * 16 + q];
  float4 o;
  o.x = v0.x + v1.x + v2.x; o.y = v0.y + v1.y + v2.y;
  o.z = v0.z + v1.z + v2.z; o.w = v0.w + v1.w + v2.w;
  ((float4*)x)[idx] = o;
}

struct PInit {
  __half* dst[5];
  const int* vals[5];
  const float* tab[5];
  int start8[5];  // cumulative half8-chunk starts
  int total8;
};

__global__ __launch_bounds__(256) void k_path_init(PInit pp) {
  for (int g = blockIdx.x * 256 + threadIdx.x; g < pp.total8; g += gridDim.x * 256) {
    int m = 0;
#pragma unroll
    for (int i = 1; i < 5; i++) if (g >= pp.start8[i]) m = i;
    int lc = g - pp.start8[m];
    int e = lc >> 3, q = lc & 7;
    int v = pp.vals[m][e];
    const float* src = pp.tab[m] + v * 64 + q * 8;
    H8 o;
#pragma unroll
    for (int j = 0; j < 8; j++) o.h[j] = __float2half(src[j]);
    ((uint4*)pp.dst[m])[lc] = o.u;
  }
}

// ---------------- prepack conv kernels to fp16 MFMA-B layout ----------------

__global__ __launch_bounds__(256) void k_prepB(const float* pK, const float* cK, f16* Bp) {
  int tid = blockIdx.x * 256 + threadIdx.x;
  if (tid >= 10 * 12288) return;
  int set = tid / 12288, pos = tid % 12288;
  int j = pos & 7, lane = (pos >> 3) & 63, kcnt = pos >> 9;
  int kc = kcnt % 6, nt = kcnt / 6;
  int k = kc * 32 + ((lane >> 4) << 3) + j;
  int n = (nt << 4) + (lane & 15);
  int w = k >> 6, ji = k & 63;
  const float* K = (set < 6) ? (pK + set * 3 * 4096) : (cK + (set - 6) * 3 * 4096);
  float v = K[w * 4096 + ji * 64 + n];
  if (set >= 6) v = 0.5f * (v + K[(2 - w) * 4096 + ji * 64 + n]);
  Bp[tid] = (f16)v;
}

// ---------------- prepack 64x64 weights to fp16 MFMA-B layout ----------------
// sets 0..5 pW_p2a, 6..9 cW_p2a, 10..15 pW_a2p, 16..19 cW_a2p

__global__ __launch_bounds__(256) void k_prepW(const float* pW, const float* cW,
                                               const float* pWa, const float* cWa, f16* Wp) {
  int tid = blockIdx.x * 256 + threadIdx.x;
  if (tid >= 20 * 4096) return;
  int set = tid >> 12, pos = tid & 4095;
  int j = pos & 7, lane = (pos >> 3) & 63, ntkc = pos >> 9;
  int kc = ntkc & 1, nt = ntkc >> 1;
  int k = kc * 32 + ((lane >> 4) << 3) + j;
  int n = (nt << 4) + (lane & 15);
  const float* W;
  if (set < 6) W = pW + set * 4096;
  else if (set < 10) W = cW + (set - 6) * 4096;
  else if (set < 16) W = pWa + (set - 10) * 4096;
  else W = cWa + (set - 16) * 4096;
  Wp[tid] = (f16)W[k * 64 + n];
}

// ---------------- a2p (MFMA): xp = xp + relu(gather(x) @ W + b) ----------------
// block = 64 edges; fp32 gather converted into A-frag layout; B-frags from global.

struct A2pParams {
  const float* x;
  const int* gidx[3];
  __half* out[3];
  const f16* Wp[3];
  const float* bias[3];
  int rows[3];
  int blk_start[3];
  int nseg;
};

__global__ __launch_bounds__(256) void k_a2p(A2pParams p) {
  __shared__ uint4 Af[512];        // 8KB: 4 m-tiles x 2 kc x 64 lanes
  __shared__ float Cf[64 * CLD];   // 17.4KB fp32 result, stride-68
  __shared__ float bl[64];
  __shared__ int ridx[64];
  int bid = blockIdx.x;
  int seg = 0;
#pragma unroll
  for (int i = 1; i < 3; i++) if (i < p.nseg && bid >= p.blk_start[i]) seg = i;
  int E = p.rows[seg];
  int brow = (bid - p.blk_start[seg]) * 64;
  int rowsv = min(64, E - brow);
  int t = threadIdx.x;
  if (t < 64) {
    int e = brow + t;
    ridx[t] = (e < E) ? p.gidx[seg][e] : 0;
    bl[t] = p.bias[seg][t];
  }
  __syncthreads();
  // gather fp32 x rows -> f16 A-frag layout
  const float4* x4 = (const float4*)p.x;
#pragma unroll
  for (int i = 0; i < 2; i++) {
    int idx = t + 256 * i;            // 0..511
    int la = idx >> 3, g = idx & 7;   // row-in-block, 8-half chunk
    long base = (long)ridx[la] * 16 + g * 2;
    float4 v0 = x4[base];
    float4 v1 = x4[base + 1];
    HU o;
    o.s[0] = (f16)v0.x; o.s[1] = (f16)v0.y; o.s[2] = (f16)v0.z; o.s[3] = (f16)v0.w;
    o.s[4] = (f16)v1.x; o.s[5] = (f16)v1.y; o.s[6] = (f16)v1.z; o.s[7] = (f16)v1.w;
    Af[(((la >> 4) << 1) + (g >> 2)) * 64 + (((g & 3) << 4) + (la & 15))] = o.u;
  }
  __syncthreads();
  int lane = t & 63, wid = t >> 6;
  HU af0, af1;
  af0.u = Af[((wid << 1) + 0) * 64 + lane];
  af1.u = Af[((wid << 1) + 1) * 64 + lane];
  const uint4* Wu = (const uint4*)p.Wp[seg];
#pragma unroll
  for (int nt = 0; nt < 4; nt++) {
    HU b0, b1;
    b0.u = Wu[((nt << 1) + 0) * 64 + lane];
    b1.u = Wu[((nt << 1) + 1) * 64 + lane];
    f32x4 z = {0.f, 0.f, 0.f, 0.f};
    z = __builtin_amdgcn_mfma_f32_16x16x32_f16(af0.h, b0.h, z, 0, 0, 0);
    z = __builtin_amdgcn_mfma_f32_16x16x32_f16(af1.h, b1.h, z, 0, 0, 0);
    int n = (nt << 4) + (lane & 15);
    float bv = bl[n];
    int rb = (wid << 4) + ((lane >> 4) << 2);
#pragma unroll
    for (int r = 0; r < 4; r++) {
      float vv = z[r] + bv;
      Cf[(rb + r) * CLD + n] = vv > 0.f ? vv : 0.f;
    }
  }
  __syncthreads();
  // residual add + store (coalesced uint4 over xp)
  __half* out = p.out[seg];
  uint4* out4 = (uint4*)(out + (long)brow * 64);
#pragma unroll
  for (int i = 0; i < 2; i++) {
    int idx = t + 256 * i;
    int r = idx >> 3, g = idx & 7;
    if (r < rowsv) {
      HU res; res.u = out4[idx];
      const float* c = &Cf[r * CLD + g * 8];
      HU o;
#pragma unroll
      for (int j = 0; j < 8; j++) o.s[j] = (f16)((float)res.s[j] + c[j]);
      out4[idx] = o.u;
    }
  }
}

// ---------------- MFMA conv v3: buf = pre + relu([Rx192]@[192x64] + Kb) ----------------
// B-frags from global; epilogue via fp32 Cf aliased into Apk; coalesced residual+store.

struct ConvParams {
  f16* buf[3];
  const f16* Bp[3];
  const float* Kb[3];
  int k[3];
  int P[3];
  int ppb[3];
  int blk_start[3];
  int nseg;
  int cyclic;
};

__global__ __launch_bounds__(256) void k_conv(ConvParams p) {
  __shared__ uint4 Apk[2304];  // 36.9KB; after MFMA reads, reused as fp32 Cf (R*68 <= 6528 fl)
  __shared__ float kbl[64];
  int bid = blockIdx.x;
  int seg = 0;
#pragma unroll
  for (int i = 1; i < 3; i++) if (i < p.nseg && bid >= p.blk_start[i]) seg = i;
  int kk = p.k[seg], ppb = p.ppb[seg], P = p.P[seg];
  f16* buf = p.buf[seg];
  int t = threadIdx.x;
  int p0 = (bid - p.blk_start[seg]) * ppb;
  int np = min(ppb, P - p0);
  int R = np * kk;       // multiple of 16
  int mtb = R >> 4;      // m-tiles: 4..6
  long ebase = (long)p0 * kk;
  if (t < 64) kbl[t] = p.Kb[seg][t];
  {
    uint4 z; z.x = z.y = z.z = z.w = 0;
    int nU = mtb * 384;
    for (int i = t; i < nU; i += 256) Apk[i] = z;
  }
  __syncthreads();
  {
    const uint4* src = (const uint4*)(buf + ebase * 64);
    int tot = R * 8;
    for (int idx = t; idx < tot; idx += 256) {
      int r = idx >> 3, jj = idx & 7;
      uint4 ch = src[idx];
      int s = r % kk;
      int kchi = jj >> 2, quad = jj & 3;
#pragma unroll
      for (int w = 0; w < 3; w++) {
        int rd;
        if (w == 1) rd = r;
        else if (w == 0) rd = (s + 1 < kk) ? r + 1 : (p.cyclic ? r + 1 - kk : -1);
        else rd = (s >= 1) ? r - 1 : (p.cyclic ? r + kk - 1 : -1);
        if (rd >= 0)
          Apk[((rd >> 4) * 6 + 2 * w + kchi) * 64 + quad * 16 + (rd & 15)] = ch;
      }
    }
  }
  __syncthreads();
  int lane = t & 63, wid = t >> 6;
  int wave_n = wid & 1, wave_m = wid >> 1;
  int mtA = (mtb + 1) >> 1;
  int m0 = wave_m ? mtA : 0;
  int mcnt = wave_m ? (mtb - mtA) : mtA;  // <= 3
  f32x4 acc[3][2];
#pragma unroll
  for (int i = 0; i < 3; i++)
#pragma unroll
    for (int jn = 0; jn < 2; jn++) {
      f32x4 z = {0.f, 0.f, 0.f, 0.f};
      acc[i][jn] = z;
    }
  const uint4* Bg = (const uint4*)p.Bp[seg];
  for (int kc = 0; kc < 6; kc++) {
    HU a[3], b[2];
#pragma unroll
    for (int jn = 0; jn < 2; jn++)
      b[jn].u = Bg[((wave_n * 2 + jn) * 6 + kc) * 64 + lane];
#pragma unroll
    for (int i = 0; i < 3; i++)
      if (i < mcnt) a[i].u = Apk[((m0 + i) * 6 + kc) * 64 + lane];
#pragma unroll
    for (int i = 0; i < 3; i++)
      if (i < mcnt) {
#pragma unroll
        for (int jn = 0; jn < 2; jn++)
          acc[i][jn] = __builtin_amdgcn_mfma_f32_16x16x32_f16(a[i].h, b[jn].h, acc[i][jn], 0, 0, 0);
      }
  }
  __syncthreads();  // all Apk reads done; reuse as Cf
  float* Cf = (float*)Apk;
#pragma unroll
  for (int i = 0; i < 3; i++) {
    if (i >= mcnt) continue;
    int mt = m0 + i;
#pragma unroll
    for (int jn = 0; jn < 2; jn++) {
      int n = (wave_n * 2 + jn) * 16 + (lane & 15);
      float bv = kbl[n];
      int rb = mt * 16 + ((lane >> 4) << 2);
#pragma unroll
      for (int reg = 0; reg < 4; reg++) {
        float v = acc[i][jn][reg] + bv;
        Cf[(rb + reg) * CLD + n] = v > 0.f ? v : 0.f;
      }
    }
  }
  __syncthreads();
  // coalesced residual read + final store
  uint4* bufg = (uint4*)(buf + ebase * 64);
  int tot = R * 8;
  for (int idx = t; idx < tot; idx += 256) {
    int r = idx >> 3, g = idx & 7;
    HU res; res.u = bufg[idx];
    const float* c = &Cf[r * CLD + g * 8];
    HU o;
#pragma unroll
    for (int j = 0; j < 8; j++) o.s[j] = (f16)((float)res.s[j] + c[j]);
    bufg[idx] = o.u;
  }
}

// ---------------- p2a scatter: acc[row[e]] += xp[e] (fp32 global atomics) ----------------

__global__ __launch_bounds__(256) void k_scatter(const f16* xp, const int* row,
                                                 float* acc, int E) {
  int gw = (blockIdx.x * 256 + threadIdx.x) >> 6;
  int lane = threadIdx.x & 63;
  int nw = (gridDim.x * 256) >> 6;
  for (int e0 = gw * 8; e0 < E; e0 += nw * 8) {
    int4 a4 = ((const int4*)row)[e0 >> 2];
    int4 b4 = ((const int4*)row)[(e0 >> 2) + 1];
    float v[8];
#pragma unroll
    for (int u = 0; u < 8; u++) v[u] = (float)xp[(long)(e0 + u) * 64 + lane];
    atomicAdd(&acc[(long)a4.x * 64 + lane], v[0]);
    atomicAdd(&acc[(long)a4.y * 64 + lane], v[1]);
    atomicAdd(&acc[(long)a4.z * 64 + lane], v[2]);
    atomicAdd(&acc[(long)a4.w * 64 + lane], v[3]);
    atomicAdd(&acc[(long)b4.x * 64 + lane], v[4]);
    atomicAdd(&acc[(long)b4.y * 64 + lane], v[5]);
    atomicAdd(&acc[(long)b4.z * 64 + lane], v[6]);
    atomicAdd(&acc[(long)b4.w * 64 + lane], v[7]);
  }
}

// ---------------- p2a apply: x += relu(acc/cnt @ W + b); self-zeroes acc ----------------

__global__ __launch_bounds__(256) void k_apply(float* acc, const int* cnt, const f16* Wp,
                                               const float* bias, float* x) {
  __shared__ float mean[64 * MLD];  // 17.4KB
  __shared__ uint4 Af[512];         // 8KB fp16 A-frags
  __shared__ float invl[64];
  __shared__ float bl[64];
  int t = threadIdx.x;
  int a0 = blockIdx.x * 64;
  if (t < 64) {
    int cb = cnt[a0 + t];
    invl[t] = 1.f / (float)(cb > 0 ? cb : 1);
    bl[t] = bias[t];
  }
  float4* acc4 = (float4*)acc;
#pragma unroll
  for (int i = 0; i < 4; i++) {
    int idx = t + 256 * i;
    int r = idx >> 4, q = idx & 15;
    float4 v = acc4[a0 * 16 + idx];
    float4 z4 = {0.f, 0.f, 0.f, 0.f};
    acc4[a0 * 16 + idx] = z4;  // ready for next map
    *(float4*)&mean[r * MLD + q * 4] = v;
  }
  __syncthreads();
#pragma unroll
  for (int i = 0; i < 2; i++) {
    int la = (t >> 3) + 32 * i;
    int g = t & 7;
    float inv = invl[la];
    const float* mr = &mean[la * MLD + g * 8];
    HU o;
#pragma unroll
    for (int j = 0; j < 8; j++) o.h[j] = (f16)(mr[j] * inv);
    int kc = g >> 2, lb = ((g & 3) << 4) + (la & 15), mtt = la >> 4;
    Af[(((mtt << 1) + kc) << 6) + lb] = o.u;
  }
  __syncthreads();
  int lane = t & 63, wid = t >> 6;
  HU af0, af1;
  af0.u = Af[((wid << 1) + 0) * 64 + lane];
  af1.u = Af[((wid << 1) + 1) * 64 + lane];
  const uint4* Wu = (const uint4*)Wp;
  int rowb = a0 + wid * 16 + ((lane >> 4) << 2);
#pragma unroll
  for (int nt = 0; nt < 4; nt++) {
    HU b0, b1;
    b0.u = Wu[((nt << 1) + 0) * 64 + lane];
    b1.u = Wu[((nt << 1) + 1) * 64 + lane];
    f32x4 z = {0.f, 0.f, 0.f, 0.f};
    z = __builtin_amdgcn_mfma_f32_16x16x32_f16(af0.h, b0.h, z, 0, 0, 0);
    z = __builtin_amdgcn_mfma_f32_16x16x32_f16(af1.h, b1.h, z, 0, 0, 0);
    int n = nt * 16 + (lane & 15);
    float bv = bl[n];
#pragma unroll
    for (int r = 0; r < 4; r++) {
      int atom = rowb + r;
      if (atom < NA) {
        float vv = z[r] + bv;
        vv = vv > 0.f ? vv : 0.f;
        x[(long)atom * 64 + n] += vv;
      }
    }
  }
}

// ---------------- batch mean: g1[b] = mean(x[a]) over CSR bucket ----------------

__global__ __launch_bounds__(256) void k_meanscatter(const float* src, const int* bucket,
                                                     const int* basea, const int* cnta,
                                                     float* dst, int nseg) {
  int wid = (blockIdx.x * 256 + threadIdx.x) >> 6;
  int lane = threadIdx.x & 63;
  if (wid >= nseg) return;
  int b0 = basea[wid], cnt = cnta[wid];
  float s = 0.f;
  for (int i = 0; i < cnt; i++) {
    int e = bucket[b0 + i];
    s += src[(long)e * 64 + lane];
  }
  dst[(long)wid * 64 + lane] = s / (float)(cnt > 0 ? cnt : 1);
}

// ---------------- head gemm: g2 = relu(g1 @ W + b) ----------------

__global__ __launch_bounds__(256) void k_head(const float* g1, const float* W,
                                              const float* bias, float* g2) {
  __shared__ float Wl[4096];
  __shared__ float inl[32 * 64];
  __shared__ float bl[64];
  int t = threadIdx.x;
  int brow = blockIdx.x * 32;
#pragma unroll
  for (int i = 0; i < 4; i++) ((float4*)Wl)[t + 256 * i] = ((const float4*)W)[t + 256 * i];
  if (t < 64) bl[t] = bias[t];
  __syncthreads();
#pragma unroll
  for (int i = 0; i < 2; i++) {
    int idx = t + 256 * i;
    int r = idx >> 4, q = idx & 15;
    ((float4*)inl)[idx] = ((const float4*)(g1 + (long)(brow + r) * 64))[q];
  }
  __syncthreads();
  int c = t & 63, rq = t >> 6;
  float acc[8];
#pragma unroll
  for (int i = 0; i < 8; i++) acc[i] = 0.f;
  for (int j = 0; j < 64; j += 4) {
    float w0 = Wl[(j + 0) * 64 + c], w1 = Wl[(j + 1) * 64 + c];
    float w2 = Wl[(j + 2) * 64 + c], w3 = Wl[(j + 3) * 64 + c];
#pragma unroll
    for (int i = 0; i < 8; i++) {
      int r = rq * 8 + i;
      float4 v = *(const float4*)&inl[r * 64 + j];
      acc[i] += v.x * w0 + v.y * w1 + v.z * w2 + v.w * w3;
    }
  }
#pragma unroll
  for (int i = 0; i < 8; i++) {
    long r = brow + rq * 8 + i;
    float v = acc[i] + bl[c];
    g2[r * 64 + c] = v > 0.f ? v : 0.f;
  }
}

__global__ __launch_bounds__(256) void k_final(const float* g2, const float* linW,
                                               const float* linb, float* out) {
  int wid = (blockIdx.x * 256 + threadIdx.x) >> 6;
  int lane = threadIdx.x & 63;
  if (wid >= NBATCH) return;
  float v = g2[(long)wid * 64 + lane] * linW[lane];
  for (int o = 32; o > 0; o >>= 1) v += __shfl_down(v, o, 64);
  if (lane == 0) out[wid] = v + linb[0];
}

__global__ __launch_bounds__(256) void k_zero_out(float* out, int n) {
  for (int i = blockIdx.x * 256 + threadIdx.x; i < n; i += gridDim.x * 256) out[i] = 0.f;
}

// ---------------- launcher ----------------

extern "C" void kernel_launch(void* const* d_in, const int* in_sizes, int n_in,
                              void* d_out, int out_size, void* d_ws, size_t ws_size,
                              hipStream_t stream) {
  (void)in_sizes; (void)n_in;

  const int* x_atom = (const int*)d_in[0];
  const int* vals[5] = {(const int*)d_in[1], (const int*)d_in[4], (const int*)d_in[7],
                        (const int*)d_in[10], (const int*)d_in[13]};
  const int* rowm[5] = {(const int*)d_in[2], (const int*)d_in[5], (const int*)d_in[8],
                        (const int*)d_in[11], (const int*)d_in[14]};
  const int* batch = (const int*)d_in[16];
  const float* aemb0 = (const float*)d_in[17];
  const float* aemb1 = (const float*)d_in[18];
  const float* aemb2 = (const float*)d_in[19];
  const float* path_emb = (const float*)d_in[20];
  const float* cycle_emb = (const float*)d_in[21];
  const float* pW_a2p = (const float*)d_in[22];
  const float* pb_a2p = (const float*)d_in[23];
  const float* pW_p2a = (const float*)d_in[24];
  const float* pb_p2a = (const float*)d_in[25];
  const float* pK = (const float*)d_in[26];
  const float* pKb = (const float*)d_in[27];
  const float* cW_a2p = (const float*)d_in[28];
  const float* cb_a2p = (const float*)d_in[29];
  const float* cW_p2a = (const float*)d_in[30];
  const float* cb_p2a = (const float*)d_in[31];
  const float* cK = (const float*)d_in[32];
  const float* cKb = (const float*)d_in[33];
  const float* alW = (const float*)d_in[34];
  const float* alb = (const float*)d_in[35];
  const float* linW = (const float*)d_in[36];
  const float* linb = (const float*)d_in[37];

  static const int Em[5] = {300000, 400000, 500000, 200000, 240000};
  static const int Km[5] = {3, 4, 5, 5, 6};
  static const int Ppb[5] = {32, 24, 16, 16, 16};  // paths/block -> R in {96,96,80,80,96}
  const int CNT_N = 5 * 100000 + NBATCH;  // 504096
  const int ACC_ROWS = 100032;            // padded to block grid (1563*64)

  char* ws = (char*)d_ws;
  size_t off = 0;
  auto alloc = [&](size_t nbytes) -> char* {
    char* p = ws + off;
    off = (off + nbytes + 255) & ~(size_t)255;
    return p;
  };
  float* x = (float*)alloc((size_t)NA * 64 * 4);
  __half* xp[5];
  for (int m = 0; m < 5; m++) xp[m] = (__half*)alloc((size_t)Em[m] * 64 * 2);
  float* acc = (float*)alloc((size_t)ACC_ROWS * 64 * 4);
  float* g1 = (float*)alloc((size_t)NBATCH * 64 * 4);
  float* g2 = (float*)alloc((size_t)NBATCH * 64 * 4);
  int* cnt = (int*)alloc((size_t)CNT_N * 4);
  int* basea_b = (int*)alloc((size_t)(NBATCH + 1) * 4);
  int* cursor_b = (int*)alloc((size_t)NBATCH * 4);
  int* bucket = (int*)alloc((size_t)NA * 4);
  f16* Bp = (f16*)alloc((size_t)10 * 12288 * 2);  // prepacked conv kernels
  f16* Wpk = (f16*)alloc((size_t)20 * 4096 * 2);  // prepacked p2a+a2p weights

  if (ws_size < off) {  // workspace too small: emit readable failure, not a fault
    k_zero_out<<<16, 256, 0, stream>>>((float*)d_out, out_size);
    return;
  }

  // ---- counts (all maps + batch) and batch CSR
  MapsParams mp;
  {
    int s = 0;
    for (int m = 0; m < 5; m++) {
      mp.row[m] = rowm[m]; mp.cnt_off[m] = m * 100000;
      mp.start[m] = s; s += Em[m];
    }
    mp.row[5] = batch; mp.cnt_off[5] = 500000; mp.start[5] = s;
    mp.total = s + NA;
  }
  hipMemsetAsync(cnt, 0, (size_t)CNT_N * 4, stream);
  hipMemsetAsync(acc, 0, (size_t)ACC_ROWS * 64 * 4, stream);
  k_count<<<2048, 256, 0, stream>>>(mp, cnt);
  k_scan_batch<<<1, 256, 0, stream>>>(cnt + 500000, basea_b);
  hipMemcpyAsync(cursor_b, basea_b, (size_t)NBATCH * 4, hipMemcpyDeviceToDevice, stream);
  k_fill_batch<<<128, 256, 0, stream>>>(batch, cursor_b, bucket);

  // ---- prepack weights + feature init
  k_prepB<<<480, 256, 0, stream>>>(pK, cK, Bp);
  k_prepW<<<320, 256, 0, stream>>>(pW_p2a, cW_p2a, pW_a2p, cW_a2p, Wpk);
  k_atom_init<<<NA * 16 / 256, 256, 0, stream>>>(x_atom, aemb0, aemb1, aemb2, x);
  {
    PInit pp;
    int s8 = 0;
    for (int m = 0; m < 5; m++) {
      pp.dst[m] = xp[m];
      pp.vals[m] = vals[m];
      pp.tab[m] = (m < 3) ? (path_emb + m * 6 * 64) : (cycle_emb + (m - 3) * 4 * 64);
      pp.start8[m] = s8;
      s8 += Em[m] * 8;
    }
    pp.total8 = s8;
    k_path_init<<<8192, 256, 0, stream>>>(pp);
  }

  int apply_blocks = ACC_ROWS / 64;  // 1563

  // ---- layers
  for (int l = 0; l < 2; l++) {
    // === paths group (maps 0..2), non-cyclic
    {
      A2pParams gp{};
      gp.nseg = 3; gp.x = x;
      int bs = 0;
      for (int m = 0; m < 3; m++) {
        gp.gidx[m] = rowm[m]; gp.out[m] = xp[m];
        gp.Wp[m] = Wpk + (size_t)(10 + l * 3 + m) * 4096;
        gp.bias[m] = pb_a2p + (l * 3 + m) * 64;
        gp.rows[m] = Em[m];
        gp.blk_start[m] = bs;
        bs += (Em[m] + 63) / 64;
      }
      k_a2p<<<bs, 256, 0, stream>>>(gp);

      ConvParams cp{};
      cp.nseg = 3; cp.cyclic = 0;
      int cbs = 0;
      for (int m = 0; m < 3; m++) {
        cp.buf[m] = (f16*)xp[m];
        cp.Bp[m] = Bp + (size_t)(l * 3 + m) * 12288;
        cp.Kb[m] = pKb + (l * 3 + m) * 64;
        cp.k[m] = Km[m]; cp.P[m] = Em[m] / Km[m]; cp.ppb[m] = Ppb[m];
        cp.blk_start[m] = cbs;
        cbs += (cp.P[m] + cp.ppb[m] - 1) / cp.ppb[m];
      }
      k_conv<<<cbs, 256, 0, stream>>>(cp);

      for (int m = 0; m < 3; m++) {
        k_scatter<<<1024, 256, 0, stream>>>((const f16*)xp[m], rowm[m], acc, Em[m]);
        k_apply<<<apply_blocks, 256, 0, stream>>>(acc, cnt + m * 100000,
                                                  Wpk + (size_t)(l * 3 + m) * 4096,
                                                  pb_p2a + (l * 3 + m) * 64, x);
      }
    }
    // === cycles group (maps 3..4), cyclic
    {
      A2pParams gp{};
      gp.nseg = 2; gp.x = x;
      int bs = 0;
      for (int m = 3; m < 5; m++) {
        int i = m - 3;
        gp.gidx[i] = rowm[m]; gp.out[i] = xp[m];
        gp.Wp[i] = Wpk + (size_t)(16 + l * 2 + i) * 4096;
        gp.bias[i] = cb_a2p + (l * 2 + i) * 64;
        gp.rows[i] = Em[m];
        gp.blk_start[i] = bs;
        bs += (Em[m] + 63) / 64;
      }
      k_a2p<<<bs, 256, 0, stream>>>(gp);

      ConvParams cp{};
      cp.nseg = 2; cp.cyclic = 1;
      int cbs = 0;
      for (int m = 3; m < 5; m++) {
        int i = m - 3;
        cp.buf[i] = (f16*)xp[m];
        cp.Bp[i] = Bp + (size_t)(6 + l * 2 + i) * 12288;
        cp.Kb[i] = cKb + (l * 2 + i) * 64;
        cp.k[i] = Km[m]; cp.P[i] = Em[m] / Km[m]; cp.ppb[i] = Ppb[m];
        cp.blk_start[i] = cbs;
        cbs += (cp.P[i] + cp.ppb[i] - 1) / cp.ppb[i];
      }
      k_conv<<<cbs, 256, 0, stream>>>(cp);

      for (int m = 3; m < 5; m++) {
        int i = m - 3;
        k_scatter<<<1024, 256, 0, stream>>>((const f16*)xp[m], rowm[m], acc, Em[m]);
        k_apply<<<apply_blocks, 256, 0, stream>>>(acc, cnt + m * 100000,
                                                  Wpk + (size_t)(6 + l * 2 + i) * 4096,
                                                  cb_p2a + (l * 2 + i) * 64, x);
      }
    }
  }

  // ---- head
  k_meanscatter<<<NBATCH / 4, 256, 0, stream>>>(x, bucket, basea_b, cnt + 500000,
                                                g1, NBATCH);
  k_head<<<NBATCH / 32, 256, 0, stream>>>(g1, alW, alb, g2);
  k_final<<<NBATCH / 4, 256, 0, stream>>>(g2, linW, linb, (float*)d_out);
}

// Round 11
// 1411.567 us; speedup vs baseline: 2.1627x; 1.2711x over previous
//
#include <hip/hip_runtime.h>
#include <hip/hip_fp16.h>

#define NA 100000
#define NBATCH 4096
#define MLD 68
#define CLD 68

typedef _Float16 f16;
typedef f16 half8 __attribute__((ext_vector_type(8)));
typedef float f32x4 __attribute__((ext_vector_type(4)));
union H8 { uint4 u; __half h[8]; };
union HU { uint4 u; half8 h; f16 s[8]; };

// packed f16 atomic add: HIP has no atomicAdd(__half2*); use the HW pk_add_f16 path.
__device__ inline void pk_atomic_add(__half2* addr, __half2 v) {
#if __has_builtin(__builtin_amdgcn_flat_atomic_fadd_v2f16)
  typedef _Float16 hv2 __attribute__((ext_vector_type(2)));
  __builtin_amdgcn_flat_atomic_fadd_v2f16((hv2*)addr, *(hv2*)&v);
#else
  unsafeAtomicAdd(addr, v);
#endif
}

// ---------------- counts (all 5 maps + batch) ----------------

struct MapsParams {
  const int* row[6];
  int cnt_off[6];
  int start[6];
  int total;
};

__global__ __launch_bounds__(256) void k_count(MapsParams mp, int* cnt) {
  for (int g = blockIdx.x * 256 + threadIdx.x; g < mp.total; g += gridDim.x * 256) {
    int m = 0;
#pragma unroll
    for (int i = 1; i < 6; i++) if (g >= mp.start[i]) m = i;
    int e = g - mp.start[m];
    atomicAdd(&cnt[mp.cnt_off[m] + mp.row[m][e]], 1);
  }
}

// single-block exclusive scan of the 4096 batch counts
__global__ __launch_bounds__(256) void k_scan_batch(const int* cntb, int* basea) {
  __shared__ int s[256];
  int t = threadIdx.x;
  int carry = 0;
  for (int c0 = 0; c0 < NBATCH; c0 += 256) {
    int v = cntb[c0 + t];
    s[t] = v;
    __syncthreads();
    for (int d = 1; d < 256; d <<= 1) {
      int x = (t >= d) ? s[t - d] : 0;
      __syncthreads();
      s[t] += x;
      __syncthreads();
    }
    basea[c0 + t] = s[t] - v + carry;
    int tot = s[255];
    __syncthreads();
    carry += tot;
  }
}

__global__ __launch_bounds__(256) void k_fill_batch(const int* batch, int* cursor, int* bucket) {
  for (int a = blockIdx.x * 256 + threadIdx.x; a < NA; a += gridDim.x * 256) {
    int b = batch[a];
    int pos = atomicAdd(&cursor[b], 1);
    bucket[pos] = a;
  }
}

// ---------------- feature init ----------------

__global__ __launch_bounds__(256) void k_atom_init(const int* xa, const float* e0,
                                                   const float* e1, const float* e2, float* x) {
  int idx = blockIdx.x * 256 + threadIdx.x;  // float4 index
  if (idx >= NA * 16) return;
  int a = idx >> 4, q = idx & 15;
  int f0 = xa[a * 3], f1 = xa[a * 3 + 1], f2 = xa[a * 3 + 2];
  float4 v0 = ((const float4*)e0)[f0 * 16 + q];
  float4 v1 = ((const float4*)e1)[f1 * 16 + q];
  float4 v2 = ((const float4*)e2)[f2 * 16 + q];
  float4 o;
  o.x = v0.x + v1.x + v2.x; o.y = v0.y + v1.y + v2.y;
  o.z = v0.z + v1.z + v2.z; o.w = v0.w + v1.w + v2.w;
  ((float4*)x)[idx] = o;
}

struct PInit {
  __half* dst[5];
  const int* vals[5];
  const float* tab[5];
  int start8[5];  // cumulative half8-chunk starts
  int total8;
};

__global__ __launch_bounds__(256) void k_path_init(PInit pp) {
  for (int g = blockIdx.x * 256 + threadIdx.x; g < pp.total8; g += gridDim.x * 256) {
    int m = 0;
#pragma unroll
    for (int i = 1; i < 5; i++) if (g >= pp.start8[i]) m = i;
    int lc = g - pp.start8[m];
    int e = lc >> 3, q = lc & 7;
    int v = pp.vals[m][e];
    const float* src = pp.tab[m] + v * 64 + q * 8;
    H8 o;
#pragma unroll
    for (int j = 0; j < 8; j++) o.h[j] = __float2half(src[j]);
    ((uint4*)pp.dst[m])[lc] = o.u;
  }
}

// ---------------- prepack conv kernels to fp16 MFMA-B layout ----------------

__global__ __launch_bounds__(256) void k_prepB(const float* pK, const float* cK, f16* Bp) {
  int tid = blockIdx.x * 256 + threadIdx.x;
  if (tid >= 10 * 12288) return;
  int set = tid / 12288, pos = tid % 12288;
  int j = pos & 7, lane = (pos >> 3) & 63, kcnt = pos >> 9;
  int kc = kcnt % 6, nt = kcnt / 6;
  int k = kc * 32 + ((lane >> 4) << 3) + j;
  int n = (nt << 4) + (lane & 15);
  int w = k >> 6, ji = k & 63;
  const float* K = (set < 6) ? (pK + set * 3 * 4096) : (cK + (set - 6) * 3 * 4096);
  float v = K[w * 4096 + ji * 64 + n];
  if (set >= 6) v = 0.5f * (v + K[(2 - w) * 4096 + ji * 64 + n]);
  Bp[tid] = (f16)v;
}

// ---------------- prepack 64x64 weights to fp16 MFMA-B layout ----------------
// sets 0..5 pW_p2a, 6..9 cW_p2a, 10..15 pW_a2p, 16..19 cW_a2p

__global__ __launch_bounds__(256) void k_prepW(const float* pW, const float* cW,
                                               const float* pWa, const float* cWa, f16* Wp) {
  int tid = blockIdx.x * 256 + threadIdx.x;
  if (tid >= 20 * 4096) return;
  int set = tid >> 12, pos = tid & 4095;
  int j = pos & 7, lane = (pos >> 3) & 63, ntkc = pos >> 9;
  int kc = ntkc & 1, nt = ntkc >> 1;
  int k = kc * 32 + ((lane >> 4) << 3) + j;
  int n = (nt << 4) + (lane & 15);
  const float* W;
  if (set < 6) W = pW + set * 4096;
  else if (set < 10) W = cW + (set - 6) * 4096;
  else if (set < 16) W = pWa + (set - 10) * 4096;
  else W = cWa + (set - 16) * 4096;
  Wp[tid] = (f16)W[k * 64 + n];
}

// ---------------- a2p (MFMA): xp = xp + relu(gather(x) @ W + b) ----------------
// block = 64 edges; fp32 gather converted into A-frag layout; B-frags from global.

struct A2pParams {
  const float* x;
  const int* gidx[3];
  __half* out[3];
  const f16* Wp[3];
  const float* bias[3];
  int rows[3];
  int blk_start[3];
  int nseg;
};

__global__ __launch_bounds__(256) void k_a2p(A2pParams p) {
  __shared__ uint4 Af[512];        // 8KB: 4 m-tiles x 2 kc x 64 lanes
  __shared__ float Cf[64 * CLD];   // 17.4KB fp32 result, stride-68
  __shared__ float bl[64];
  __shared__ int ridx[64];
  int bid = blockIdx.x;
  int seg = 0;
#pragma unroll
  for (int i = 1; i < 3; i++) if (i < p.nseg && bid >= p.blk_start[i]) seg = i;
  int E = p.rows[seg];
  int brow = (bid - p.blk_start[seg]) * 64;
  int rowsv = min(64, E - brow);
  int t = threadIdx.x;
  if (t < 64) {
    int e = brow + t;
    ridx[t] = (e < E) ? p.gidx[seg][e] : 0;
    bl[t] = p.bias[seg][t];
  }
  __syncthreads();
  // gather fp32 x rows -> f16 A-frag layout
  const float4* x4 = (const float4*)p.x;
#pragma unroll
  for (int i = 0; i < 2; i++) {
    int idx = t + 256 * i;            // 0..511
    int la = idx >> 3, g = idx & 7;   // row-in-block, 8-half chunk
    long base = (long)ridx[la] * 16 + g * 2;
    float4 v0 = x4[base];
    float4 v1 = x4[base + 1];
    HU o;
    o.s[0] = (f16)v0.x; o.s[1] = (f16)v0.y; o.s[2] = (f16)v0.z; o.s[3] = (f16)v0.w;
    o.s[4] = (f16)v1.x; o.s[5] = (f16)v1.y; o.s[6] = (f16)v1.z; o.s[7] = (f16)v1.w;
    Af[(((la >> 4) << 1) + (g >> 2)) * 64 + (((g & 3) << 4) + (la & 15))] = o.u;
  }
  __syncthreads();
  int lane = t & 63, wid = t >> 6;
  HU af0, af1;
  af0.u = Af[((wid << 1) + 0) * 64 + lane];
  af1.u = Af[((wid << 1) + 1) * 64 + lane];
  const uint4* Wu = (const uint4*)p.Wp[seg];
#pragma unroll
  for (int nt = 0; nt < 4; nt++) {
    HU b0, b1;
    b0.u = Wu[((nt << 1) + 0) * 64 + lane];
    b1.u = Wu[((nt << 1) + 1) * 64 + lane];
    f32x4 z = {0.f, 0.f, 0.f, 0.f};
    z = __builtin_amdgcn_mfma_f32_16x16x32_f16(af0.h, b0.h, z, 0, 0, 0);
    z = __builtin_amdgcn_mfma_f32_16x16x32_f16(af1.h, b1.h, z, 0, 0, 0);
    int n = (nt << 4) + (lane & 15);
    float bv = bl[n];
    int rb = (wid << 4) + ((lane >> 4) << 2);
#pragma unroll
    for (int r = 0; r < 4; r++) {
      float vv = z[r] + bv;
      Cf[(rb + r) * CLD + n] = vv > 0.f ? vv : 0.f;
    }
  }
  __syncthreads();
  // residual add + store (coalesced uint4 over xp)
  __half* out = p.out[seg];
  uint4* out4 = (uint4*)(out + (long)brow * 64);
#pragma unroll
  for (int i = 0; i < 2; i++) {
    int idx = t + 256 * i;
    int r = idx >> 3, g = idx & 7;
    if (r < rowsv) {
      HU res; res.u = out4[idx];
      const float* c = &Cf[r * CLD + g * 8];
      HU o;
#pragma unroll
      for (int j = 0; j < 8; j++) o.s[j] = (f16)((float)res.s[j] + c[j]);
      out4[idx] = o.u;
    }
  }
}

// ---------------- MFMA conv v3: buf = pre + relu([Rx192]@[192x64] + Kb) ----------------
// B-frags from global; epilogue via fp32 Cf aliased into Apk; coalesced residual+store.

struct ConvParams {
  f16* buf[3];
  const f16* Bp[3];
  const float* Kb[3];
  int k[3];
  int P[3];
  int ppb[3];
  int blk_start[3];
  int nseg;
  int cyclic;
};

__global__ __launch_bounds__(256) void k_conv(ConvParams p) {
  __shared__ uint4 Apk[2304];  // 36.9KB; after MFMA reads, reused as fp32 Cf (R*68 <= 6528 fl)
  __shared__ float kbl[64];
  int bid = blockIdx.x;
  int seg = 0;
#pragma unroll
  for (int i = 1; i < 3; i++) if (i < p.nseg && bid >= p.blk_start[i]) seg = i;
  int kk = p.k[seg], ppb = p.ppb[seg], P = p.P[seg];
  f16* buf = p.buf[seg];
  int t = threadIdx.x;
  int p0 = (bid - p.blk_start[seg]) * ppb;
  int np = min(ppb, P - p0);
  int R = np * kk;       // multiple of 16
  int mtb = R >> 4;      // m-tiles: 4..6
  long ebase = (long)p0 * kk;
  if (t < 64) kbl[t] = p.Kb[seg][t];
  {
    uint4 z; z.x = z.y = z.z = z.w = 0;
    int nU = mtb * 384;
    for (int i = t; i < nU; i += 256) Apk[i] = z;
  }
  __syncthreads();
  {
    const uint4* src = (const uint4*)(buf + ebase * 64);
    int tot = R * 8;
    for (int idx = t; idx < tot; idx += 256) {
      int r = idx >> 3, jj = idx & 7;
      uint4 ch = src[idx];
      int s = r % kk;
      int kchi = jj >> 2, quad = jj & 3;
#pragma unroll
      for (int w = 0; w < 3; w++) {
        int rd;
        if (w == 1) rd = r;
        else if (w == 0) rd = (s + 1 < kk) ? r + 1 : (p.cyclic ? r + 1 - kk : -1);
        else rd = (s >= 1) ? r - 1 : (p.cyclic ? r + kk - 1 : -1);
        if (rd >= 0)
          Apk[((rd >> 4) * 6 + 2 * w + kchi) * 64 + quad * 16 + (rd & 15)] = ch;
      }
    }
  }
  __syncthreads();
  int lane = t & 63, wid = t >> 6;
  int wave_n = wid & 1, wave_m = wid >> 1;
  int mtA = (mtb + 1) >> 1;
  int m0 = wave_m ? mtA : 0;
  int mcnt = wave_m ? (mtb - mtA) : mtA;  // <= 3
  f32x4 acc[3][2];
#pragma unroll
  for (int i = 0; i < 3; i++)
#pragma unroll
    for (int jn = 0; jn < 2; jn++) {
      f32x4 z = {0.f, 0.f, 0.f, 0.f};
      acc[i][jn] = z;
    }
  const uint4* Bg = (const uint4*)p.Bp[seg];
  for (int kc = 0; kc < 6; kc++) {
    HU a[3], b[2];
#pragma unroll
    for (int jn = 0; jn < 2; jn++)
      b[jn].u = Bg[((wave_n * 2 + jn) * 6 + kc) * 64 + lane];
#pragma unroll
    for (int i = 0; i < 3; i++)
      if (i < mcnt) a[i].u = Apk[((m0 + i) * 6 + kc) * 64 + lane];
#pragma unroll
    for (int i = 0; i < 3; i++)
      if (i < mcnt) {
#pragma unroll
        for (int jn = 0; jn < 2; jn++)
          acc[i][jn] = __builtin_amdgcn_mfma_f32_16x16x32_f16(a[i].h, b[jn].h, acc[i][jn], 0, 0, 0);
      }
  }
  __syncthreads();  // all Apk reads done; reuse as Cf
  float* Cf = (float*)Apk;
#pragma unroll
  for (int i = 0; i < 3; i++) {
    if (i >= mcnt) continue;
    int mt = m0 + i;
#pragma unroll
    for (int jn = 0; jn < 2; jn++) {
      int n = (wave_n * 2 + jn) * 16 + (lane & 15);
      float bv = kbl[n];
      int rb = mt * 16 + ((lane >> 4) << 2);
#pragma unroll
      for (int reg = 0; reg < 4; reg++) {
        float v = acc[i][jn][reg] + bv;
        Cf[(rb + reg) * CLD + n] = v > 0.f ? v : 0.f;
      }
    }
  }
  __syncthreads();
  // coalesced residual read + final store
  uint4* bufg = (uint4*)(buf + ebase * 64);
  int tot = R * 8;
  for (int idx = t; idx < tot; idx += 256) {
    int r = idx >> 3, g = idx & 7;
    HU res; res.u = bufg[idx];
    const float* c = &Cf[r * CLD + g * 8];
    HU o;
#pragma unroll
    for (int j = 0; j < 8; j++) o.s[j] = (f16)((float)res.s[j] + c[j]);
    bufg[idx] = o.u;
  }
}

// ---------------- p2a scatter: acc[row[e]] += xp[e] (packed f16 global atomics) ----------
// wave = 2 edges x 32 half2 lanes; 8 edges per unrolled iteration; coalesced reads.

__global__ __launch_bounds__(256) void k_scatter(const f16* xp, const int* row,
                                                 __half2* acc, int E) {
  int gw = (blockIdx.x * 256 + threadIdx.x) >> 6;
  int half = (threadIdx.x >> 5) & 1;
  int l = threadIdx.x & 31;
  int nw = (gridDim.x * 256) >> 6;
  const unsigned int* xpu = (const unsigned int*)xp;
  for (int e0 = gw * 8; e0 < E; e0 += nw * 8) {
    int e[4]; unsigned int v[4]; int a[4];
#pragma unroll
    for (int u = 0; u < 4; u++) e[u] = e0 + 2 * u + half;
#pragma unroll
    for (int u = 0; u < 4; u++) v[u] = xpu[(long)e[u] * 32 + l];
#pragma unroll
    for (int u = 0; u < 4; u++) a[u] = row[e[u]];
#pragma unroll
    for (int u = 0; u < 4; u++) {
      __half2 hv = *(__half2*)&v[u];
      pk_atomic_add(&acc[(long)a[u] * 32 + l], hv);
    }
  }
}

// ---------------- p2a apply: x += relu(acc/cnt @ W + b); self-zeroes f16 acc ----------------

__global__ __launch_bounds__(256) void k_apply(f16* acc, const int* cnt, const f16* Wp,
                                               const float* bias, float* x) {
  __shared__ float mean[64 * MLD];  // 17.4KB
  __shared__ uint4 Af[512];         // 8KB fp16 A-frags
  __shared__ float invl[64];
  __shared__ float bl[64];
  int t = threadIdx.x;
  int a0 = blockIdx.x * 64;
  if (t < 64) {
    int cb = cnt[a0 + t];
    invl[t] = 1.f / (float)(cb > 0 ? cb : 1);
    bl[t] = bias[t];
  }
  uint4* acc4 = (uint4*)acc;  // 8 halves per uint4; 64 rows x 8 = 512 per tile
#pragma unroll
  for (int i = 0; i < 2; i++) {
    int idx = t + 256 * i;
    int r = idx >> 3, q = idx & 7;
    HU v; v.u = acc4[(long)a0 * 8 + idx];
    uint4 z4; z4.x = z4.y = z4.z = z4.w = 0;
    acc4[(long)a0 * 8 + idx] = z4;  // ready for next map
    float* mr = &mean[r * MLD + q * 8];
#pragma unroll
    for (int j = 0; j < 8; j++) mr[j] = (float)v.s[j];
  }
  __syncthreads();
#pragma unroll
  for (int i = 0; i < 2; i++) {
    int la = (t >> 3) + 32 * i;
    int g = t & 7;
    float inv = invl[la];
    const float* mr = &mean[la * MLD + g * 8];
    HU o;
#pragma unroll
    for (int j = 0; j < 8; j++) o.h[j] = (f16)(mr[j] * inv);
    int kc = g >> 2, lb = ((g & 3) << 4) + (la & 15), mtt = la >> 4;
    Af[(((mtt << 1) + kc) << 6) + lb] = o.u;
  }
  __syncthreads();
  int lane = t & 63, wid = t >> 6;
  HU af0, af1;
  af0.u = Af[((wid << 1) + 0) * 64 + lane];
  af1.u = Af[((wid << 1) + 1) * 64 + lane];
  const uint4* Wu = (const uint4*)Wp;
  int rowb = a0 + wid * 16 + ((lane >> 4) << 2);
#pragma unroll
  for (int nt = 0; nt < 4; nt++) {
    HU b0, b1;
    b0.u = Wu[((nt << 1) + 0) * 64 + lane];
    b1.u = Wu[((nt << 1) + 1) * 64 + lane];
    f32x4 z = {0.f, 0.f, 0.f, 0.f};
    z = __builtin_amdgcn_mfma_f32_16x16x32_f16(af0.h, b0.h, z, 0, 0, 0);
    z = __builtin_amdgcn_mfma_f32_16x16x32_f16(af1.h, b1.h, z, 0, 0, 0);
    int n = nt * 16 + (lane & 15);
    float bv = bl[n];
#pragma unroll
    for (int r = 0; r < 4; r++) {
      int atom = rowb + r;
      if (atom < NA) {
        float vv = z[r] + bv;
        vv = vv > 0.f ? vv : 0.f;
        x[(long)atom * 64 + n] += vv;
      }
    }
  }
}

// ---------------- batch mean: g1[b] = mean(x[a]) over CSR bucket ----------------

__global__ __launch_bounds__(256) void k_meanscatter(const float* src, const int* bucket,
                                                     const int* basea, const int* cnta,
                                                     float* dst, int nseg) {
  int wid = (blockIdx.x * 256 + threadIdx.x) >> 6;
  int lane = threadIdx.x & 63;
  if (wid >= nseg) return;
  int b0 = basea[wid], cnt = cnta[wid];
  float s = 0.f;
  for (int i = 0; i < cnt; i++) {
    int e = bucket[b0 + i];
    s += src[(long)e * 64 + lane];
  }
  dst[(long)wid * 64 + lane] = s / (float)(cnt > 0 ? cnt : 1);
}

// ---------------- head gemm: g2 = relu(g1 @ W + b) ----------------

__global__ __launch_bounds__(256) void k_head(const float* g1, const float* W,
                                              const float* bias, float* g2) {
  __shared__ float Wl[4096];
  __shared__ float inl[32 * 64];
  __shared__ float bl[64];
  int t = threadIdx.x;
  int brow = blockIdx.x * 32;
#pragma unroll
  for (int i = 0; i < 4; i++) ((float4*)Wl)[t + 256 * i] = ((const float4*)W)[t + 256 * i];
  if (t < 64) bl[t] = bias[t];
  __syncthreads();
#pragma unroll
  for (int i = 0; i < 2; i++) {
    int idx = t + 256 * i;
    int r = idx >> 4, q = idx & 15;
    ((float4*)inl)[idx] = ((const float4*)(g1 + (long)(brow + r) * 64))[q];
  }
  __syncthreads();
  int c = t & 63, rq = t >> 6;
  float acc[8];
#pragma unroll
  for (int i = 0; i < 8; i++) acc[i] = 0.f;
  for (int j = 0; j < 64; j += 4) {
    float w0 = Wl[(j + 0) * 64 + c], w1 = Wl[(j + 1) * 64 + c];
    float w2 = Wl[(j + 2) * 64 + c], w3 = Wl[(j + 3) * 64 + c];
#pragma unroll
    for (int i = 0; i < 8; i++) {
      int r = rq * 8 + i;
      float4 v = *(const float4*)&inl[r * 64 + j];
      acc[i] += v.x * w0 + v.y * w1 + v.z * w2 + v.w * w3;
    }
  }
#pragma unroll
  for (int i = 0; i < 8; i++) {
    long r = brow + rq * 8 + i;
    float v = acc[i] + bl[c];
    g2[r * 64 + c] = v > 0.f ? v : 0.f;
  }
}

__global__ __launch_bounds__(256) void k_final(const float* g2, const float* linW,
                                               const float* linb, float* out) {
  int wid = (blockIdx.x * 256 + threadIdx.x) >> 6;
  int lane = threadIdx.x & 63;
  if (wid >= NBATCH) return;
  float v = g2[(long)wid * 64 + lane] * linW[lane];
  for (int o = 32; o > 0; o >>= 1) v += __shfl_down(v, o, 64);
  if (lane == 0) out[wid] = v + linb[0];
}

__global__ __launch_bounds__(256) void k_zero_out(float* out, int n) {
  for (int i = blockIdx.x * 256 + threadIdx.x; i < n; i += gridDim.x * 256) out[i] = 0.f;
}

// ---------------- launcher ----------------

extern "C" void kernel_launch(void* const* d_in, const int* in_sizes, int n_in,
                              void* d_out, int out_size, void* d_ws, size_t ws_size,
                              hipStream_t stream) {
  (void)in_sizes; (void)n_in;

  const int* x_atom = (const int*)d_in[0];
  const int* vals[5] = {(const int*)d_in[1], (const int*)d_in[4], (const int*)d_in[7],
                        (const int*)d_in[10], (const int*)d_in[13]};
  const int* rowm[5] = {(const int*)d_in[2], (const int*)d_in[5], (const int*)d_in[8],
                        (const int*)d_in[11], (const int*)d_in[14]};
  const int* batch = (const int*)d_in[16];
  const float* aemb0 = (const float*)d_in[17];
  const float* aemb1 = (const float*)d_in[18];
  const float* aemb2 = (const float*)d_in[19];
  const float* path_emb = (const float*)d_in[20];
  const float* cycle_emb = (const float*)d_in[21];
  const float* pW_a2p = (const float*)d_in[22];
  const float* pb_a2p = (const float*)d_in[23];
  const float* pW_p2a = (const float*)d_in[24];
  const float* pb_p2a = (const float*)d_in[25];
  const float* pK = (const float*)d_in[26];
  const float* pKb = (const float*)d_in[27];
  const float* cW_a2p = (const float*)d_in[28];
  const float* cb_a2p = (const float*)d_in[29];
  const float* cW_p2a = (const float*)d_in[30];
  const float* cb_p2a = (const float*)d_in[31];
  const float* cK = (const float*)d_in[32];
  const float* cKb = (const float*)d_in[33];
  const float* alW = (const float*)d_in[34];
  const float* alb = (const float*)d_in[35];
  const float* linW = (const float*)d_in[36];
  const float* linb = (const float*)d_in[37];

  static const int Em[5] = {300000, 400000, 500000, 200000, 240000};
  static const int Km[5] = {3, 4, 5, 5, 6};
  static const int Ppb[5] = {32, 24, 16, 16, 16};  // paths/block -> R in {96,96,80,80,96}
  const int CNT_N = 5 * 100000 + NBATCH;  // 504096
  const int ACC_ROWS = 100032;            // padded to block grid (1563*64)

  char* ws = (char*)d_ws;
  size_t off = 0;
  auto alloc = [&](size_t nbytes) -> char* {
    char* p = ws + off;
    off = (off + nbytes + 255) & ~(size_t)255;
    return p;
  };
  float* x = (float*)alloc((size_t)NA * 64 * 4);
  __half* xp[5];
  for (int m = 0; m < 5; m++) xp[m] = (__half*)alloc((size_t)Em[m] * 64 * 2);
  f16* acc = (f16*)alloc((size_t)ACC_ROWS * 64 * 2);  // f16 accumulator
  float* g1 = (float*)alloc((size_t)NBATCH * 64 * 4);
  float* g2 = (float*)alloc((size_t)NBATCH * 64 * 4);
  int* cnt = (int*)alloc((size_t)CNT_N * 4);
  int* basea_b = (int*)alloc((size_t)(NBATCH + 1) * 4);
  int* cursor_b = (int*)alloc((size_t)NBATCH * 4);
  int* bucket = (int*)alloc((size_t)NA * 4);
  f16* Bp = (f16*)alloc((size_t)10 * 12288 * 2);  // prepacked conv kernels
  f16* Wpk = (f16*)alloc((size_t)20 * 4096 * 2);  // prepacked p2a+a2p weights

  if (ws_size < off) {  // workspace too small: emit readable failure, not a fault
    k_zero_out<<<16, 256, 0, stream>>>((float*)d_out, out_size);
    return;
  }

  // ---- counts (all maps + batch) and batch CSR
  MapsParams mp;
  {
    int s = 0;
    for (int m = 0; m < 5; m++) {
      mp.row[m] = rowm[m]; mp.cnt_off[m] = m * 100000;
      mp.start[m] = s; s += Em[m];
    }
    mp.row[5] = batch; mp.cnt_off[5] = 500000; mp.start[5] = s;
    mp.total = s + NA;
  }
  (void)hipMemsetAsync(cnt, 0, (size_t)CNT_N * 4, stream);
  (void)hipMemsetAsync(acc, 0, (size_t)ACC_ROWS * 64 * 2, stream);
  k_count<<<2048, 256, 0, stream>>>(mp, cnt);
  k_scan_batch<<<1, 256, 0, stream>>>(cnt + 500000, basea_b);
  (void)hipMemcpyAsync(cursor_b, basea_b, (size_t)NBATCH * 4, hipMemcpyDeviceToDevice, stream);
  k_fill_batch<<<128, 256, 0, stream>>>(batch, cursor_b, bucket);

  // ---- prepack weights + feature init
  k_prepB<<<480, 256, 0, stream>>>(pK, cK, Bp);
  k_prepW<<<320, 256, 0, stream>>>(pW_p2a, cW_p2a, pW_a2p, cW_a2p, Wpk);
  k_atom_init<<<NA * 16 / 256, 256, 0, stream>>>(x_atom, aemb0, aemb1, aemb2, x);
  {
    PInit pp;
    int s8 = 0;
    for (int m = 0; m < 5; m++) {
      pp.dst[m] = xp[m];
      pp.vals[m] = vals[m];
      pp.tab[m] = (m < 3) ? (path_emb + m * 6 * 64) : (cycle_emb + (m - 3) * 4 * 64);
      pp.start8[m] = s8;
      s8 += Em[m] * 8;
    }
    pp.total8 = s8;
    k_path_init<<<8192, 256, 0, stream>>>(pp);
  }

  int apply_blocks = ACC_ROWS / 64;  // 1563

  // ---- layers
  for (int l = 0; l < 2; l++) {
    // === paths group (maps 0..2), non-cyclic
    {
      A2pParams gp{};
      gp.nseg = 3; gp.x = x;
      int bs = 0;
      for (int m = 0; m < 3; m++) {
        gp.gidx[m] = rowm[m]; gp.out[m] = xp[m];
        gp.Wp[m] = Wpk + (size_t)(10 + l * 3 + m) * 4096;
        gp.bias[m] = pb_a2p + (l * 3 + m) * 64;
        gp.rows[m] = Em[m];
        gp.blk_start[m] = bs;
        bs += (Em[m] + 63) / 64;
      }
      k_a2p<<<bs, 256, 0, stream>>>(gp);

      ConvParams cp{};
      cp.nseg = 3; cp.cyclic = 0;
      int cbs = 0;
      for (int m = 0; m < 3; m++) {
        cp.buf[m] = (f16*)xp[m];
        cp.Bp[m] = Bp + (size_t)(l * 3 + m) * 12288;
        cp.Kb[m] = pKb + (l * 3 + m) * 64;
        cp.k[m] = Km[m]; cp.P[m] = Em[m] / Km[m]; cp.ppb[m] = Ppb[m];
        cp.blk_start[m] = cbs;
        cbs += (cp.P[m] + cp.ppb[m] - 1) / cp.ppb[m];
      }
      k_conv<<<cbs, 256, 0, stream>>>(cp);

      for (int m = 0; m < 3; m++) {
        k_scatter<<<1024, 256, 0, stream>>>((const f16*)xp[m], rowm[m], (__half2*)acc, Em[m]);
        k_apply<<<apply_blocks, 256, 0, stream>>>(acc, cnt + m * 100000,
                                                  Wpk + (size_t)(l * 3 + m) * 4096,
                                                  pb_p2a + (l * 3 + m) * 64, x);
      }
    }
    // === cycles group (maps 3..4), cyclic
    {
      A2pParams gp{};
      gp.nseg = 2; gp.x = x;
      int bs = 0;
      for (int m = 3; m < 5; m++) {
        int i = m - 3;
        gp.gidx[i] = rowm[m]; gp.out[i] = xp[m];
        gp.Wp[i] = Wpk + (size_t)(16 + l * 2 + i) * 4096;
        gp.bias[i] = cb_a2p + (l * 2 + i) * 64;
        gp.rows[i] = Em[m];
        gp.blk_start[i] = bs;
        bs += (Em[m] + 63) / 64;
      }
      k_a2p<<<bs, 256, 0, stream>>>(gp);

      ConvParams cp{};
      cp.nseg = 2; cp.cyclic = 1;
      int cbs = 0;
      for (int m = 3; m < 5; m++) {
        int i = m - 3;
        cp.buf[i] = (f16*)xp[m];
        cp.Bp[i] = Bp + (size_t)(6 + l * 2 + i) * 12288;
        cp.Kb[i] = cKb + (l * 2 + i) * 64;
        cp.k[i] = Km[m]; cp.P[i] = Em[m] / Km[m]; cp.ppb[i] = Ppb[m];
        cp.blk_start[i] = cbs;
        cbs += (cp.P[i] + cp.ppb[i] - 1) / cp.ppb[i];
      }
      k_conv<<<cbs, 256, 0, stream>>>(cp);

      for (int m = 3; m < 5; m++) {
        int i = m - 3;
        k_scatter<<<1024, 256, 0, stream>>>((const f16*)xp[m], rowm[m], (__half2*)acc, Em[m]);
        k_apply<<<apply_blocks, 256, 0, stream>>>(acc, cnt + m * 100000,
                                                  Wpk + (size_t)(6 + l * 2 + i) * 4096,
                                                  cb_p2a + (l * 2 + i) * 64, x);
      }
    }
  }

  // ---- head
  k_meanscatter<<<NBATCH / 4, 256, 0, stream>>>(x, bucket, basea_b, cnt + 500000,
                                                g1, NBATCH);
  k_head<<<NBATCH / 32, 256, 0, stream>>>(g1, alW, alb, g2);
  k_final<<<NBATCH / 4, 256, 0, stream>>>(g2, linW, linb, (float*)d_out);
}

// Round 12
// 1284.898 us; speedup vs baseline: 2.3759x; 1.0986x over previous
//
#include <hip/hip_runtime.h>
#include <hip/hip_fp16.h>

#define NA 100000
#define NBATCH 4096
#define MLD 68
#define CLD2 66

typedef _Float16 f16;
typedef f16 half8 __attribute__((ext_vector_type(8)));
typedef float f32x4 __attribute__((ext_vector_type(4)));
union H8 { uint4 u; __half h[8]; };
union HU { uint4 u; half8 h; f16 s[8]; };

// packed f16 atomic add: HIP has no atomicAdd(__half2*); use the HW pk_add_f16 path.
__device__ inline void pk_atomic_add(__half2* addr, __half2 v) {
#if __has_builtin(__builtin_amdgcn_flat_atomic_fadd_v2f16)
  typedef _Float16 hv2 __attribute__((ext_vector_type(2)));
  __builtin_amdgcn_flat_atomic_fadd_v2f16((hv2*)addr, *(hv2*)&v);
#else
  unsafeAtomicAdd(addr, v);
#endif
}

// ---------------- counts (all 5 maps + batch) ----------------

struct MapsParams {
  const int* row[6];
  int cnt_off[6];
  int start[6];
  int total;
};

__global__ __launch_bounds__(256) void k_count(MapsParams mp, int* cnt) {
  for (int g = blockIdx.x * 256 + threadIdx.x; g < mp.total; g += gridDim.x * 256) {
    int m = 0;
#pragma unroll
    for (int i = 1; i < 6; i++) if (g >= mp.start[i]) m = i;
    int e = g - mp.start[m];
    atomicAdd(&cnt[mp.cnt_off[m] + mp.row[m][e]], 1);
  }
}

__global__ __launch_bounds__(256) void k_scan_batch(const int* cntb, int* basea) {
  __shared__ int s[256];
  int t = threadIdx.x;
  int carry = 0;
  for (int c0 = 0; c0 < NBATCH; c0 += 256) {
    int v = cntb[c0 + t];
    s[t] = v;
    __syncthreads();
    for (int d = 1; d < 256; d <<= 1) {
      int x = (t >= d) ? s[t - d] : 0;
      __syncthreads();
      s[t] += x;
      __syncthreads();
    }
    basea[c0 + t] = s[t] - v + carry;
    int tot = s[255];
    __syncthreads();
    carry += tot;
  }
}

__global__ __launch_bounds__(256) void k_fill_batch(const int* batch, int* cursor, int* bucket) {
  for (int a = blockIdx.x * 256 + threadIdx.x; a < NA; a += gridDim.x * 256) {
    int b = batch[a];
    int pos = atomicAdd(&cursor[b], 1);
    bucket[pos] = a;
  }
}

// ---------------- feature init ----------------

__global__ __launch_bounds__(256) void k_atom_init(const int* xa, const float* e0,
                                                   const float* e1, const float* e2, float* x) {
  int idx = blockIdx.x * 256 + threadIdx.x;  // float4 index
  if (idx >= NA * 16) return;
  int a = idx >> 4, q = idx & 15;
  int f0 = xa[a * 3], f1 = xa[a * 3 + 1], f2 = xa[a * 3 + 2];
  float4 v0 = ((const float4*)e0)[f0 * 16 + q];
  float4 v1 = ((const float4*)e1)[f1 * 16 + q];
  float4 v2 = ((const float4*)e2)[f2 * 16 + q];
  float4 o;
  o.x = v0.x + v1.x + v2.x; o.y = v0.y + v1.y + v2.y;
  o.z = v0.z + v1.z + v2.z; o.w = v0.w + v1.w + v2.w;
  ((float4*)x)[idx] = o;
}

struct PInit {
  __half* dst[5];
  const int* vals[5];
  const float* tab[5];
  int start8[5];  // cumulative half8-chunk starts
  int total8;
};

__global__ __launch_bounds__(256) void k_path_init(PInit pp) {
  for (int g = blockIdx.x * 256 + threadIdx.x; g < pp.total8; g += gridDim.x * 256) {
    int m = 0;
#pragma unroll
    for (int i = 1; i < 5; i++) if (g >= pp.start8[i]) m = i;
    int lc = g - pp.start8[m];
    int e = lc >> 3, q = lc & 7;
    int v = pp.vals[m][e];
    const float* src = pp.tab[m] + v * 64 + q * 8;
    H8 o;
#pragma unroll
    for (int j = 0; j < 8; j++) o.h[j] = __float2half(src[j]);
    ((uint4*)pp.dst[m])[lc] = o.u;
  }
}

// ---------------- prepack conv kernels to fp16 MFMA-B layout ----------------

__global__ __launch_bounds__(256) void k_prepB(const float* pK, const float* cK, f16* Bp) {
  int tid = blockIdx.x * 256 + threadIdx.x;
  if (tid >= 10 * 12288) return;
  int set = tid / 12288, pos = tid % 12288;
  int j = pos & 7, lane = (pos >> 3) & 63, kcnt = pos >> 9;
  int kc = kcnt % 6, nt = kcnt / 6;
  int k = kc * 32 + ((lane >> 4) << 3) + j;
  int n = (nt << 4) + (lane & 15);
  int w = k >> 6, ji = k & 63;
  const float* K = (set < 6) ? (pK + set * 3 * 4096) : (cK + (set - 6) * 3 * 4096);
  float v = K[w * 4096 + ji * 64 + n];
  if (set >= 6) v = 0.5f * (v + K[(2 - w) * 4096 + ji * 64 + n]);
  Bp[tid] = (f16)v;
}

// ---------------- prepack 64x64 weights to fp16 MFMA-B layout ----------------
// sets 0..5 pW_p2a, 6..9 cW_p2a, 10..15 pW_a2p, 16..19 cW_a2p

__global__ __launch_bounds__(256) void k_prepW(const float* pW, const float* cW,
                                               const float* pWa, const float* cWa, f16* Wp) {
  int tid = blockIdx.x * 256 + threadIdx.x;
  if (tid >= 20 * 4096) return;
  int set = tid >> 12, pos = tid & 4095;
  int j = pos & 7, lane = (pos >> 3) & 63, ntkc = pos >> 9;
  int kc = ntkc & 1, nt = ntkc >> 1;
  int k = kc * 32 + ((lane >> 4) << 3) + j;
  int n = (nt << 4) + (lane & 15);
  const float* W;
  if (set < 6) W = pW + set * 4096;
  else if (set < 10) W = cW + (set - 6) * 4096;
  else if (set < 16) W = pWa + (set - 10) * 4096;
  else W = cWa + (set - 16) * 4096;
  Wp[tid] = (f16)W[k * 64 + n];
}

// ---------------- fused a2p+conv per map-group ----------------
// Block owns whole paths (R edges, mult of 16). Computes:
//   t = xp_old + relu(gather(x) @ Wa + ba)        (a2p)
//   xp_new = t + relu(conv3(t) @ K + Kb)          (conv, via [Rx192]@[192x64])
// One global read of xp_old, one global write of xp_new.

struct FusedParams {
  const float* x;
  const int* gidx[3];
  __half* xp[3];
  const f16* Wa[3];
  const float* ba[3];
  const f16* Bp[3];
  const float* Kb[3];
  int k[3];
  int P[3];
  int ppb[3];
  int blk_start[3];
  int nseg;
  int cyclic;
};

__global__ __launch_bounds__(256) void k_fused(FusedParams p) {
  __shared__ uint4 CfU[1584];   // 25.3KB: a2p A-frags (12.3KB), then fp32 C tile [96xCLD2]
  __shared__ uint4 xn4[873];    // 14KB: xnew f16, 97 rows x 9 uint4 (row 96 = zeros)
  __shared__ float bl[64], kbl[64];
  __shared__ int ridx[96];
  float* Cf = (float*)CfU;
  uint4* Af = CfU;
  int bid = blockIdx.x;
  int seg = 0;
#pragma unroll
  for (int i = 1; i < 3; i++) if (i < p.nseg && bid >= p.blk_start[i]) seg = i;
  int kk = p.k[seg], ppb = p.ppb[seg], P = p.P[seg];
  int cyc = p.cyclic;
  int t = threadIdx.x;
  int p0 = (bid - p.blk_start[seg]) * ppb;
  int np = min(ppb, P - p0);
  int R = np * kk;      // multiple of 16 (16..96)
  int mtb = R >> 4;
  long ebase = (long)p0 * kk;
  if (t < 64) { bl[t] = p.ba[seg][t]; kbl[t] = p.Kb[seg][t]; }
  if (t < 9) { uint4 z; z.x = z.y = z.z = z.w = 0; xn4[96 * 9 + t] = z; }
  if (t < R) ridx[t] = p.gidx[seg][ebase + t];
  __syncthreads();
  // ---- build a2p A-frags from gathered fp32 x
  const float4* x4 = (const float4*)p.x;
  for (int idx = t; idx < R * 8; idx += 256) {
    int row = idx >> 3, ch = idx & 7;
    long base = (long)ridx[row] * 16 + ch * 2;
    float4 v0 = x4[base];
    float4 v1 = x4[base + 1];
    HU o;
    o.s[0] = (f16)v0.x; o.s[1] = (f16)v0.y; o.s[2] = (f16)v0.z; o.s[3] = (f16)v0.w;
    o.s[4] = (f16)v1.x; o.s[5] = (f16)v1.y; o.s[6] = (f16)v1.z; o.s[7] = (f16)v1.w;
    Af[(((row >> 4) << 1) + (ch >> 2)) * 64 + ((ch & 3) << 4) + (row & 15)] = o.u;
  }
  __syncthreads();
  int lane = t & 63, wid = t >> 6;
  int wave_n = wid & 1, wave_m = wid >> 1;
  int mtA = (mtb + 1) >> 1;
  int m0 = wave_m ? mtA : 0;
  int mcnt = wave_m ? (mtb - mtA) : mtA;  // <= 3
  // ---- a2p MFMA
  f32x4 acc[3][2];
#pragma unroll
  for (int i = 0; i < 3; i++)
#pragma unroll
    for (int jn = 0; jn < 2; jn++) { f32x4 z = {0.f, 0.f, 0.f, 0.f}; acc[i][jn] = z; }
  const uint4* Wau = (const uint4*)p.Wa[seg];
#pragma unroll
  for (int kc = 0; kc < 2; kc++) {
    HU a[3], b[2];
#pragma unroll
    for (int jn = 0; jn < 2; jn++)
      b[jn].u = Wau[(((wave_n * 2 + jn) << 1) + kc) * 64 + lane];
#pragma unroll
    for (int i = 0; i < 3; i++)
      if (i < mcnt) a[i].u = Af[(((m0 + i) << 1) + kc) * 64 + lane];
#pragma unroll
    for (int i = 0; i < 3; i++)
      if (i < mcnt) {
#pragma unroll
        for (int jn = 0; jn < 2; jn++)
          acc[i][jn] = __builtin_amdgcn_mfma_f32_16x16x32_f16(a[i].h, b[jn].h, acc[i][jn], 0, 0, 0);
      }
  }
  __syncthreads();  // Af reads done; Cf may overwrite
  // ---- a2p epilogue -> Cf
#pragma unroll
  for (int i = 0; i < 3; i++) {
    if (i >= mcnt) continue;
#pragma unroll
    for (int jn = 0; jn < 2; jn++) {
      int n = ((wave_n * 2 + jn) << 4) + (lane & 15);
      float bv = bl[n];
      int rb = ((m0 + i) << 4) + ((lane >> 4) << 2);
#pragma unroll
      for (int reg = 0; reg < 4; reg++) {
        float v = acc[i][jn][reg] + bv;
        Cf[(rb + reg) * CLD2 + n] = v > 0.f ? v : 0.f;
      }
    }
  }
  __syncthreads();
  // ---- t = xp_old + relu(...) -> xnew (LDS only)
  uint4* xg = (uint4*)(p.xp[seg] + (long)ebase * 64);
  for (int idx = t; idx < R * 8; idx += 256) {
    int row = idx >> 3, ch = idx & 7;
    HU res; res.u = xg[idx];
    const float* c = &Cf[row * CLD2 + ch * 8];
    HU o;
#pragma unroll
    for (int j = 0; j < 8; j++) o.s[j] = (f16)((float)res.s[j] + c[j]);
    xn4[row * 9 + ch] = o.u;
  }
  __syncthreads();
  // ---- conv MFMA: A-frags gathered from xnew with shifted rows (dest m reads src row)
  f32x4 acc2[3][2];
#pragma unroll
  for (int i = 0; i < 3; i++)
#pragma unroll
    for (int jn = 0; jn < 2; jn++) { f32x4 z = {0.f, 0.f, 0.f, 0.f}; acc2[i][jn] = z; }
  int rdw[3][3];
#pragma unroll
  for (int i = 0; i < 3; i++) {
    if (i >= mcnt) continue;
    int mr = ((m0 + i) << 4) + (lane & 15);
    int sm = mr % kk;
    rdw[i][1] = mr;
    rdw[i][0] = (sm >= 1) ? mr - 1 : (cyc ? mr + kk - 1 : 96);
    rdw[i][2] = (sm + 1 < kk) ? mr + 1 : (cyc ? mr + 1 - kk : 96);
  }
  const uint4* Bg = (const uint4*)p.Bp[seg];
  for (int kc = 0; kc < 6; kc++) {
    int w = kc >> 1;
    int chunk = ((kc & 1) << 2) + (lane >> 4);
    HU a[3], b[2];
#pragma unroll
    for (int jn = 0; jn < 2; jn++)
      b[jn].u = Bg[((wave_n * 2 + jn) * 6 + kc) * 64 + lane];
#pragma unroll
    for (int i = 0; i < 3; i++)
      if (i < mcnt) a[i].u = xn4[rdw[i][w] * 9 + chunk];
#pragma unroll
    for (int i = 0; i < 3; i++)
      if (i < mcnt) {
#pragma unroll
        for (int jn = 0; jn < 2; jn++)
          acc2[i][jn] = __builtin_amdgcn_mfma_f32_16x16x32_f16(a[i].h, b[jn].h, acc2[i][jn], 0, 0, 0);
      }
  }
  __syncthreads();  // xnew-combine Cf reads done; Cf overwrite OK
  // ---- conv epilogue -> Cf
#pragma unroll
  for (int i = 0; i < 3; i++) {
    if (i >= mcnt) continue;
#pragma unroll
    for (int jn = 0; jn < 2; jn++) {
      int n = ((wave_n * 2 + jn) << 4) + (lane & 15);
      float bv = kbl[n];
      int rb = ((m0 + i) << 4) + ((lane >> 4) << 2);
#pragma unroll
      for (int reg = 0; reg < 4; reg++) {
        float v = acc2[i][jn][reg] + bv;
        Cf[(rb + reg) * CLD2 + n] = v > 0.f ? v : 0.f;
      }
    }
  }
  __syncthreads();
  // ---- final: xp_new = xnew + relu-conv, single coalesced global write
  for (int idx = t; idx < R * 8; idx += 256) {
    int row = idx >> 3, ch = idx & 7;
    HU res; res.u = xn4[row * 9 + ch];
    const float* c = &Cf[row * CLD2 + ch * 8];
    HU o;
#pragma unroll
    for (int j = 0; j < 8; j++) o.s[j] = (f16)((float)res.s[j] + c[j]);
    xg[idx] = o.u;
  }
}

// ---------------- p2a scatter: acc[row[e]] += xp[e] (packed f16 global atomics) ----------

__global__ __launch_bounds__(256) void k_scatter(const f16* xp, const int* row,
                                                 __half2* acc, int E) {
  int gw = (blockIdx.x * 256 + threadIdx.x) >> 6;
  int half = (threadIdx.x >> 5) & 1;
  int l = threadIdx.x & 31;
  int nw = (gridDim.x * 256) >> 6;
  const unsigned int* xpu = (const unsigned int*)xp;
  for (int e0 = gw * 8; e0 < E; e0 += nw * 8) {
    int e[4]; unsigned int v[4]; int a[4];
#pragma unroll
    for (int u = 0; u < 4; u++) e[u] = e0 + 2 * u + half;
#pragma unroll
    for (int u = 0; u < 4; u++) v[u] = xpu[(long)e[u] * 32 + l];
#pragma unroll
    for (int u = 0; u < 4; u++) a[u] = row[e[u]];
#pragma unroll
    for (int u = 0; u < 4; u++) {
      __half2 hv = *(__half2*)&v[u];
      pk_atomic_add(&acc[(long)a[u] * 32 + l], hv);
    }
  }
}

// ---------------- p2a apply: x += relu(acc/cnt @ W + b); self-zeroes f16 acc ----------------

__global__ __launch_bounds__(256) void k_apply(f16* acc, const int* cnt, const f16* Wp,
                                               const float* bias, float* x) {
  __shared__ float mean[64 * MLD];  // 17.4KB
  __shared__ uint4 Af[512];         // 8KB fp16 A-frags
  __shared__ float invl[64];
  __shared__ float bl[64];
  int t = threadIdx.x;
  int a0 = blockIdx.x * 64;
  if (t < 64) {
    int cb = cnt[a0 + t];
    invl[t] = 1.f / (float)(cb > 0 ? cb : 1);
    bl[t] = bias[t];
  }
  uint4* acc4 = (uint4*)acc;  // 8 halves per uint4; 64 rows x 8 = 512 per tile
#pragma unroll
  for (int i = 0; i < 2; i++) {
    int idx = t + 256 * i;
    int r = idx >> 3, q = idx & 7;
    HU v; v.u = acc4[(long)a0 * 8 + idx];
    uint4 z4; z4.x = z4.y = z4.z = z4.w = 0;
    acc4[(long)a0 * 8 + idx] = z4;  // ready for next map
    float* mr = &mean[r * MLD + q * 8];
#pragma unroll
    for (int j = 0; j < 8; j++) mr[j] = (float)v.s[j];
  }
  __syncthreads();
#pragma unroll
  for (int i = 0; i < 2; i++) {
    int la = (t >> 3) + 32 * i;
    int g = t & 7;
    float inv = invl[la];
    const float* mr = &mean[la * MLD + g * 8];
    HU o;
#pragma unroll
    for (int j = 0; j < 8; j++) o.h[j] = (f16)(mr[j] * inv);
    int kc = g >> 2, lb = ((g & 3) << 4) + (la & 15), mtt = la >> 4;
    Af[(((mtt << 1) + kc) << 6) + lb] = o.u;
  }
  __syncthreads();
  int lane = t & 63, wid = t >> 6;
  HU af0, af1;
  af0.u = Af[((wid << 1) + 0) * 64 + lane];
  af1.u = Af[((wid << 1) + 1) * 64 + lane];
  const uint4* Wu = (const uint4*)Wp;
  int rowb = a0 + wid * 16 + ((lane >> 4) << 2);
#pragma unroll
  for (int nt = 0; nt < 4; nt++) {
    HU b0, b1;
    b0.u = Wu[((nt << 1) + 0) * 64 + lane];
    b1.u = Wu[((nt << 1) + 1) * 64 + lane];
    f32x4 z = {0.f, 0.f, 0.f, 0.f};
    z = __builtin_amdgcn_mfma_f32_16x16x32_f16(af0.h, b0.h, z, 0, 0, 0);
    z = __builtin_amdgcn_mfma_f32_16x16x32_f16(af1.h, b1.h, z, 0, 0, 0);
    int n = nt * 16 + (lane & 15);
    float bv = bl[n];
#pragma unroll
    for (int r = 0; r < 4; r++) {
      int atom = rowb + r;
      if (atom < NA) {
        float vv = z[r] + bv;
        vv = vv > 0.f ? vv : 0.f;
        x[(long)atom * 64 + n] += vv;
      }
    }
  }
}

// ---------------- batch mean: g1[b] = mean(x[a]) over CSR bucket ----------------

__global__ __launch_bounds__(256) void k_meanscatter(const float* src, const int* bucket,
                                                     const int* basea, const int* cnta,
                                                     float* dst, int nseg) {
  int wid = (blockIdx.x * 256 + threadIdx.x) >> 6;
  int lane = threadIdx.x & 63;
  if (wid >= nseg) return;
  int b0 = basea[wid], cnt = cnta[wid];
  float s = 0.f;
  for (int i = 0; i < cnt; i++) {
    int e = bucket[b0 + i];
    s += src[(long)e * 64 + lane];
  }
  dst[(long)wid * 64 + lane] = s / (float)(cnt > 0 ? cnt : 1);
}

// ---------------- head gemm: g2 = relu(g1 @ W + b) ----------------

__global__ __launch_bounds__(256) void k_head(const float* g1, const float* W,
                                              const float* bias, float* g2) {
  __shared__ float Wl[4096];
  __shared__ float inl[32 * 64];
  __shared__ float bl[64];
  int t = threadIdx.x;
  int brow = blockIdx.x * 32;
#pragma unroll
  for (int i = 0; i < 4; i++) ((float4*)Wl)[t + 256 * i] = ((const float4*)W)[t + 256 * i];
  if (t < 64) bl[t] = bias[t];
  __syncthreads();
#pragma unroll
  for (int i = 0; i < 2; i++) {
    int idx = t + 256 * i;
    int r = idx >> 4, q = idx & 15;
    ((float4*)inl)[idx] = ((const float4*)(g1 + (long)(brow + r) * 64))[q];
  }
  __syncthreads();
  int c = t & 63, rq = t >> 6;
  float acc[8];
#pragma unroll
  for (int i = 0; i < 8; i++) acc[i] = 0.f;
  for (int j = 0; j < 64; j += 4) {
    float w0 = Wl[(j + 0) * 64 + c], w1 = Wl[(j + 1) * 64 + c];
    float w2 = Wl[(j + 2) * 64 + c], w3 = Wl[(j + 3) * 64 + c];
#pragma unroll
    for (int i = 0; i < 8; i++) {
      int r = rq * 8 + i;
      float4 v = *(const float4*)&inl[r * 64 + j];
      acc[i] += v.x * w0 + v.y * w1 + v.z * w2 + v.w * w3;
    }
  }
#pragma unroll
  for (int i = 0; i < 8; i++) {
    long r = brow + rq * 8 + i;
    float v = acc[i] + bl[c];
    g2[r * 64 + c] = v > 0.f ? v : 0.f;
  }
}

__global__ __launch_bounds__(256) void k_final(const float* g2, const float* linW,
                                               const float* linb, float* out) {
  int wid = (blockIdx.x * 256 + threadIdx.x) >> 6;
  int lane = threadIdx.x & 63;
  if (wid >= NBATCH) return;
  float v = g2[(long)wid * 64 + lane] * linW[lane];
  for (int o = 32; o > 0; o >>= 1) v += __shfl_down(v, o, 64);
  if (lane == 0) out[wid] = v + linb[0];
}

__global__ __launch_bounds__(256) void k_zero_out(float* out, int n) {
  for (int i = blockIdx.x * 256 + threadIdx.x; i < n; i += gridDim.x * 256) out[i] = 0.f;
}

// ---------------- launcher ----------------

extern "C" void kernel_launch(void* const* d_in, const int* in_sizes, int n_in,
                              void* d_out, int out_size, void* d_ws, size_t ws_size,
                              hipStream_t stream) {
  (void)in_sizes; (void)n_in;

  const int* x_atom = (const int*)d_in[0];
  const int* vals[5] = {(const int*)d_in[1], (const int*)d_in[4], (const int*)d_in[7],
                        (const int*)d_in[10], (const int*)d_in[13]};
  const int* rowm[5] = {(const int*)d_in[2], (const int*)d_in[5], (const int*)d_in[8],
                        (const int*)d_in[11], (const int*)d_in[14]};
  const int* batch = (const int*)d_in[16];
  const float* aemb0 = (const float*)d_in[17];
  const float* aemb1 = (const float*)d_in[18];
  const float* aemb2 = (const float*)d_in[19];
  const float* path_emb = (const float*)d_in[20];
  const float* cycle_emb = (const float*)d_in[21];
  const float* pW_a2p = (const float*)d_in[22];
  const float* pb_a2p = (const float*)d_in[23];
  const float* pW_p2a = (const float*)d_in[24];
  const float* pb_p2a = (const float*)d_in[25];
  const float* pK = (const float*)d_in[26];
  const float* pKb = (const float*)d_in[27];
  const float* cW_a2p = (const float*)d_in[28];
  const float* cb_a2p = (const float*)d_in[29];
  const float* cW_p2a = (const float*)d_in[30];
  const float* cb_p2a = (const float*)d_in[31];
  const float* cK = (const float*)d_in[32];
  const float* cKb = (const float*)d_in[33];
  const float* alW = (const float*)d_in[34];
  const float* alb = (const float*)d_in[35];
  const float* linW = (const float*)d_in[36];
  const float* linb = (const float*)d_in[37];

  static const int Em[5] = {300000, 400000, 500000, 200000, 240000};
  static const int Km[5] = {3, 4, 5, 5, 6};
  static const int Ppb[5] = {32, 24, 16, 16, 16};  // paths/block -> R in {96,96,80,80,96}
  const int CNT_N = 5 * 100000 + NBATCH;  // 504096
  const int ACC_ROWS = 100032;            // padded to block grid (1563*64)

  char* ws = (char*)d_ws;
  size_t off = 0;
  auto alloc = [&](size_t nbytes) -> char* {
    char* p = ws + off;
    off = (off + nbytes + 255) & ~(size_t)255;
    return p;
  };
  float* x = (float*)alloc((size_t)NA * 64 * 4);
  __half* xp[5];
  for (int m = 0; m < 5; m++) xp[m] = (__half*)alloc((size_t)Em[m] * 64 * 2);
  f16* acc = (f16*)alloc((size_t)ACC_ROWS * 64 * 2);  // f16 accumulator
  float* g1 = (float*)alloc((size_t)NBATCH * 64 * 4);
  float* g2 = (float*)alloc((size_t)NBATCH * 64 * 4);
  int* cnt = (int*)alloc((size_t)CNT_N * 4);
  int* basea_b = (int*)alloc((size_t)(NBATCH + 1) * 4);
  int* cursor_b = (int*)alloc((size_t)NBATCH * 4);
  int* bucket = (int*)alloc((size_t)NA * 4);
  f16* Bp = (f16*)alloc((size_t)10 * 12288 * 2);  // prepacked conv kernels
  f16* Wpk = (f16*)alloc((size_t)20 * 4096 * 2);  // prepacked p2a+a2p weights

  if (ws_size < off) {  // workspace too small: emit readable failure, not a fault
    k_zero_out<<<16, 256, 0, stream>>>((float*)d_out, out_size);
    return;
  }

  // ---- counts (all maps + batch) and batch CSR
  MapsParams mp;
  {
    int s = 0;
    for (int m = 0; m < 5; m++) {
      mp.row[m] = rowm[m]; mp.cnt_off[m] = m * 100000;
      mp.start[m] = s; s += Em[m];
    }
    mp.row[5] = batch; mp.cnt_off[5] = 500000; mp.start[5] = s;
    mp.total = s + NA;
  }
  (void)hipMemsetAsync(cnt, 0, (size_t)CNT_N * 4, stream);
  (void)hipMemsetAsync(acc, 0, (size_t)ACC_ROWS * 64 * 2, stream);
  k_count<<<2048, 256, 0, stream>>>(mp, cnt);
  k_scan_batch<<<1, 256, 0, stream>>>(cnt + 500000, basea_b);
  (void)hipMemcpyAsync(cursor_b, basea_b, (size_t)NBATCH * 4, hipMemcpyDeviceToDevice, stream);
  k_fill_batch<<<128, 256, 0, stream>>>(batch, cursor_b, bucket);

  // ---- prepack weights + feature init
  k_prepB<<<480, 256, 0, stream>>>(pK, cK, Bp);
  k_prepW<<<320, 256, 0, stream>>>(pW_p2a, cW_p2a, pW_a2p, cW_a2p, Wpk);
  k_atom_init<<<NA * 16 / 256, 256, 0, stream>>>(x_atom, aemb0, aemb1, aemb2, x);
  {
    PInit pp;
    int s8 = 0;
    for (int m = 0; m < 5; m++) {
      pp.dst[m] = xp[m];
      pp.vals[m] = vals[m];
      pp.tab[m] = (m < 3) ? (path_emb + m * 6 * 64) : (cycle_emb + (m - 3) * 4 * 64);
      pp.start8[m] = s8;
      s8 += Em[m] * 8;
    }
    pp.total8 = s8;
    k_path_init<<<8192, 256, 0, stream>>>(pp);
  }

  int apply_blocks = ACC_ROWS / 64;  // 1563

  // ---- layers
  for (int l = 0; l < 2; l++) {
    // === paths group (maps 0..2), non-cyclic
    {
      FusedParams fp{};
      fp.nseg = 3; fp.cyclic = 0; fp.x = x;
      int bs = 0;
      for (int m = 0; m < 3; m++) {
        fp.gidx[m] = rowm[m]; fp.xp[m] = xp[m];
        fp.Wa[m] = Wpk + (size_t)(10 + l * 3 + m) * 4096;
        fp.ba[m] = pb_a2p + (l * 3 + m) * 64;
        fp.Bp[m] = Bp + (size_t)(l * 3 + m) * 12288;
        fp.Kb[m] = pKb + (l * 3 + m) * 64;
        fp.k[m] = Km[m]; fp.P[m] = Em[m] / Km[m]; fp.ppb[m] = Ppb[m];
        fp.blk_start[m] = bs;
        bs += (fp.P[m] + fp.ppb[m] - 1) / fp.ppb[m];
      }
      k_fused<<<bs, 256, 0, stream>>>(fp);

      for (int m = 0; m < 3; m++) {
        k_scatter<<<1024, 256, 0, stream>>>((const f16*)xp[m], rowm[m], (__half2*)acc, Em[m]);
        k_apply<<<apply_blocks, 256, 0, stream>>>(acc, cnt + m * 100000,
                                                  Wpk + (size_t)(l * 3 + m) * 4096,
                                                  pb_p2a + (l * 3 + m) * 64, x);
      }
    }
    // === cycles group (maps 3..4), cyclic
    {
      FusedParams fp{};
      fp.nseg = 2; fp.cyclic = 1; fp.x = x;
      int bs = 0;
      for (int m = 3; m < 5; m++) {
        int i = m - 3;
        fp.gidx[i] = rowm[m]; fp.xp[i] = xp[m];
        fp.Wa[i] = Wpk + (size_t)(16 + l * 2 + i) * 4096;
        fp.ba[i] = cb_a2p + (l * 2 + i) * 64;
        fp.Bp[i] = Bp + (size_t)(6 + l * 2 + i) * 12288;
        fp.Kb[i] = cKb + (l * 2 + i) * 64;
        fp.k[i] = Km[m]; fp.P[i] = Em[m] / Km[m]; fp.ppb[i] = Ppb[m];
        fp.blk_start[i] = bs;
        bs += (fp.P[i] + fp.ppb[i] - 1) / fp.ppb[i];
      }
      k_fused<<<bs, 256, 0, stream>>>(fp);

      for (int m = 3; m < 5; m++) {
        int i = m - 3;
        k_scatter<<<1024, 256, 0, stream>>>((const f16*)xp[m], rowm[m], (__half2*)acc, Em[m]);
        k_apply<<<apply_blocks, 256, 0, stream>>>(acc, cnt + m * 100000,
                                                  Wpk + (size_t)(6 + l * 2 + i) * 4096,
                                                  cb_p2a + (l * 2 + i) * 64, x);
      }
    }
  }

  // ---- head
  k_meanscatter<<<NBATCH / 4, 256, 0, stream>>>(x, bucket, basea_b, cnt + 500000,
                                                g1, NBATCH);
  k_head<<<NBATCH / 32, 256, 0, stream>>>(g1, alW, alb, g2);
  k_final<<<NBATCH / 4, 256, 0, stream>>>(g2, linW, linb, (float*)d_out);
}